// Round 9
// baseline (277.426 us; speedup 1.0000x reference)
//
#include <hip/hip_runtime.h>
#include <hip/hip_bf16.h>
#include <cstdint>

typedef __attribute__((ext_vector_type(8))) __bf16 bf16v8;
typedef __attribute__((ext_vector_type(4))) float f32x4;
typedef __attribute__((ext_vector_type(4))) unsigned short ushort4v;
typedef __attribute__((ext_vector_type(8))) unsigned short ushort8v;

#define BB 8
#define NN 2048
#define DD 768

__device__ __forceinline__ float b2f(unsigned short u) {
  union { unsigned int i; float f; } c; c.i = ((unsigned int)u) << 16; return c.f;
}
__device__ __forceinline__ unsigned short f2b(float f) {
  union { float f; unsigned int i; } c; c.f = f;
  unsigned int u = c.i;
  return (unsigned short)((u + 0x7fffu + ((u >> 16) & 1u)) >> 16);
}

// ---------------- LayerNorm: f32 [16384][768] -> bf16 ----------------
__global__ __launch_bounds__(256) void ln_kernel(const float* __restrict__ x,
                                                 const float* __restrict__ gamma,
                                                 const float* __restrict__ beta,
                                                 unsigned short* __restrict__ xb) {
  int row = blockIdx.x;
  const float* xr = x + (size_t)row * DD;
  int t = threadIdx.x;
  float a0 = xr[t], a1 = xr[t + 256], a2 = xr[t + 512];
  float s = a0 + a1 + a2;
  float q = a0 * a0 + a1 * a1 + a2 * a2;
  for (int o = 32; o > 0; o >>= 1) { s += __shfl_xor(s, o); q += __shfl_xor(q, o); }
  __shared__ float red[2][4];
  int w = t >> 6, lane = t & 63;
  if (lane == 0) { red[0][w] = s; red[1][w] = q; }
  __syncthreads();
  s = red[0][0] + red[0][1] + red[0][2] + red[0][3];
  q = red[1][0] + red[1][1] + red[1][2] + red[1][3];
  float mean = s * (1.0f / DD);
  float var = q * (1.0f / DD) - mean * mean;
  float inv = rsqrtf(var + 1e-5f);
  unsigned short* o0 = xb + (size_t)row * DD;
  o0[t]       = f2b((a0 - mean) * inv * gamma[t]       + beta[t]);
  o0[t + 256] = f2b((a1 - mean) * inv * gamma[t + 256] + beta[t + 256]);
  o0[t + 512] = f2b((a2 - mean) * inv * gamma[t + 512] + beta[t + 512]);
}

// ------------- Weight concat/convert: Wcat[2304][768] bf16, scale folded into Wq -------------
__global__ __launch_bounds__(256) void wconvert(const float* __restrict__ Wq,
                                                const float* __restrict__ Wk,
                                                const float* __restrict__ Wv,
                                                unsigned short* __restrict__ Wcat) {
  int i = blockIdx.x * 256 + threadIdx.x;
  const int dd = DD * DD;
  if (i >= 3 * dd) return;
  float v;
  if (i < dd)           v = Wq[i] * 0.03608439182435161f;   // 1/sqrt(768)
  else if (i < 2 * dd)  v = Wk[i - dd];
  else                  v = Wv[i - 2 * dd];
  Wcat[i] = f2b(v);
}

// ---------------- async global->LDS (16B per lane, wave-uniform LDS base) ----------------
__device__ __forceinline__ void gload_lds16(const void* g, void* l) {
  __builtin_amdgcn_global_load_lds(
      (const __attribute__((address_space(1))) void*)g,
      (__attribute__((address_space(3))) void*)(unsigned)(uintptr_t)l,
      16, 0, 0);
}

// LDS geometry (elements): buffer b at b*32768.
//   slot A-ks at  buf + ks*8192          (256 rows x 32 cols, 64B rows)
//   slot B-ks at  buf + 16384 + ks*8192  (B slot sized for 256 rows; only BN rows read)
#define RDA(i0, ks, B)                                                                   \
  _Pragma("unroll")                                                                      \
  for (int i_ = 0; i_ < 4; ++i_)                                                         \
    aq[i_] = *(const bf16v8*)&smem[(B) + (ks) * 8192 + arow0 + ((i0) + i_) * 512 + kg8];
#define RDB(ks, B)                                                                       \
  _Pragma("unroll")                                                                      \
  for (int j_ = 0; j_ < NJ; ++j_)                                                        \
    bq[j_] = *(const bf16v8*)&smem[(B) + 16384 + (ks) * 8192 + brow0 + j_ * 512 + kg8];
#define MFQ(i0)                                                                          \
  _Pragma("unroll")                                                                      \
  for (int i_ = 0; i_ < 4; ++i_) {                                                       \
    _Pragma("unroll")                                                                    \
    for (int j_ = 0; j_ < NJ; ++j_)                                                      \
      acc[(i0) + i_][j_] = __builtin_amdgcn_mfma_f32_16x16x32_bf16(                      \
          aq[i_], bq[j_], acc[(i0) + i_][j_], 0, 0, 0);                                  \
  }
#define BARF asm volatile("s_barrier" ::: "memory")
#define VMC6 asm volatile("s_waitcnt vmcnt(6)" ::: "memory")
#define VMC0 asm volatile("s_waitcnt vmcnt(0)" ::: "memory")
#define P1   __builtin_amdgcn_s_setprio(1)
#define P0   __builtin_amdgcn_s_setprio(0)

// One K-tile = 4 balanced phases (ledger identical to round-6, per-tile local):
//   ph1: stage A-ks1(t+1) -> NXTB    ph2: stage B-ks1(t+1) -> NXTB
//   ph3: stage A-ks0(t+2) -> CURB    ph4: stage B-ks0(t+2) -> CURB
//   VMC6 at ph2/ph4 ends; VMC0 only at kt==NT-2 (tail drain inside the tile).
#define TILEK(KT, CURB, NXTB)                                                            \
  do {                                                                                   \
    RDA(0, 0, CURB); RDB(0, CURB);                                                       \
    if ((KT) + 1 < NT) stgA((KT) + 1, 1, (NXTB));                                        \
    BARF; P1; MFQ(0); P0; BARF;                                                          \
    RDA(4, 0, CURB);                                                                     \
    if ((KT) + 1 < NT) stgB((KT) + 1, 1, (NXTB));                                        \
    BARF; P1; MFQ(4); P0;                                                                \
    VMC6; BARF;                                                                          \
    RDA(0, 1, CURB); RDB(1, CURB);                                                       \
    if ((KT) + 2 < NT) stgA((KT) + 2, 0, (CURB));                                        \
    BARF; P1; MFQ(0); P0; BARF;                                                          \
    RDA(4, 1, CURB);                                                                     \
    if ((KT) + 2 < NT) stgB((KT) + 2, 0, (CURB));                                        \
    BARF; P1; MFQ(4); P0;                                                                \
    if ((KT) < NT - 2) { VMC6; } else { VMC0; }                                          \
    BARF;                                                                                \
  } while (0)

// ---- 256xBN GEMM, C = A*B^T. 256 blocks (1.0/CU, single generation). Each block runs
// TPB tiles sequentially: full drain -> epilogue -> fresh prologue per tile (stores are
// never inside a counted-vmcnt window; the next prologue's vmcnt(8) drains them).
// MODE 0: QKV epilogue (Q/K direct; V via LDS-transpose coalesced store)
// MODE 1: bf16 store   MODE 2: f32 store
template <int MODE, int NJ, int NTT, int TPB>
__global__ __launch_bounds__(512, 2) void gemmT(
    const unsigned short* __restrict__ A, const unsigned short* __restrict__ Bm,
    unsigned short* __restrict__ Cq, unsigned short* __restrict__ Ck,
    unsigned short* __restrict__ Cv, float* __restrict__ Cf,
    int lda, int ldb,
    long aStride, long bStride, long cStride) {
  extern __shared__ unsigned short smem[];      // 131072 B
  constexpr int NT = NTT;

  const int t = threadIdx.x;
  // physical->logical: each XCD (bid&7) owns a contiguous chunk of 32 logical blocks
  const int lid = (blockIdx.x & 7) * 32 + (blockIdx.x >> 3);

  const int lane = t & 63;
  const int w = t >> 6;
  const int wm = w >> 2, wn = w & 3;            // 2 x 4 wave grid
  const int frow = lane & 15;
  const int kg8 = (lane >> 4) * 8;
  const int arow0 = (wm * 128 + frow) * 32;
  const int brow0 = (wn * (NJ * 16) + frow) * 32;
  const int srow = t >> 2;
  const int scol8 = (t & 3) * 8;
  const int sdst = w * 512;
  const int r0 = (lane >> 4) * 4;
  const int c0 = lane & 15;

  f32x4 acc[8][NJ];
  bf16v8 aq[4], bq[NJ];

#pragma unroll 1
  for (int tt = 0; tt < TPB; ++tt) {
    const int T = lid * TPB + tt;
    int m0, n0, bz;
    if (MODE == 0)      { bz = 0;      n0 = (T >> 6) * 192;        m0 = (T & 63) * 256; }
    else if (MODE == 1) { bz = T >> 6; m0 = ((T >> 3) & 7) * 256;  n0 = (T & 7) * 256; }
    else                { bz = T >> 5; m0 = ((T >> 2) & 7) * 256;  n0 = (T & 3) * 192; }

    const unsigned short* AsrcB = A + (size_t)bz * aStride + (size_t)(m0 + srow) * lda + scol8;
    const unsigned short* BsrcB = Bm + (size_t)bz * bStride + (size_t)(n0 + srow) * ldb + scol8;

    auto stgA = [&](int kt, int ks, int bufb) {
      const unsigned short* s = AsrcB + kt * 64 + ks * 32;
      gload_lds16(s, &smem[bufb + ks * 8192 + sdst]);
      gload_lds16(s + (size_t)128 * lda, &smem[bufb + ks * 8192 + 4096 + sdst]);
    };
    auto stgB = [&](int kt, int ks, int bufb) {
      const unsigned short* s = BsrcB + kt * 64 + ks * 32;
      gload_lds16(s, &smem[bufb + 16384 + ks * 8192 + sdst]);
      gload_lds16(s + (size_t)128 * ldb, &smem[bufb + 16384 + ks * 8192 + 4096 + sdst]);
    };

#pragma unroll
    for (int i = 0; i < 8; ++i)
#pragma unroll
      for (int j = 0; j < NJ; ++j) acc[i][j] = f32x4{0.f, 0.f, 0.f, 0.f};

    // prologue: ks0(0), ks1(0), ks0(1); vmcnt(8) retires ks0(0) AND drains prior stores
    stgA(0, 0, 0);     stgB(0, 0, 0);
    stgA(0, 1, 0);     stgB(0, 1, 0);
    stgA(1, 0, 32768); stgB(1, 0, 32768);
    asm volatile("s_waitcnt vmcnt(8)" ::: "memory");
    BARF;

    for (int ktp = 0; ktp < NT; ktp += 2) {
      TILEK(ktp, 0, 32768);
      TILEK(ktp + 1, 32768, 0);
    }

    // ---- epilogue (pipeline fully drained: tail VMC0 + BARF inside last TILEK) ----
    const int mrowB = m0 + wm * 128 + r0;
    const int ncolB = n0 + wn * (NJ * 16) + c0;

    if (MODE == 0) {
      if (n0 < 1536) {  // Q or K region (block-uniform)
        unsigned short* dst = (n0 < 768) ? Cq : Ck;
        const int cb = (n0 < 768) ? 0 : 768;
#pragma unroll
        for (int i = 0; i < 8; ++i)
#pragma unroll
          for (int j = 0; j < NJ; ++j)
#pragma unroll
            for (int r = 0; r < 4; ++r)
              dst[(size_t)(mrowB + i * 16 + r) * DD + (ncolB + j * 16 - cb)] = f2b(acc[i][j][r]);
      } else {
        // V region (full 256x192 tile): transpose via LDS -> coalesced Vt stores.
        // LDS layout [192][264] ushort (stride 264 = 2-way-free banking).
        BARF;
#pragma unroll
        for (int i = 0; i < 8; ++i)
#pragma unroll
          for (int j = 0; j < NJ; ++j) {
            const int nl = wn * (NJ * 16) + j * 16 + c0;       // 0..191
            const int ml = wm * 128 + i * 16 + r0;             // 0..255, %4==0
            ushort4v pk;
#pragma unroll
            for (int r = 0; r < 4; ++r) pk[r] = f2b(acc[i][j][r]);
            *(ushort4v*)&smem[nl * 264 + ml] = pk;             // ds_write_b64
          }
        BARF;
        const int bb = m0 >> 11, nnb = m0 & 2047;
        const int e0 = n0 - 1536;
#pragma unroll
        for (int ii = 0; ii < 12; ++ii) {
          const int flat = t + ii * 512;                       // 0..6143
          const int e = flat >> 5;                             // 0..191
          const int mo = (flat & 31) * 8;                      // 0..248
          ushort8v vv = *(const ushort8v*)&smem[e * 264 + mo];
          *(ushort8v*)&Cv[((size_t)(bb * DD + e0 + e)) * NN + nnb + mo] = vv;
        }
        BARF;  // protect smem before next tile's prologue staging
      }
    } else if (MODE == 1) {
      unsigned short* dst = Cq + (size_t)bz * cStride;
#pragma unroll
      for (int i = 0; i < 8; ++i)
#pragma unroll
        for (int j = 0; j < NJ; ++j)
#pragma unroll
          for (int r = 0; r < 4; ++r)
            dst[(size_t)(mrowB + i * 16 + r) * NN + (ncolB + j * 16)] = f2b(acc[i][j][r]);
    } else {
      float* dst = Cf + (size_t)bz * cStride;
#pragma unroll
      for (int i = 0; i < 8; ++i)
#pragma unroll
        for (int j = 0; j < NJ; ++j)
#pragma unroll
          for (int r = 0; r < 4; ++r)
            dst[(size_t)(mrowB + i * 16 + r) * DD + (ncolB + j * 16)] = acc[i][j][r];
    }
  }
}

// ---------------- masked softmax, in-place on bf16 S rows ----------------
__global__ __launch_bounds__(256) void softmax_mask(unsigned short* __restrict__ S,
                                                    const int* __restrict__ mask) {
  int row = blockIdx.x;            // 0..16383
  int bb = row >> 11;
  unsigned short* sr = S + (size_t)row * NN;
  const int* mr = mask + bb * NN;
  int t = threadIdx.x;

  ushort8v pk = *(const ushort8v*)&sr[t * 8];
  float v[8];
  int msk[8];
#pragma unroll
  for (int j = 0; j < 8; ++j) msk[j] = mr[t * 8 + j];
  float mx = -1e30f;
#pragma unroll
  for (int j = 0; j < 8; ++j) {
    v[j] = b2f(pk[j]);
    if (!msk[j]) mx = fmaxf(mx, v[j]);
  }
  for (int o = 32; o > 0; o >>= 1) mx = fmaxf(mx, __shfl_xor(mx, o));
  __shared__ float redm[4], reds[4];
  int w = t >> 6, lane = t & 63;
  if (lane == 0) redm[w] = mx;
  __syncthreads();
  mx = fmaxf(fmaxf(redm[0], redm[1]), fmaxf(redm[2], redm[3]));

  float e[8];
  float sum = 0.f;
#pragma unroll
  for (int j = 0; j < 8; ++j) {
    e[j] = msk[j] ? 0.f : __expf(v[j] - mx);
    sum += e[j];
  }
  for (int o = 32; o > 0; o >>= 1) sum += __shfl_xor(sum, o);
  if (lane == 0) reds[w] = sum;
  __syncthreads();
  sum = reds[0] + reds[1] + reds[2] + reds[3];
  float inv = 1.0f / sum;

  ushort8v op;
#pragma unroll
  for (int j = 0; j < 8; ++j) op[j] = f2b(e[j] * inv);
  *(ushort8v*)&sr[t * 8] = op;
}

extern "C" void kernel_launch(void* const* d_in, const int* in_sizes, int n_in,
                              void* d_out, int out_size, void* d_ws, size_t ws_size,
                              hipStream_t stream) {
  const float* features = (const float*)d_in[0];
  const int* mask       = (const int*)d_in[1];
  const float* Wq       = (const float*)d_in[2];
  const float* Wk       = (const float*)d_in[3];
  const float* Wv       = (const float*)d_in[4];
  const float* gamma    = (const float*)d_in[5];
  const float* beta     = (const float*)d_in[6];
  float* out = (float*)d_out;

  char* ws = (char*)d_ws;
  size_t off = 0;
  auto alloc = [&](size_t bytes) {
    char* p = ws + off;
    off += (bytes + 255) & ~(size_t)255;
    return p;
  };
  // Wcat padded by 64 rows (192-wide B staging over-read at the last N-tile)
  unsigned short* Wcat = (unsigned short*)alloc((size_t)(2304 + 64) * DD * 2);
  unsigned short* Qb   = (unsigned short*)alloc((size_t)BB * NN * DD * 2);
  unsigned short* Kb   = (unsigned short*)alloc((size_t)BB * NN * DD * 2);
  // Vt padded by 64 rows of 2048 (over-read at last e-tile of last batch)
  unsigned short* Vt   = (unsigned short*)alloc(((size_t)BB * DD + 64) * NN * 2);
  // S (67 MB) aliases the X buffer region: X is dead once GEMM0 completes.
  char* last = alloc((size_t)BB * NN * NN * 2);
  unsigned short* Sb = (unsigned short*)last;
  unsigned short* Xb = (unsigned short*)last;  // first 25 MB of the S region

  (void)hipFuncSetAttribute(reinterpret_cast<const void*>(&gemmT<0, 3, 12, 3>),
                            hipFuncAttributeMaxDynamicSharedMemorySize, 131072);
  (void)hipFuncSetAttribute(reinterpret_cast<const void*>(&gemmT<1, 4, 12, 2>),
                            hipFuncAttributeMaxDynamicSharedMemorySize, 131072);
  (void)hipFuncSetAttribute(reinterpret_cast<const void*>(&gemmT<2, 3, 32, 1>),
                            hipFuncAttributeMaxDynamicSharedMemorySize, 131072);

  ln_kernel<<<BB * NN, 256, 0, stream>>>(features, gamma, beta, Xb);
  wconvert<<<(3 * DD * DD + 255) / 256, 256, 0, stream>>>(Wq, Wk, Wv, Wcat);

  // QKV projection: [16384,768] x [2304,768]^T ; 256 blocks x 3 tiles (12x64 tile grid)
  gemmT<0, 3, 12, 3><<<256, 512, 131072, stream>>>(
      Xb, Wcat, Qb, Kb, Vt, nullptr, DD, DD, 0, 0, 0);

  // Scores: per batch [2048,768] x [2048,768]^T -> S bf16 ; 256 blocks x 2 tiles
  gemmT<1, 4, 12, 2><<<256, 512, 131072, stream>>>(
      Qb, Kb, Sb, nullptr, nullptr, nullptr, DD, DD,
      (long)NN * DD, (long)NN * DD, (long)NN * NN);

  softmax_mask<<<BB * NN, 256, 0, stream>>>(Sb, mask);

  // Context: per batch P[2048,2048] x Vt[768,2048]^T -> f32 out ; 256 blocks x 1 tile
  gemmT<2, 3, 32, 1><<<256, 512, 131072, stream>>>(
      Sb, Vt, nullptr, nullptr, nullptr, out, NN, NN,
      (long)NN * NN, (long)DD * NN, (long)NN * DD);
}

// Round 10
// 252.669 us; speedup vs baseline: 1.0980x; 1.0980x over previous
//
#include <hip/hip_runtime.h>
#include <hip/hip_bf16.h>
#include <cstdint>

typedef __attribute__((ext_vector_type(8))) __bf16 bf16v8;
typedef __attribute__((ext_vector_type(4))) float f32x4;
typedef __attribute__((ext_vector_type(4))) unsigned short ushort4v;
typedef __attribute__((ext_vector_type(8))) unsigned short ushort8v;

#define BB 8
#define NN 2048
#define DD 768

__device__ __forceinline__ float b2f(unsigned short u) {
  union { unsigned int i; float f; } c; c.i = ((unsigned int)u) << 16; return c.f;
}
__device__ __forceinline__ unsigned short f2b(float f) {
  union { float f; unsigned int i; } c; c.f = f;
  unsigned int u = c.i;
  return (unsigned short)((u + 0x7fffu + ((u >> 16) & 1u)) >> 16);
}

// ---------------- LayerNorm: f32 [16384][768] -> bf16 ----------------
__global__ __launch_bounds__(256) void ln_kernel(const float* __restrict__ x,
                                                 const float* __restrict__ gamma,
                                                 const float* __restrict__ beta,
                                                 unsigned short* __restrict__ xb) {
  int row = blockIdx.x;
  const float* xr = x + (size_t)row * DD;
  int t = threadIdx.x;
  float a0 = xr[t], a1 = xr[t + 256], a2 = xr[t + 512];
  float s = a0 + a1 + a2;
  float q = a0 * a0 + a1 * a1 + a2 * a2;
  for (int o = 32; o > 0; o >>= 1) { s += __shfl_xor(s, o); q += __shfl_xor(q, o); }
  __shared__ float red[2][4];
  int w = t >> 6, lane = t & 63;
  if (lane == 0) { red[0][w] = s; red[1][w] = q; }
  __syncthreads();
  s = red[0][0] + red[0][1] + red[0][2] + red[0][3];
  q = red[1][0] + red[1][1] + red[1][2] + red[1][3];
  float mean = s * (1.0f / DD);
  float var = q * (1.0f / DD) - mean * mean;
  float inv = rsqrtf(var + 1e-5f);
  unsigned short* o0 = xb + (size_t)row * DD;
  o0[t]       = f2b((a0 - mean) * inv * gamma[t]       + beta[t]);
  o0[t + 256] = f2b((a1 - mean) * inv * gamma[t + 256] + beta[t + 256]);
  o0[t + 512] = f2b((a2 - mean) * inv * gamma[t + 512] + beta[t + 512]);
}

// ------------- Weight concat/convert: Wcat[2304][768] bf16, scale folded into Wq -------------
__global__ __launch_bounds__(256) void wconvert(const float* __restrict__ Wq,
                                                const float* __restrict__ Wk,
                                                const float* __restrict__ Wv,
                                                unsigned short* __restrict__ Wcat) {
  int i = blockIdx.x * 256 + threadIdx.x;
  const int dd = DD * DD;
  if (i >= 3 * dd) return;
  float v;
  if (i < dd)           v = Wq[i] * 0.03608439182435161f;   // 1/sqrt(768)
  else if (i < 2 * dd)  v = Wk[i - dd];
  else                  v = Wv[i - 2 * dd];
  Wcat[i] = f2b(v);
}

// ---------------- async global->LDS (16B per lane, wave-uniform LDS base) ----------------
__device__ __forceinline__ void gload_lds16(const void* g, void* l) {
  __builtin_amdgcn_global_load_lds(
      (const __attribute__((address_space(1))) void*)g,
      (__attribute__((address_space(3))) void*)(unsigned)(uintptr_t)l,
      16, 0, 0);
}

// LDS geometry (elements): buffer b at b*32768.
//   slot A-ks at  buf + ks*8192          (256 rows x 32 cols, 64B rows)
//   slot B-ks at  buf + 16384 + ks*8192
#define RDA(i0, ks, B)                                                                   \
  _Pragma("unroll")                                                                      \
  for (int i_ = 0; i_ < 4; ++i_)                                                         \
    aq[i_] = *(const bf16v8*)&smem[(B) + (ks) * 8192 + arow0 + ((i0) + i_) * 512 + kg8];
#define RDB(ks, B)                                                                       \
  _Pragma("unroll")                                                                      \
  for (int j_ = 0; j_ < NJ; ++j_)                                                        \
    bq[j_] = *(const bf16v8*)&smem[(B) + 16384 + (ks) * 8192 + brow0 + j_ * 512 + kg8];
#define MFQ(i0)                                                                          \
  _Pragma("unroll")                                                                      \
  for (int i_ = 0; i_ < 4; ++i_) {                                                       \
    _Pragma("unroll")                                                                    \
    for (int j_ = 0; j_ < NJ; ++j_)                                                      \
      acc[(i0) + i_][j_] = __builtin_amdgcn_mfma_f32_16x16x32_bf16(                      \
          aq[i_], bq[j_], acc[(i0) + i_][j_], 0, 0, 0);                                  \
  }
#define BARF asm volatile("s_barrier" ::: "memory")
#define VMC6 asm volatile("s_waitcnt vmcnt(6)" ::: "memory")
#define VMC0 asm volatile("s_waitcnt vmcnt(0)" ::: "memory")
#define P1   __builtin_amdgcn_s_setprio(1)
#define P0   __builtin_amdgcn_s_setprio(0)

// r6 per-tile schedule (single-tile kernels):
#define TILEK(KT, CURB, NXTB)                                                            \
  do {                                                                                   \
    RDA(0, 0, CURB); RDB(0, CURB);                                                       \
    if ((KT) + 1 < NT) stgA((KT) + 1, 1, (NXTB));                                        \
    BARF; P1; MFQ(0); P0; BARF;                                                          \
    RDA(4, 0, CURB);                                                                     \
    if ((KT) + 1 < NT) stgB((KT) + 1, 1, (NXTB));                                        \
    BARF; P1; MFQ(4); P0;                                                                \
    VMC6; BARF;                                                                          \
    RDA(0, 1, CURB); RDB(1, CURB);                                                       \
    if ((KT) + 2 < NT) stgA((KT) + 2, 0, (CURB));                                        \
    BARF; P1; MFQ(0); P0; BARF;                                                          \
    RDA(4, 1, CURB);                                                                     \
    if ((KT) + 2 < NT) stgB((KT) + 2, 0, (CURB));                                        \
    BARF; P1; MFQ(4); P0;                                                                \
    if ((KT) < NT - 2) { VMC6; } else { VMC0; }                                          \
    BARF;                                                                                \
  } while (0)

// Streamed variant: stage targets given explicitly (kk within segment + B base pointer).
#define TILEKS(CURB, NXTB, S1OK, S1KK, S2OK, S2KK, BB1, BB2, TAILV)                      \
  do {                                                                                   \
    RDA(0, 0, CURB); RDB(0, CURB);                                                       \
    if (S1OK) stgA((S1KK), 1, (NXTB));                                                   \
    BARF; P1; MFQ(0); P0; BARF;                                                          \
    RDA(4, 0, CURB);                                                                     \
    if (S1OK) stgB((BB1), (S1KK), 1, (NXTB));                                            \
    BARF; P1; MFQ(4); P0;                                                                \
    VMC6; BARF;                                                                          \
    RDA(0, 1, CURB); RDB(1, CURB);                                                       \
    if (S2OK) stgA((S2KK), 0, (CURB));                                                   \
    BARF; P1; MFQ(0); P0; BARF;                                                          \
    RDA(4, 1, CURB);                                                                     \
    if (S2OK) stgB((BB2), (S2KK), 0, (CURB));                                            \
    BARF; P1; MFQ(4); P0;                                                                \
    TAILV;                                                                               \
    BARF;                                                                                \
  } while (0)

// ---- r6 single-tile 256xBN GEMM (used for gemm1 / gemm2) ----
// MODE 1: bf16 store   MODE 2: f32 store
template <int MODE, int NJ>
__global__ __launch_bounds__(512, 2) void gemm256(
    const unsigned short* __restrict__ A, const unsigned short* __restrict__ Bm,
    unsigned short* __restrict__ Cq, unsigned short* __restrict__ Ck,
    unsigned short* __restrict__ Cv, float* __restrict__ Cf,
    int K, int lda, int ldb,
    long aStride, long bStride, long cStride) {
  extern __shared__ unsigned short smem[];      // 65536 elems = 131072 B
  const int BN = NJ * 64;

  const int t = threadIdx.x;
  int bx = blockIdx.x, by = blockIdx.y, bz = blockIdx.z;
  {  // bijective XCD swizzle (all grids are %8==0)
    const int gx = gridDim.x, gy = gridDim.y;
    const int nwg = gx * gy * (int)gridDim.z;
    int id = bx + gx * (by + gy * bz);
    int sw = (id & 7) * (nwg >> 3) + (id >> 3);
    bx = sw % gx; int r2 = sw / gx;
    by = r2 % gy; bz = r2 / gy;
  }
  const int n0 = bx * BN, m0 = by * 256;
  const unsigned short* Ab = A + (size_t)bz * aStride;
  const unsigned short* Bb = Bm + (size_t)bz * bStride;

  const int lane = t & 63;
  const int w = t >> 6;
  const int wm = w >> 2, wn = w & 3;
  const int frow = lane & 15;
  const int kg8 = (lane >> 4) * 8;
  const int arow0 = (wm * 128 + frow) * 32;
  const int brow0 = (wn * (NJ * 16) + frow) * 32;

  const int srow = t >> 2;
  const int scol8 = (t & 3) * 8;
  const unsigned short* Asrc = Ab + (size_t)(m0 + srow) * lda + scol8;
  const unsigned short* Bsrc = Bb + (size_t)(n0 + srow) * ldb + scol8;
  const int sdst = w * 512;

  auto stgA = [&](int kt, int ks, int bufb) {
    const unsigned short* s = Asrc + kt * 64 + ks * 32;
    gload_lds16(s, &smem[bufb + ks * 8192 + sdst]);
    gload_lds16(s + (size_t)128 * lda, &smem[bufb + ks * 8192 + 4096 + sdst]);
  };
  auto stgB = [&](int kt, int ks, int bufb) {
    const unsigned short* s = Bsrc + kt * 64 + ks * 32;
    gload_lds16(s, &smem[bufb + 16384 + ks * 8192 + sdst]);
    gload_lds16(s + (size_t)128 * ldb, &smem[bufb + 16384 + ks * 8192 + 4096 + sdst]);
  };

  f32x4 acc[8][NJ] = {};
  const int NT = K >> 6;
  bf16v8 aq[4], bq[NJ];

  stgA(0, 0, 0);     stgB(0, 0, 0);
  stgA(0, 1, 0);     stgB(0, 1, 0);
  stgA(1, 0, 32768); stgB(1, 0, 32768);
  asm volatile("s_waitcnt vmcnt(8)" ::: "memory");
  BARF;

  for (int ktp = 0; ktp < NT; ktp += 2) {
    TILEK(ktp, 0, 32768);
    TILEK(ktp + 1, 32768, 0);
  }

  const int r0 = (lane >> 4) * 4;
  const int c0 = lane & 15;
  const int mrowB = m0 + wm * 128 + r0;
  const int ncolB = n0 + wn * (NJ * 16) + c0;

  if (MODE == 1) {
    unsigned short* dst = Cq + (size_t)bz * cStride;
#pragma unroll
    for (int i = 0; i < 8; ++i)
#pragma unroll
      for (int j = 0; j < NJ; ++j)
#pragma unroll
        for (int r = 0; r < 4; ++r)
          dst[(size_t)(mrowB + i * 16 + r) * NN + (ncolB + j * 16)] = f2b(acc[i][j][r]);
  } else {
    float* dst = Cf + (size_t)bz * cStride;
#pragma unroll
    for (int i = 0; i < 8; ++i)
#pragma unroll
      for (int j = 0; j < NJ; ++j)
#pragma unroll
        for (int r = 0; r < 4; ++r)
          dst[(size_t)(mrowB + i * 16 + r) * DD + (ncolB + j * 16)] = acc[i][j][r];
  }
}

// ---- Streamed QKV GEMM (gemm0): 256 blocks, each runs SEGS=3 n-tiles (shared m0) as one
// continuous 36-K-tile pipelined stream. A pointer invariant; B base hops per segment with
// the boundary pair peeled (compile-time). Counted vmcnt never drains mid-stream; the
// per-segment epilogue (scalar stores) rides inside the vmcnt window.
template <int MODE, int NJ, int NTT, int SEGS>
__global__ __launch_bounds__(512, 2) void gemmS(
    const unsigned short* __restrict__ A, const unsigned short* __restrict__ Bm,
    unsigned short* __restrict__ Cq, unsigned short* __restrict__ Ck,
    unsigned short* __restrict__ Cv, float* __restrict__ Cf,
    int lda, int ldb) {
  extern __shared__ unsigned short smem[];      // 131072 B
  constexpr int NSTEP = NJ * 64;                // 192

  const int t = threadIdx.x;
  // XCD chunking: XCD (bid&7) owns 32 consecutive logical ids -> shared Wcat slice in L2
  const int lid = (blockIdx.x & 7) * 32 + (blockIdx.x >> 3);
  const int m0 = (lid & 63) * 256;
  const int n0base = (lid >> 6) * (SEGS * NSTEP);   // 0,576,1152,1728

  const int lane = t & 63;
  const int w = t >> 6;
  const int wm = w >> 2, wn = w & 3;
  const int frow = lane & 15;
  const int kg8 = (lane >> 4) * 8;
  const int arow0 = (wm * 128 + frow) * 32;
  const int brow0 = (wn * (NJ * 16) + frow) * 32;
  const int srow = t >> 2;
  const int scol8 = (t & 3) * 8;
  const int sdst = w * 512;

  const unsigned short* AsrcB = A + (size_t)(m0 + srow) * lda + scol8;
  const unsigned short* Bsrc0 = Bm + (size_t)(n0base + srow) * ldb + scol8;

  auto stgA = [&](int kk, int ks, int bufb) {
    const unsigned short* s = AsrcB + kk * 64 + ks * 32;
    gload_lds16(s, &smem[bufb + ks * 8192 + sdst]);
    gload_lds16(s + (size_t)128 * lda, &smem[bufb + ks * 8192 + 4096 + sdst]);
  };
  auto stgB = [&](const unsigned short* bb_, int kk, int ks, int bufb) {
    const unsigned short* s = bb_ + kk * 64 + ks * 32;
    gload_lds16(s, &smem[bufb + 16384 + ks * 8192 + sdst]);
    gload_lds16(s + (size_t)128 * ldb, &smem[bufb + 16384 + ks * 8192 + 4096 + sdst]);
  };

  f32x4 acc[8][NJ] = {};
  bf16v8 aq[4], bq[NJ];
  const int r0 = (lane >> 4) * 4;
  const int c0 = lane & 15;
  const int mrowB = m0 + wm * 128 + r0;

  // prologue (segment 0)
  stgA(0, 0, 0);     stgB(Bsrc0, 0, 0, 0);
  stgA(0, 1, 0);     stgB(Bsrc0, 0, 1, 0);
  stgA(1, 0, 32768); stgB(Bsrc0, 1, 0, 32768);
  asm volatile("s_waitcnt vmcnt(8)" ::: "memory");
  BARF;

#pragma unroll
  for (int s = 0; s < SEGS; ++s) {
    const unsigned short* Bcur = Bsrc0 + (size_t)s * NSTEP * ldb;
    const unsigned short* Bnxt = Bcur + (size_t)NSTEP * ldb;
    const bool hn = (s + 1 < SEGS);       // compile-time after unroll
    const bool lastSeg = !hn;

    // normal pairs: kt = 0..NTT-4 (stages stay within this segment)
    for (int ktp = 0; ktp < NTT - 2; ktp += 2) {
      TILEKS(0,     32768, true, ktp + 1, true, ktp + 2, Bcur, Bcur, VMC6);
      TILEKS(32768, 0,     true, ktp + 2, true, ktp + 3, Bcur, Bcur, VMC6);
    }
    // peeled boundary pair: kt = NTT-2 (buf 0), NTT-1 (buf 32768)
    if (lastSeg) {
      TILEKS(0,     32768, true, NTT - 1, false, 0, Bcur, Bnxt, VMC0);
      TILEKS(32768, 0,     false, 0,      false, 1, Bnxt, Bnxt, VMC0);
    } else {
      TILEKS(0,     32768, true, NTT - 1, true, 0, Bcur, Bnxt, VMC6);
      TILEKS(32768, 0,     true, 0,       true, 1, Bnxt, Bnxt, VMC6);
    }

    // ---- epilogue for segment tile s (scalar stores; pipeline stays loaded) ----
    {
      const int n0 = n0base + s * NSTEP;
      const int ncolB = n0 + wn * (NJ * 16) + c0;
      if (n0 < 1536) {  // Q or K (192-tiles never straddle the 768/1536 boundaries)
        unsigned short* dst = (n0 < 768) ? Cq : Ck;
        const int cb = (n0 < 768) ? 0 : 768;
#pragma unroll
        for (int i = 0; i < 8; ++i)
#pragma unroll
          for (int j = 0; j < NJ; ++j)
#pragma unroll
            for (int r = 0; r < 4; ++r)
              dst[(size_t)(mrowB + i * 16 + r) * DD + (ncolB + j * 16 - cb)] = f2b(acc[i][j][r]);
      } else {          // V: store transposed Vt[b][e][n]
#pragma unroll
        for (int i = 0; i < 8; ++i) {
          int row = mrowB + i * 16;
          int bb = row >> 11, nn = row & 2047;
#pragma unroll
          for (int j = 0; j < NJ; ++j) {
            int e = ncolB + j * 16 - 1536;
            ushort4v pk;
#pragma unroll
            for (int r = 0; r < 4; ++r) pk[r] = f2b(acc[i][j][r]);
            *(ushort4v*)&Cv[((size_t)(bb * DD + e)) * NN + nn] = pk;
          }
        }
      }
      if (hn) {
#pragma unroll
        for (int i = 0; i < 8; ++i)
#pragma unroll
          for (int j = 0; j < NJ; ++j) acc[i][j] = f32x4{0.f, 0.f, 0.f, 0.f};
      }
    }
  }
}

// ---------------- masked softmax, in-place on bf16 S rows ----------------
__global__ __launch_bounds__(256) void softmax_mask(unsigned short* __restrict__ S,
                                                    const int* __restrict__ mask) {
  int row = blockIdx.x;            // 0..16383
  int bb = row >> 11;
  unsigned short* sr = S + (size_t)row * NN;
  const int* mr = mask + bb * NN;
  int t = threadIdx.x;

  ushort8v pk = *(const ushort8v*)&sr[t * 8];
  float v[8];
  int msk[8];
#pragma unroll
  for (int j = 0; j < 8; ++j) msk[j] = mr[t * 8 + j];
  float mx = -1e30f;
#pragma unroll
  for (int j = 0; j < 8; ++j) {
    v[j] = b2f(pk[j]);
    if (!msk[j]) mx = fmaxf(mx, v[j]);
  }
  for (int o = 32; o > 0; o >>= 1) mx = fmaxf(mx, __shfl_xor(mx, o));
  __shared__ float redm[4], reds[4];
  int w = t >> 6, lane = t & 63;
  if (lane == 0) redm[w] = mx;
  __syncthreads();
  mx = fmaxf(fmaxf(redm[0], redm[1]), fmaxf(redm[2], redm[3]));

  float e[8];
  float sum = 0.f;
#pragma unroll
  for (int j = 0; j < 8; ++j) {
    e[j] = msk[j] ? 0.f : __expf(v[j] - mx);
    sum += e[j];
  }
  for (int o = 32; o > 0; o >>= 1) sum += __shfl_xor(sum, o);
  if (lane == 0) reds[w] = sum;
  __syncthreads();
  sum = reds[0] + reds[1] + reds[2] + reds[3];
  float inv = 1.0f / sum;

  ushort8v op;
#pragma unroll
  for (int j = 0; j < 8; ++j) op[j] = f2b(e[j] * inv);
  *(ushort8v*)&sr[t * 8] = op;
}

extern "C" void kernel_launch(void* const* d_in, const int* in_sizes, int n_in,
                              void* d_out, int out_size, void* d_ws, size_t ws_size,
                              hipStream_t stream) {
  const float* features = (const float*)d_in[0];
  const int* mask       = (const int*)d_in[1];
  const float* Wq       = (const float*)d_in[2];
  const float* Wk       = (const float*)d_in[3];
  const float* Wv       = (const float*)d_in[4];
  const float* gamma    = (const float*)d_in[5];
  const float* beta     = (const float*)d_in[6];
  float* out = (float*)d_out;

  char* ws = (char*)d_ws;
  size_t off = 0;
  auto alloc = [&](size_t bytes) {
    char* p = ws + off;
    off += (bytes + 255) & ~(size_t)255;
    return p;
  };
  unsigned short* Wcat = (unsigned short*)alloc((size_t)(2304 + 64) * DD * 2);
  unsigned short* Qb   = (unsigned short*)alloc((size_t)BB * NN * DD * 2);
  unsigned short* Kb   = (unsigned short*)alloc((size_t)BB * NN * DD * 2);
  unsigned short* Vt   = (unsigned short*)alloc(((size_t)BB * DD + 64) * NN * 2);
  // S (67 MB) aliases the X buffer region: X is dead once GEMM0 completes.
  char* last = alloc((size_t)BB * NN * NN * 2);
  unsigned short* Sb = (unsigned short*)last;
  unsigned short* Xb = (unsigned short*)last;  // first 25 MB of the S region

  (void)hipFuncSetAttribute(reinterpret_cast<const void*>(&gemmS<0, 3, 12, 3>),
                            hipFuncAttributeMaxDynamicSharedMemorySize, 131072);
  (void)hipFuncSetAttribute(reinterpret_cast<const void*>(&gemm256<1, 4>),
                            hipFuncAttributeMaxDynamicSharedMemorySize, 131072);
  (void)hipFuncSetAttribute(reinterpret_cast<const void*>(&gemm256<2, 3>),
                            hipFuncAttributeMaxDynamicSharedMemorySize, 131072);

  ln_kernel<<<BB * NN, 256, 0, stream>>>(features, gamma, beta, Xb);
  wconvert<<<(3 * DD * DD + 255) / 256, 256, 0, stream>>>(Wq, Wk, Wv, Wcat);

  // QKV projection: [16384,768] x [2304,768]^T ; 256 blocks x 3 streamed n-tiles
  gemmS<0, 3, 12, 3><<<256, 512, 131072, stream>>>(
      Xb, Wcat, Qb, Kb, Vt, nullptr, DD, DD);

  // Scores: per batch [2048,768] x [2048,768]^T -> S bf16 ; 8x8x8 = 512 blocks (r6)
  gemm256<1, 4><<<dim3(NN / 256, NN / 256, BB), 512, 131072, stream>>>(
      Qb, Kb, Sb, nullptr, nullptr, nullptr, DD, DD, DD,
      (long)NN * DD, (long)NN * DD, (long)NN * NN);

  softmax_mask<<<BB * NN, 256, 0, stream>>>(Sb, mask);

  // Context: per batch P[2048,2048] x Vt[768,2048]^T -> f32 out ; 4x8x8 = 256 blocks (r6)
  gemm256<2, 3><<<dim3(DD / 192, NN / 256, BB), 512, 131072, stream>>>(
      Sb, Vt, nullptr, nullptr, nullptr, out, NN, NN, NN,
      (long)NN * NN, (long)DD * NN, (long)NN * DD);
}

// Round 11
// 247.633 us; speedup vs baseline: 1.1203x; 1.0203x over previous
//
#include <hip/hip_runtime.h>
#include <hip/hip_bf16.h>
#include <cstdint>

typedef __attribute__((ext_vector_type(8))) __bf16 bf16v8;
typedef __attribute__((ext_vector_type(4))) float f32x4;
typedef __attribute__((ext_vector_type(4))) unsigned short ushort4v;
typedef __attribute__((ext_vector_type(8))) unsigned short ushort8v;

#define BB 8
#define NN 2048
#define DD 768

__device__ __forceinline__ float b2f(unsigned short u) {
  union { unsigned int i; float f; } c; c.i = ((unsigned int)u) << 16; return c.f;
}
__device__ __forceinline__ unsigned short f2b(float f) {
  union { float f; unsigned int i; } c; c.f = f;
  unsigned int u = c.i;
  return (unsigned short)((u + 0x7fffu + ((u >> 16) & 1u)) >> 16);
}

// ---------------- LayerNorm: f32 [16384][768] -> bf16 ----------------
__global__ __launch_bounds__(256) void ln_kernel(const float* __restrict__ x,
                                                 const float* __restrict__ gamma,
                                                 const float* __restrict__ beta,
                                                 unsigned short* __restrict__ xb) {
  int row = blockIdx.x;
  const float* xr = x + (size_t)row * DD;
  int t = threadIdx.x;
  float a0 = xr[t], a1 = xr[t + 256], a2 = xr[t + 512];
  float s = a0 + a1 + a2;
  float q = a0 * a0 + a1 * a1 + a2 * a2;
  for (int o = 32; o > 0; o >>= 1) { s += __shfl_xor(s, o); q += __shfl_xor(q, o); }
  __shared__ float red[2][4];
  int w = t >> 6, lane = t & 63;
  if (lane == 0) { red[0][w] = s; red[1][w] = q; }
  __syncthreads();
  s = red[0][0] + red[0][1] + red[0][2] + red[0][3];
  q = red[1][0] + red[1][1] + red[1][2] + red[1][3];
  float mean = s * (1.0f / DD);
  float var = q * (1.0f / DD) - mean * mean;
  float inv = rsqrtf(var + 1e-5f);
  unsigned short* o0 = xb + (size_t)row * DD;
  o0[t]       = f2b((a0 - mean) * inv * gamma[t]       + beta[t]);
  o0[t + 256] = f2b((a1 - mean) * inv * gamma[t + 256] + beta[t + 256]);
  o0[t + 512] = f2b((a2 - mean) * inv * gamma[t + 512] + beta[t + 512]);
}

// ------------- Weight concat/convert: Wcat[2304][768] bf16, scale folded into Wq -------------
__global__ __launch_bounds__(256) void wconvert(const float* __restrict__ Wq,
                                                const float* __restrict__ Wk,
                                                const float* __restrict__ Wv,
                                                unsigned short* __restrict__ Wcat) {
  int i = blockIdx.x * 256 + threadIdx.x;
  const int dd = DD * DD;
  if (i >= 3 * dd) return;
  float v;
  if (i < dd)           v = Wq[i] * 0.03608439182435161f;   // 1/sqrt(768)
  else if (i < 2 * dd)  v = Wk[i - dd];
  else                  v = Wv[i - 2 * dd];
  Wcat[i] = f2b(v);
}

// ------------- mask prefix scan: pfx[b*NN+n] = # unmasked before n; ncnt[b] = total -------------
__global__ __launch_bounds__(256) void mask_scan(const int* __restrict__ mask,
                                                 int* __restrict__ pfx,
                                                 int* __restrict__ ncnt) {
  int b = blockIdx.x;
  const int* mr = mask + b * NN;
  int t = threadIdx.x;
  int v[8]; int s = 0;
#pragma unroll
  for (int j = 0; j < 8; ++j) { v[j] = (mr[t * 8 + j] == 0) ? 1 : 0; s += v[j]; }
  int lane = t & 63, w = t >> 6;
  int x = s;
  for (int o = 1; o < 64; o <<= 1) { int y = __shfl_up(x, o); if (lane >= o) x += y; }
  __shared__ int wsum[4];
  if (lane == 63) wsum[w] = x;
  __syncthreads();
  int base = 0;
#pragma unroll
  for (int i = 0; i < 4; ++i) if (i < w) base += wsum[i];
  int run = base + x - s;                 // exclusive prefix at this thread's first element
#pragma unroll
  for (int j = 0; j < 8; ++j) { pfx[b * NN + t * 8 + j] = run; run += v[j]; }
  if (t == 255) ncnt[b] = base + x;
}

// ------------- zero pad regions: K_c rows [nc,r256), Vt_c cols [nc,r128) -------------
__global__ __launch_bounds__(256) void padzero(const int* __restrict__ ncnt,
                                               unsigned short* __restrict__ Kc,
                                               unsigned short* __restrict__ Vtc) {
  int b = blockIdx.x & 7, sub = blockIdx.x >> 3;   // 8 slices per batch
  int nc = ncnt[b];
  int r256 = (nc + 255) & ~255, r128 = (nc + 127) & ~127;
  int cnt1 = (r256 - nc) * DD;
  unsigned short* k0 = Kc + ((size_t)b * NN + nc) * DD;
  for (int i = sub * 256 + threadIdx.x; i < cnt1; i += 2048) k0[i] = 0;
  int wcols = r128 - nc;
  if (wcols > 0) {
    int cnt2 = DD * wcols;
    for (int i = sub * 256 + threadIdx.x; i < cnt2; i += 2048) {
      int e = i / wcols, c = i - e * wcols;
      Vtc[((size_t)b * DD + e) * NN + nc + c] = 0;
    }
  }
}

// ---------------- async global->LDS (16B per lane, wave-uniform LDS base) ----------------
__device__ __forceinline__ void gload_lds16(const void* g, void* l) {
  __builtin_amdgcn_global_load_lds(
      (const __attribute__((address_space(1))) void*)g,
      (__attribute__((address_space(3))) void*)(unsigned)(uintptr_t)l,
      16, 0, 0);
}

// LDS geometry (elements): buffer b at b*32768.
//   slot A-ks at  buf + ks*8192          (256 rows x 32 cols, 64B rows)
//   slot B-ks at  buf + 16384 + ks*8192
#define RDA(i0, ks, B)                                                                   \
  _Pragma("unroll")                                                                      \
  for (int i_ = 0; i_ < 4; ++i_)                                                         \
    aq[i_] = *(const bf16v8*)&smem[(B) + (ks) * 8192 + arow0 + ((i0) + i_) * 512 + kg8];
#define RDB(ks, B)                                                                       \
  _Pragma("unroll")                                                                      \
  for (int j_ = 0; j_ < NJ; ++j_)                                                        \
    bq[j_] = *(const bf16v8*)&smem[(B) + 16384 + (ks) * 8192 + brow0 + j_ * 512 + kg8];
#define MFQ(i0)                                                                          \
  _Pragma("unroll")                                                                      \
  for (int i_ = 0; i_ < 4; ++i_) {                                                       \
    _Pragma("unroll")                                                                    \
    for (int j_ = 0; j_ < NJ; ++j_)                                                      \
      acc[(i0) + i_][j_] = __builtin_amdgcn_mfma_f32_16x16x32_bf16(                      \
          aq[i_], bq[j_], acc[(i0) + i_][j_], 0, 0, 0);                                  \
  }
#define BARF asm volatile("s_barrier" ::: "memory")
#define VMC6 asm volatile("s_waitcnt vmcnt(6)" ::: "memory")
#define VMC0 asm volatile("s_waitcnt vmcnt(0)" ::: "memory")
#define P1   __builtin_amdgcn_s_setprio(1)
#define P0   __builtin_amdgcn_s_setprio(0)

// r6 per-tile schedule:
#define TILEK(KT, CURB, NXTB)                                                            \
  do {                                                                                   \
    RDA(0, 0, CURB); RDB(0, CURB);                                                       \
    if ((KT) + 1 < NT) stgA((KT) + 1, 1, (NXTB));                                        \
    BARF; P1; MFQ(0); P0; BARF;                                                          \
    RDA(4, 0, CURB);                                                                     \
    if ((KT) + 1 < NT) stgB((KT) + 1, 1, (NXTB));                                        \
    BARF; P1; MFQ(4); P0;                                                                \
    VMC6; BARF;                                                                          \
    RDA(0, 1, CURB); RDB(1, CURB);                                                       \
    if ((KT) + 2 < NT) stgA((KT) + 2, 0, (CURB));                                        \
    BARF; P1; MFQ(0); P0; BARF;                                                          \
    RDA(4, 1, CURB);                                                                     \
    if ((KT) + 2 < NT) stgB((KT) + 2, 0, (CURB));                                        \
    BARF; P1; MFQ(4); P0;                                                                \
    if ((KT) < NT - 2) { VMC6; } else { VMC0; }                                          \
    BARF;                                                                                \
  } while (0)

// ---- 256xBN pipelined bf16 GEMM, C = A * B^T (r6 structure + compaction hooks) ----
// MODE 0: QKV epilogue -- Q direct; K rows compacted via pfx; V cols compacted (Vt_c)
// MODE 1: bf16 store, early-exit tiles beyond roundup(ncnt,256)
// MODE 2: f32 store, runtime NT = roundup(ncnt,128)/64 per batch
template <int MODE, int NJ>
__global__ __launch_bounds__(512, 2) void gemm256(
    const unsigned short* __restrict__ A, const unsigned short* __restrict__ Bm,
    unsigned short* __restrict__ Cq, unsigned short* __restrict__ Ck,
    unsigned short* __restrict__ Cv, float* __restrict__ Cf,
    int K, int lda, int ldb,
    long aStride, long bStride, long cStride,
    const int* __restrict__ pfx, const int* __restrict__ msk,
    const int* __restrict__ ncnt) {
  extern __shared__ unsigned short smem[];      // 65536 elems = 131072 B
  const int BN = NJ * 64;

  const int t = threadIdx.x;
  int bx = blockIdx.x, by = blockIdx.y, bz = blockIdx.z;
  {  // bijective XCD swizzle (all grids are %8==0)
    const int gx = gridDim.x, gy = gridDim.y;
    const int nwg = gx * gy * (int)gridDim.z;
    int id = bx + gx * (by + gy * bz);
    int sw = (id & 7) * (nwg >> 3) + (id >> 3);
    bx = sw % gx; int r2 = sw / gx;
    by = r2 % gy; bz = r2 / gy;
  }
  const int n0 = bx * BN, m0 = by * 256;

  if (MODE == 1) {  // compacted-K scores: skip tiles entirely beyond the active bound
    const int bound = (ncnt[bz] + 255) & ~255;
    if (n0 >= bound) return;
  }
  const int NT = (MODE == 2) ? (((ncnt[bz] + 127) >> 7) << 1) : (K >> 6);

  const unsigned short* Ab = A + (size_t)bz * aStride;
  const unsigned short* Bb = Bm + (size_t)bz * bStride;

  const int lane = t & 63;
  const int w = t >> 6;
  const int wm = w >> 2, wn = w & 3;
  const int frow = lane & 15;
  const int kg8 = (lane >> 4) * 8;
  const int arow0 = (wm * 128 + frow) * 32;
  const int brow0 = (wn * (NJ * 16) + frow) * 32;

  const int srow = t >> 2;
  const int scol8 = (t & 3) * 8;
  const unsigned short* Asrc = Ab + (size_t)(m0 + srow) * lda + scol8;
  const unsigned short* Bsrc = Bb + (size_t)(n0 + srow) * ldb + scol8;
  const int sdst = w * 512;

  auto stgA = [&](int kt, int ks, int bufb) {
    const unsigned short* s = Asrc + kt * 64 + ks * 32;
    gload_lds16(s, &smem[bufb + ks * 8192 + sdst]);
    gload_lds16(s + (size_t)128 * lda, &smem[bufb + ks * 8192 + 4096 + sdst]);
  };
  auto stgB = [&](int kt, int ks, int bufb) {
    const unsigned short* s = Bsrc + kt * 64 + ks * 32;
    gload_lds16(s, &smem[bufb + 16384 + ks * 8192 + sdst]);
    gload_lds16(s + (size_t)128 * ldb, &smem[bufb + 16384 + ks * 8192 + 4096 + sdst]);
  };

  f32x4 acc[8][NJ] = {};
  bf16v8 aq[4], bq[NJ];

  stgA(0, 0, 0);     stgB(0, 0, 0);
  stgA(0, 1, 0);     stgB(0, 1, 0);
  stgA(1, 0, 32768); stgB(1, 0, 32768);
  asm volatile("s_waitcnt vmcnt(8)" ::: "memory");
  BARF;

  for (int ktp = 0; ktp < NT; ktp += 2) {
    TILEK(ktp, 0, 32768);
    TILEK(ktp + 1, 32768, 0);
  }

  // Epilogue. C/D layout: col = lane&15, row = (lane>>4)*4 + reg  [HW-verified]
  const int r0 = (lane >> 4) * 4;
  const int c0 = lane & 15;
  const int mrowB = m0 + wm * 128 + r0;
  const int ncolB = n0 + wn * (NJ * 16) + c0;

  if (MODE == 0) {
    if (n0 < 768) {            // Q: direct full store
#pragma unroll
      for (int i = 0; i < 8; ++i)
#pragma unroll
        for (int j = 0; j < NJ; ++j)
#pragma unroll
          for (int r = 0; r < 4; ++r)
            Cq[(size_t)(mrowB + i * 16 + r) * DD + (ncolB + j * 16)] = f2b(acc[i][j][r]);
    } else if (n0 < 1536) {    // K: row-compacted store into K_c[b][pfx[row]][col]
#pragma unroll
      for (int i = 0; i < 8; ++i)
#pragma unroll
        for (int r = 0; r < 4; ++r) {
          const int row = mrowB + i * 16 + r;      // global token
          if (msk[row] == 0) {
            const int bbb = row >> 11;
            unsigned short* dst = Ck + ((size_t)bbb * NN + pfx[row]) * DD + (ncolB - 768);
#pragma unroll
            for (int j = 0; j < NJ; ++j) dst[j * 16] = f2b(acc[i][j][r]);
          }
        }
    } else {                   // V: col-compacted transposed store Vt_c[b][e][pfx[tok]]
#pragma unroll
      for (int i = 0; i < 8; ++i) {
        const int row0 = mrowB + i * 16;
        const int bbb = row0 >> 11;
#pragma unroll
        for (int r = 0; r < 4; ++r) {
          const int tok = row0 + r;
          if (msk[tok] == 0) {
            const int cc = pfx[tok];
#pragma unroll
            for (int j = 0; j < NJ; ++j) {
              const int e = ncolB + j * 16 - 1536;
              Cv[((size_t)bbb * DD + e) * NN + cc] = f2b(acc[i][j][r]);
            }
          }
        }
      }
    }
  } else if (MODE == 1) {
    unsigned short* dst = Cq + (size_t)bz * cStride;
#pragma unroll
    for (int i = 0; i < 8; ++i)
#pragma unroll
      for (int j = 0; j < NJ; ++j)
#pragma unroll
        for (int r = 0; r < 4; ++r)
          dst[(size_t)(mrowB + i * 16 + r) * NN + (ncolB + j * 16)] = f2b(acc[i][j][r]);
  } else {
    float* dst = Cf + (size_t)bz * cStride;
#pragma unroll
    for (int i = 0; i < 8; ++i)
#pragma unroll
      for (int j = 0; j < NJ; ++j)
#pragma unroll
        for (int r = 0; r < 4; ++r)
          dst[(size_t)(mrowB + i * 16 + r) * DD + (ncolB + j * 16)] = acc[i][j][r];
  }
}

// ---------------- compacted softmax: cols [0,nc) valid, zero-fill [nc,r128), skip rest ----------------
__global__ __launch_bounds__(256) void softmax_c(unsigned short* __restrict__ S,
                                                 const int* __restrict__ ncnt) {
  int row = blockIdx.x;            // 0..16383
  int bb = row >> 11;
  const int nc = ncnt[bb];
  const int p128 = (nc + 127) & ~127;
  unsigned short* sr = S + (size_t)row * NN;
  int t = threadIdx.x;
  const int cbase = t * 8;

  float v[8];
  const bool anyload = cbase < nc;
  ushort8v pk;
  if (anyload) pk = *(const ushort8v*)&sr[cbase];
  float mx = -1e30f;
#pragma unroll
  for (int j = 0; j < 8; ++j) {
    v[j] = anyload ? b2f(pk[j]) : 0.f;
    if (cbase + j < nc) mx = fmaxf(mx, v[j]);
  }
  for (int o = 32; o > 0; o >>= 1) mx = fmaxf(mx, __shfl_xor(mx, o));
  __shared__ float redm[4], reds[4];
  int w = t >> 6, lane = t & 63;
  if (lane == 0) redm[w] = mx;
  __syncthreads();
  mx = fmaxf(fmaxf(redm[0], redm[1]), fmaxf(redm[2], redm[3]));

  float e[8];
  float sum = 0.f;
#pragma unroll
  for (int j = 0; j < 8; ++j) {
    e[j] = (cbase + j < nc) ? __expf(v[j] - mx) : 0.f;
    sum += e[j];
  }
  for (int o = 32; o > 0; o >>= 1) sum += __shfl_xor(sum, o);
  if (lane == 0) reds[w] = sum;
  __syncthreads();
  sum = reds[0] + reds[1] + reds[2] + reds[3];
  float inv = 1.0f / sum;

  if (cbase < p128) {
    ushort8v op;
#pragma unroll
    for (int j = 0; j < 8; ++j) op[j] = f2b(e[j] * inv);
    *(ushort8v*)&sr[cbase] = op;
  }
}

extern "C" void kernel_launch(void* const* d_in, const int* in_sizes, int n_in,
                              void* d_out, int out_size, void* d_ws, size_t ws_size,
                              hipStream_t stream) {
  const float* features = (const float*)d_in[0];
  const int* mask       = (const int*)d_in[1];
  const float* Wq       = (const float*)d_in[2];
  const float* Wk       = (const float*)d_in[3];
  const float* Wv       = (const float*)d_in[4];
  const float* gamma    = (const float*)d_in[5];
  const float* beta     = (const float*)d_in[6];
  float* out = (float*)d_out;

  char* ws = (char*)d_ws;
  size_t off = 0;
  auto alloc = [&](size_t bytes) {
    char* p = ws + off;
    off += (bytes + 255) & ~(size_t)255;
    return p;
  };
  unsigned short* Wcat = (unsigned short*)alloc((size_t)(2304 + 64) * DD * 2);
  unsigned short* Qb   = (unsigned short*)alloc((size_t)BB * NN * DD * 2);
  unsigned short* Kc   = (unsigned short*)alloc((size_t)BB * NN * DD * 2);   // compacted K
  unsigned short* Vtc  = (unsigned short*)alloc(((size_t)BB * DD + 64) * NN * 2);  // compacted Vt
  int* pfx  = (int*)alloc((size_t)BB * NN * 4);
  int* ncnt = (int*)alloc(64 * 4);
  // S (67 MB) aliases the X buffer region: X is dead once GEMM0 completes.
  char* last = alloc((size_t)BB * NN * NN * 2);
  unsigned short* Sb = (unsigned short*)last;
  unsigned short* Xb = (unsigned short*)last;  // first 25 MB of the S region

  (void)hipFuncSetAttribute(reinterpret_cast<const void*>(&gemm256<0, 3>),
                            hipFuncAttributeMaxDynamicSharedMemorySize, 131072);
  (void)hipFuncSetAttribute(reinterpret_cast<const void*>(&gemm256<1, 4>),
                            hipFuncAttributeMaxDynamicSharedMemorySize, 131072);
  (void)hipFuncSetAttribute(reinterpret_cast<const void*>(&gemm256<2, 3>),
                            hipFuncAttributeMaxDynamicSharedMemorySize, 131072);

  ln_kernel<<<BB * NN, 256, 0, stream>>>(features, gamma, beta, Xb);
  wconvert<<<(3 * DD * DD + 255) / 256, 256, 0, stream>>>(Wq, Wk, Wv, Wcat);
  mask_scan<<<BB, 256, 0, stream>>>(mask, pfx, ncnt);

  // QKV projection: [16384,768] x [2304,768]^T ; 12x64 grid (r6 champion config)
  gemm256<0, 3><<<dim3(2304 / 192, (BB * NN) / 256, 1), 512, 131072, stream>>>(
      Xb, Wcat, Qb, Kc, Vtc, nullptr, DD, DD, DD, 0, 0, 0, pfx, mask, ncnt);

  padzero<<<64, 256, 0, stream>>>(ncnt, Kc, Vtc);

  // Scores (compacted keys): per batch [2048,768] x [nc,768]^T -> S bf16 ; inactive tiles exit
  gemm256<1, 4><<<dim3(NN / 256, NN / 256, BB), 512, 131072, stream>>>(
      Qb, Kc, Sb, nullptr, nullptr, nullptr, DD, DD, DD,
      (long)NN * DD, (long)NN * DD, (long)NN * NN, nullptr, nullptr, ncnt);

  softmax_c<<<BB * NN, 256, 0, stream>>>(Sb, ncnt);

  // Context (compacted K-dim): per batch P[2048,r128] x Vt_c[768,r128]^T -> f32 out
  gemm256<2, 3><<<dim3(DD / 192, NN / 256, BB), 512, 131072, stream>>>(
      Sb, Vtc, nullptr, nullptr, nullptr, out, NN, NN, NN,
      (long)NN * NN, (long)DD * NN, (long)NN * DD, nullptr, nullptr, ncnt);
}

// Round 13
// 225.065 us; speedup vs baseline: 1.2326x; 1.1003x over previous
//
#include <hip/hip_runtime.h>
#include <hip/hip_bf16.h>
#include <cstdint>

typedef __attribute__((ext_vector_type(8))) __bf16 bf16v8;
typedef __attribute__((ext_vector_type(4))) float f32x4;
typedef __attribute__((ext_vector_type(4))) unsigned short ushort4v;
typedef __attribute__((ext_vector_type(8))) unsigned short ushort8v;

#define BB 8
#define NN 2048
#define DD 768

__device__ __forceinline__ float b2f(unsigned short u) {
  union { unsigned int i; float f; } c; c.i = ((unsigned int)u) << 16; return c.f;
}
__device__ __forceinline__ unsigned short f2b(float f) {
  union { float f; unsigned int i; } c; c.f = f;
  unsigned int u = c.i;
  return (unsigned short)((u + 0x7fffu + ((u >> 16) & 1u)) >> 16);
}

// ---------------- LayerNorm: f32 [16384][768] -> bf16 ----------------
__global__ __launch_bounds__(256) void ln_kernel(const float* __restrict__ x,
                                                 const float* __restrict__ gamma,
                                                 const float* __restrict__ beta,
                                                 unsigned short* __restrict__ xb) {
  int row = blockIdx.x;
  const float* xr = x + (size_t)row * DD;
  int t = threadIdx.x;
  float a0 = xr[t], a1 = xr[t + 256], a2 = xr[t + 512];
  float s = a0 + a1 + a2;
  float q = a0 * a0 + a1 * a1 + a2 * a2;
  for (int o = 32; o > 0; o >>= 1) { s += __shfl_xor(s, o); q += __shfl_xor(q, o); }
  __shared__ float red[2][4];
  int w = t >> 6, lane = t & 63;
  if (lane == 0) { red[0][w] = s; red[1][w] = q; }
  __syncthreads();
  s = red[0][0] + red[0][1] + red[0][2] + red[0][3];
  q = red[1][0] + red[1][1] + red[1][2] + red[1][3];
  float mean = s * (1.0f / DD);
  float var = q * (1.0f / DD) - mean * mean;
  float inv = rsqrtf(var + 1e-5f);
  unsigned short* o0 = xb + (size_t)row * DD;
  o0[t]       = f2b((a0 - mean) * inv * gamma[t]       + beta[t]);
  o0[t + 256] = f2b((a1 - mean) * inv * gamma[t + 256] + beta[t + 256]);
  o0[t + 512] = f2b((a2 - mean) * inv * gamma[t + 512] + beta[t + 512]);
}

// ------------- Weight concat/convert: Wcat[2304][768] bf16, scale folded into Wq -------------
__global__ __launch_bounds__(256) void wconvert(const float* __restrict__ Wq,
                                                const float* __restrict__ Wk,
                                                const float* __restrict__ Wv,
                                                unsigned short* __restrict__ Wcat) {
  int i = blockIdx.x * 256 + threadIdx.x;
  const int dd = DD * DD;
  if (i >= 3 * dd) return;
  float v;
  if (i < dd)           v = Wq[i] * 0.03608439182435161f;   // 1/sqrt(768)
  else if (i < 2 * dd)  v = Wk[i - dd];
  else                  v = Wv[i - 2 * dd];
  Wcat[i] = f2b(v);
}

// ------------- mask scan: kidx[b][c] = original index of c-th unmasked key (0 beyond); ncnt[b] -------------
__global__ __launch_bounds__(256) void mask_scan(const int* __restrict__ mask,
                                                 int* __restrict__ kidx,
                                                 int* __restrict__ ncnt) {
  int b = blockIdx.x;
  const int* mr = mask + b * NN;
  int t = threadIdx.x;
#pragma unroll
  for (int j = 0; j < 8; ++j) kidx[b * NN + t * 8 + j] = 0;
  int v[8]; int s = 0;
#pragma unroll
  for (int j = 0; j < 8; ++j) { v[j] = (mr[t * 8 + j] == 0) ? 1 : 0; s += v[j]; }
  int lane = t & 63, w = t >> 6;
  int x = s;
  for (int o = 1; o < 64; o <<= 1) { int y = __shfl_up(x, o); if (lane >= o) x += y; }
  __shared__ int wsum[4];
  if (lane == 63) wsum[w] = x;
  __syncthreads();
  int base = 0;
#pragma unroll
  for (int i = 0; i < 4; ++i) if (i < w) base += wsum[i];
  int run = base + x - s;                 // exclusive prefix at this thread's first element
#pragma unroll
  for (int j = 0; j < 8; ++j) { if (v[j]) kidx[b * NN + run] = t * 8 + j; run += v[j]; }
  if (t == 255) ncnt[b] = base + x;
}

// ------------- Vt column gather: Vtc[b][e][c] = Vt[b][e][kidx[c]] (c<nc), 0 for [nc,r128) -------------
__global__ __launch_bounds__(256) void vtc_gather(const unsigned short* __restrict__ Vt,
                                                  const int* __restrict__ kidx,
                                                  const int* __restrict__ ncnt,
                                                  unsigned short* __restrict__ Vtc) {
  int be = blockIdx.x;              // b*DD + e
  int b = be / DD;
  int nc = ncnt[b];
  int r128 = (nc + 127) & ~127;
  const unsigned short* src = Vt + (size_t)be * NN;
  unsigned short* dst = Vtc + (size_t)be * NN;
  const int* kx = kidx + b * NN;
  for (int c = threadIdx.x; c < r128; c += 256)
    dst[c] = (c < nc) ? src[kx[c]] : (unsigned short)0;
}

// ---------------- async global->LDS (16B per lane, wave-uniform LDS base) ----------------
__device__ __forceinline__ void gload_lds16(const void* g, void* l) {
  __builtin_amdgcn_global_load_lds(
      (const __attribute__((address_space(1))) void*)g,
      (__attribute__((address_space(3))) void*)(unsigned)(uintptr_t)l,
      16, 0, 0);
}

// LDS geometry (elements): buffer b at b*32768.
//   slot A-ks at  buf + ks*8192          (256 rows x 32 cols, 64B rows)
//   slot B-ks at  buf + 16384 + ks*8192
#define RDA(i0, ks, B)                                                                   \
  _Pragma("unroll")                                                                      \
  for (int i_ = 0; i_ < 4; ++i_)                                                         \
    aq[i_] = *(const bf16v8*)&smem[(B) + (ks) * 8192 + arow0 + ((i0) + i_) * 512 + kg8];
#define RDB(ks, B)                                                                       \
  _Pragma("unroll")                                                                      \
  for (int j_ = 0; j_ < NJ; ++j_)                                                        \
    bq[j_] = *(const bf16v8*)&smem[(B) + 16384 + (ks) * 8192 + brow0 + j_ * 512 + kg8];
#define MFQ(i0)                                                                          \
  _Pragma("unroll")                                                                      \
  for (int i_ = 0; i_ < 4; ++i_) {                                                       \
    _Pragma("unroll")                                                                    \
    for (int j_ = 0; j_ < NJ; ++j_)                                                      \
      acc[(i0) + i_][j_] = __builtin_amdgcn_mfma_f32_16x16x32_bf16(                      \
          aq[i_], bq[j_], acc[(i0) + i_][j_], 0, 0, 0);                                  \
  }
#define BARF asm volatile("s_barrier" ::: "memory")
#define VMC6 asm volatile("s_waitcnt vmcnt(6)" ::: "memory")
#define VMC0 asm volatile("s_waitcnt vmcnt(0)" ::: "memory")
#define P1   __builtin_amdgcn_s_setprio(1)
#define P0   __builtin_amdgcn_s_setprio(0)

// r6 per-tile schedule:
#define TILEK(KT, CURB, NXTB)                                                            \
  do {                                                                                   \
    RDA(0, 0, CURB); RDB(0, CURB);                                                       \
    if ((KT) + 1 < NT) stgA((KT) + 1, 1, (NXTB));                                        \
    BARF; P1; MFQ(0); P0; BARF;                                                          \
    RDA(4, 0, CURB);                                                                     \
    if ((KT) + 1 < NT) stgB((KT) + 1, 1, (NXTB));                                        \
    BARF; P1; MFQ(4); P0;                                                                \
    VMC6; BARF;                                                                          \
    RDA(0, 1, CURB); RDB(1, CURB);                                                       \
    if ((KT) + 2 < NT) stgA((KT) + 2, 0, (CURB));                                        \
    BARF; P1; MFQ(0); P0; BARF;                                                          \
    RDA(4, 1, CURB);                                                                     \
    if ((KT) + 2 < NT) stgB((KT) + 2, 0, (CURB));                                        \
    BARF; P1; MFQ(4); P0;                                                                \
    if ((KT) < NT - 2) { VMC6; } else { VMC0; }                                          \
    BARF;                                                                                \
  } while (0)

// ---- 256xBN pipelined bf16 GEMM (r6 structure), C = A * B^T ----
// MODE 0: QKV epilogue (r6: Q/K direct, V -> Vt vectorized transposed store)
// MODE 2: f32 store with runtime NT = 2*ceil(ncnt/128) per batch
template <int MODE, int NJ>
__global__ __launch_bounds__(512, 2) void gemm256(
    const unsigned short* __restrict__ A, const unsigned short* __restrict__ Bm,
    unsigned short* __restrict__ Cq, unsigned short* __restrict__ Ck,
    unsigned short* __restrict__ Cv, float* __restrict__ Cf,
    int K, int lda, int ldb,
    long aStride, long bStride, long cStride,
    const int* __restrict__ ncnt) {
  extern __shared__ unsigned short smem[];      // 65536 elems = 131072 B
  const int BN = NJ * 64;

  const int t = threadIdx.x;
  int bx = blockIdx.x, by = blockIdx.y, bz = blockIdx.z;
  {  // bijective XCD swizzle (all grids are %8==0)
    const int gx = gridDim.x, gy = gridDim.y;
    const int nwg = gx * gy * (int)gridDim.z;
    int id = bx + gx * (by + gy * bz);
    int sw = (id & 7) * (nwg >> 3) + (id >> 3);
    bx = sw % gx; int r2 = sw / gx;
    by = r2 % gy; bz = r2 / gy;
  }
  const int n0 = bx * BN, m0 = by * 256;
  const int NT = (MODE == 2) ? (((ncnt[bz] + 127) >> 7) << 1) : (K >> 6);

  const unsigned short* Ab = A + (size_t)bz * aStride;
  const unsigned short* Bb = Bm + (size_t)bz * bStride;

  const int lane = t & 63;
  const int w = t >> 6;
  const int wm = w >> 2, wn = w & 3;
  const int frow = lane & 15;
  const int kg8 = (lane >> 4) * 8;
  const int arow0 = (wm * 128 + frow) * 32;
  const int brow0 = (wn * (NJ * 16) + frow) * 32;

  const int srow = t >> 2;
  const int scol8 = (t & 3) * 8;
  const unsigned short* Asrc = Ab + (size_t)(m0 + srow) * lda + scol8;
  const unsigned short* Bsrc = Bb + (size_t)(n0 + srow) * ldb + scol8;
  const int sdst = w * 512;

  auto stgA = [&](int kt, int ks, int bufb) {
    const unsigned short* s = Asrc + kt * 64 + ks * 32;
    gload_lds16(s, &smem[bufb + ks * 8192 + sdst]);
    gload_lds16(s + (size_t)128 * lda, &smem[bufb + ks * 8192 + 4096 + sdst]);
  };
  auto stgB = [&](int kt, int ks, int bufb) {
    const unsigned short* s = Bsrc + kt * 64 + ks * 32;
    gload_lds16(s, &smem[bufb + 16384 + ks * 8192 + sdst]);
    gload_lds16(s + (size_t)128 * ldb, &smem[bufb + 16384 + ks * 8192 + 4096 + sdst]);
  };

  f32x4 acc[8][NJ] = {};
  bf16v8 aq[4], bq[NJ];

  stgA(0, 0, 0);     stgB(0, 0, 0);
  stgA(0, 1, 0);     stgB(0, 1, 0);
  stgA(1, 0, 32768); stgB(1, 0, 32768);
  asm volatile("s_waitcnt vmcnt(8)" ::: "memory");
  BARF;

  for (int ktp = 0; ktp < NT; ktp += 2) {
    TILEK(ktp, 0, 32768);
    TILEK(ktp + 1, 32768, 0);
  }

  // Epilogue. C/D layout: col = lane&15, row = (lane>>4)*4 + reg  [HW-verified]
  const int r0 = (lane >> 4) * 4;
  const int c0 = lane & 15;
  const int mrowB = m0 + wm * 128 + r0;
  const int ncolB = n0 + wn * (NJ * 16) + c0;

  if (MODE == 0) {
    if (n0 < 1536) {  // Q or K region (block-uniform: BN | 768)
      unsigned short* dst = (n0 < 768) ? Cq : Ck;
      const int cb = (n0 < 768) ? 0 : 768;
#pragma unroll
      for (int i = 0; i < 8; ++i)
#pragma unroll
        for (int j = 0; j < NJ; ++j)
#pragma unroll
          for (int r = 0; r < 4; ++r)
            dst[(size_t)(mrowB + i * 16 + r) * DD + (ncolB + j * 16 - cb)] = f2b(acc[i][j][r]);
    } else {  // V region: store transposed Vt[b][e][n]
#pragma unroll
      for (int i = 0; i < 8; ++i) {
        int row = mrowB + i * 16;          // global token index = b*2048 + n
        int bb = row >> 11, nn = row & 2047;
#pragma unroll
        for (int j = 0; j < NJ; ++j) {
          int e = ncolB + j * 16 - 1536;
          ushort4v pk;
#pragma unroll
          for (int r = 0; r < 4; ++r) pk[r] = f2b(acc[i][j][r]);
          *(ushort4v*)&Cv[((size_t)(bb * DD + e)) * NN + nn] = pk;
        }
      }
    }
  } else {
    float* dst = Cf + (size_t)bz * cStride;
#pragma unroll
    for (int i = 0; i < 8; ++i)
#pragma unroll
      for (int j = 0; j < NJ; ++j)
#pragma unroll
        for (int r = 0; r < 4; ++r)
          dst[(size_t)(mrowB + i * 16 + r) * DD + (ncolB + j * 16)] = acc[i][j][r];
  }
}

// ---- Persistent scores GEMM: S[b][m][c] = Q[b][m] . K[b][kidx[c]] (compacted keys) ----
// 256 blocks; active tiles enumerated densely (per batch: ceil(nc/256) n-tiles x 8 m-tiles,
// ordered n-major so consecutive items share the B panel). Block lid takes items lid, lid+256.
// B staged via per-lane kidx indirection from the NORMAL K buffer. NOTE: the two 128-row
// half-tiles need INDEPENDENT indirection (kidx[c] and kidx[c+128]) — a +128*ldb offset
// would address kidx[c]+128, which is wrong under compaction (r12 bug).
template <int NJ, int NTT>
__global__ __launch_bounds__(512, 2) void gemm1P(
    const unsigned short* __restrict__ Qa, const unsigned short* __restrict__ Kn,
    unsigned short* __restrict__ So, const int* __restrict__ kidx,
    const int* __restrict__ ncnt, int lda, int ldb) {
  extern __shared__ unsigned short smem[];      // 131072 B
  constexpr int NT = NTT;

  const int t = threadIdx.x;
  const int lane = t & 63;
  const int w = t >> 6;
  const int wm = w >> 2, wn = w & 3;
  const int frow = lane & 15;
  const int kg8 = (lane >> 4) * 8;
  const int arow0 = (wm * 128 + frow) * 32;
  const int brow0 = (wn * (NJ * 16) + frow) * 32;
  const int srow = t >> 2;
  const int scol8 = (t & 3) * 8;
  const int sdst = w * 512;
  const int r0 = (lane >> 4) * 4;
  const int c0 = lane & 15;

  int nbv[8];
#pragma unroll
  for (int b_ = 0; b_ < 8; ++b_) nbv[b_] = (ncnt[b_] + 255) >> 8;   // n-tiles per batch

  f32x4 acc[8][NJ];
  bf16v8 aq[4], bq[NJ];

#pragma unroll 1
  for (int it = 0; it < 2; ++it) {
    int rem = (int)blockIdx.x + it * 256;
    int b = 0;
#pragma unroll 1
    for (; b < 8; ++b) { int c = nbv[b] * 8; if (rem < c) break; rem -= c; }
    if (b >= 8) break;                       // items are dense; nothing further
    const int ni = rem >> 3, mi = rem & 7;   // n-major: 8 consecutive items share B panel
    const int m0 = mi * 256, n0 = ni * 256;

    const unsigned short* Asrc = Qa + ((size_t)b * NN + m0 + srow) * lda + scol8;
    // independent indirection for the two 128-row half-tiles (r12 fix)
    const int kv0 = kidx[b * NN + n0 + srow];
    const int kv1 = kidx[b * NN + n0 + 128 + srow];
    const unsigned short* Bsrc0 = Kn + ((size_t)b * NN + kv0) * ldb + scol8;
    const unsigned short* Bsrc1 = Kn + ((size_t)b * NN + kv1) * ldb + scol8;

    auto stgA = [&](int kt, int ks, int bufb) {
      const unsigned short* s = Asrc + kt * 64 + ks * 32;
      gload_lds16(s, &smem[bufb + ks * 8192 + sdst]);
      gload_lds16(s + (size_t)128 * lda, &smem[bufb + ks * 8192 + 4096 + sdst]);
    };
    auto stgB = [&](int kt, int ks, int bufb) {
      gload_lds16(Bsrc0 + kt * 64 + ks * 32, &smem[bufb + 16384 + ks * 8192 + sdst]);
      gload_lds16(Bsrc1 + kt * 64 + ks * 32, &smem[bufb + 16384 + ks * 8192 + 4096 + sdst]);
    };

#pragma unroll
    for (int i = 0; i < 8; ++i)
#pragma unroll
      for (int j = 0; j < NJ; ++j) acc[i][j] = f32x4{0.f, 0.f, 0.f, 0.f};

    stgA(0, 0, 0);     stgB(0, 0, 0);
    stgA(0, 1, 0);     stgB(0, 1, 0);
    stgA(1, 0, 32768); stgB(1, 0, 32768);
    asm volatile("s_waitcnt vmcnt(8)" ::: "memory");
    BARF;

    for (int ktp = 0; ktp < NT; ktp += 2) {
      TILEK(ktp, 0, 32768);
      TILEK(ktp + 1, 32768, 0);
    }

    unsigned short* dst = So + (size_t)b * NN * NN;
    const int mrowB = m0 + wm * 128 + r0;
    const int ncolB = n0 + wn * (NJ * 16) + c0;
#pragma unroll
    for (int i = 0; i < 8; ++i)
#pragma unroll
      for (int j = 0; j < NJ; ++j)
#pragma unroll
        for (int r = 0; r < 4; ++r)
          dst[(size_t)(mrowB + i * 16 + r) * NN + (ncolB + j * 16)] = f2b(acc[i][j][r]);
  }
}

// ---------------- compacted softmax: cols [0,nc) valid, zero-fill [nc,r128), skip rest ----------------
__global__ __launch_bounds__(256) void softmax_c(unsigned short* __restrict__ S,
                                                 const int* __restrict__ ncnt) {
  int row = blockIdx.x;            // 0..16383
  int bb = row >> 11;
  const int nc = ncnt[bb];
  const int p128 = (nc + 127) & ~127;
  unsigned short* sr = S + (size_t)row * NN;
  int t = threadIdx.x;
  const int cbase = t * 8;

  float v[8];
  const bool anyload = cbase < nc;
  ushort8v pk;
  if (anyload) pk = *(const ushort8v*)&sr[cbase];
  float mx = -1e30f;
#pragma unroll
  for (int j = 0; j < 8; ++j) {
    v[j] = anyload ? b2f(pk[j]) : 0.f;
    if (cbase + j < nc) mx = fmaxf(mx, v[j]);
  }
  for (int o = 32; o > 0; o >>= 1) mx = fmaxf(mx, __shfl_xor(mx, o));
  __shared__ float redm[4], reds[4];
  int w = t >> 6, lane = t & 63;
  if (lane == 0) redm[w] = mx;
  __syncthreads();
  mx = fmaxf(fmaxf(redm[0], redm[1]), fmaxf(redm[2], redm[3]));

  float e[8];
  float sum = 0.f;
#pragma unroll
  for (int j = 0; j < 8; ++j) {
    e[j] = (cbase + j < nc) ? __expf(v[j] - mx) : 0.f;
    sum += e[j];
  }
  for (int o = 32; o > 0; o >>= 1) sum += __shfl_xor(sum, o);
  if (lane == 0) reds[w] = sum;
  __syncthreads();
  sum = reds[0] + reds[1] + reds[2] + reds[3];
  float inv = 1.0f / sum;

  if (cbase < p128) {
    ushort8v op;
#pragma unroll
    for (int j = 0; j < 8; ++j) op[j] = f2b(e[j] * inv);
    *(ushort8v*)&sr[cbase] = op;
  }
}

extern "C" void kernel_launch(void* const* d_in, const int* in_sizes, int n_in,
                              void* d_out, int out_size, void* d_ws, size_t ws_size,
                              hipStream_t stream) {
  const float* features = (const float*)d_in[0];
  const int* mask       = (const int*)d_in[1];
  const float* Wq       = (const float*)d_in[2];
  const float* Wk       = (const float*)d_in[3];
  const float* Wv       = (const float*)d_in[4];
  const float* gamma    = (const float*)d_in[5];
  const float* beta     = (const float*)d_in[6];
  float* out = (float*)d_out;

  char* ws = (char*)d_ws;
  size_t off = 0;
  auto alloc = [&](size_t bytes) {
    char* p = ws + off;
    off += (bytes + 255) & ~(size_t)255;
    return p;
  };
  // Wcat padded by 64 rows (192-wide B staging over-read at the last N-tile)
  unsigned short* Wcat = (unsigned short*)alloc((size_t)(2304 + 64) * DD * 2);
  unsigned short* Qb   = (unsigned short*)alloc((size_t)BB * NN * DD * 2);
  unsigned short* Kb   = (unsigned short*)alloc((size_t)BB * NN * DD * 2);
  // Vt padded by 64 rows of 2048 (gemm0 V epilogue region)
  unsigned short* Vt   = (unsigned short*)alloc(((size_t)BB * DD + 64) * NN * 2);
  int* kidx = (int*)alloc((size_t)BB * NN * 4);
  int* ncnt = (int*)alloc(64 * 4);
  // S (67 MB) aliases the X buffer region: X is dead once GEMM0 completes.
  char* last = alloc((size_t)BB * NN * NN * 2);
  unsigned short* Sb = (unsigned short*)last;
  unsigned short* Xb = (unsigned short*)last;  // first 25 MB of the S region
  // Vtc (25.4 MB) aliases Qb+Kb (50.3 MB): Q,K dead after gemm1P; written by vtc_gather.
  unsigned short* Vtc = Qb;

  (void)hipFuncSetAttribute(reinterpret_cast<const void*>(&gemm256<0, 3>),
                            hipFuncAttributeMaxDynamicSharedMemorySize, 131072);
  (void)hipFuncSetAttribute(reinterpret_cast<const void*>(&gemm1P<4, 12>),
                            hipFuncAttributeMaxDynamicSharedMemorySize, 131072);
  (void)hipFuncSetAttribute(reinterpret_cast<const void*>(&gemm256<2, 3>),
                            hipFuncAttributeMaxDynamicSharedMemorySize, 131072);

  ln_kernel<<<BB * NN, 256, 0, stream>>>(features, gamma, beta, Xb);
  wconvert<<<(3 * DD * DD + 255) / 256, 256, 0, stream>>>(Wq, Wk, Wv, Wcat);
  mask_scan<<<BB, 256, 0, stream>>>(mask, kidx, ncnt);

  // QKV projection: [16384,768] x [2304,768]^T ; 12x64 grid (r6 champion, r6 epilogue)
  gemm256<0, 3><<<dim3(2304 / 192, (BB * NN) / 256, 1), 512, 131072, stream>>>(
      Xb, Wcat, Qb, Kb, Vt, nullptr, DD, DD, DD, 0, 0, 0, ncnt);

  // Scores (compacted keys, persistent balanced): S[b][m][c] bf16
  gemm1P<4, 12><<<256, 512, 131072, stream>>>(Qb, Kb, Sb, kidx, ncnt, DD, DD);

  // Vt column compaction (Q/K now dead; Vtc aliases their storage)
  vtc_gather<<<BB * DD, 256, 0, stream>>>(Vt, kidx, ncnt, Vtc);

  softmax_c<<<BB * NN, 256, 0, stream>>>(Sb, ncnt);

  // Context (compacted K-dim): per batch P[2048,r128] x Vtc[768,r128]^T -> f32 out
  gemm256<2, 3><<<dim3(DD / 192, NN / 256, BB), 512, 131072, stream>>>(
      Sb, Vtc, nullptr, nullptr, nullptr, out, NN, NN, NN,
      (long)NN * NN, (long)DD * NN, (long)NN * DD, ncnt);
}

// Round 14
// 223.513 us; speedup vs baseline: 1.2412x; 1.0069x over previous
//
#include <hip/hip_runtime.h>
#include <hip/hip_bf16.h>
#include <cstdint>

typedef __attribute__((ext_vector_type(8))) __bf16 bf16v8;
typedef __attribute__((ext_vector_type(4))) float f32x4;
typedef __attribute__((ext_vector_type(4))) unsigned short ushort4v;
typedef __attribute__((ext_vector_type(8))) unsigned short ushort8v;

#define BB 8
#define NN 2048
#define DD 768

__device__ __forceinline__ float b2f(unsigned short u) {
  union { unsigned int i; float f; } c; c.i = ((unsigned int)u) << 16; return c.f;
}
__device__ __forceinline__ unsigned short f2b(float f) {
  union { float f; unsigned int i; } c; c.f = f;
  unsigned int u = c.i;
  return (unsigned short)((u + 0x7fffu + ((u >> 16) & 1u)) >> 16);
}

// ---------------- LayerNorm: f32 [16384][768] -> bf16 ----------------
__global__ __launch_bounds__(256) void ln_kernel(const float* __restrict__ x,
                                                 const float* __restrict__ gamma,
                                                 const float* __restrict__ beta,
                                                 unsigned short* __restrict__ xb) {
  int row = blockIdx.x;
  const float* xr = x + (size_t)row * DD;
  int t = threadIdx.x;
  float a0 = xr[t], a1 = xr[t + 256], a2 = xr[t + 512];
  float s = a0 + a1 + a2;
  float q = a0 * a0 + a1 * a1 + a2 * a2;
  for (int o = 32; o > 0; o >>= 1) { s += __shfl_xor(s, o); q += __shfl_xor(q, o); }
  __shared__ float red[2][4];
  int w = t >> 6, lane = t & 63;
  if (lane == 0) { red[0][w] = s; red[1][w] = q; }
  __syncthreads();
  s = red[0][0] + red[0][1] + red[0][2] + red[0][3];
  q = red[1][0] + red[1][1] + red[1][2] + red[1][3];
  float mean = s * (1.0f / DD);
  float var = q * (1.0f / DD) - mean * mean;
  float inv = rsqrtf(var + 1e-5f);
  unsigned short* o0 = xb + (size_t)row * DD;
  o0[t]       = f2b((a0 - mean) * inv * gamma[t]       + beta[t]);
  o0[t + 256] = f2b((a1 - mean) * inv * gamma[t + 256] + beta[t + 256]);
  o0[t + 512] = f2b((a2 - mean) * inv * gamma[t + 512] + beta[t + 512]);
}

// ------------- Weight concat/convert: Wcat[2304][768] bf16, scale folded into Wq -------------
__global__ __launch_bounds__(256) void wconvert(const float* __restrict__ Wq,
                                                const float* __restrict__ Wk,
                                                const float* __restrict__ Wv,
                                                unsigned short* __restrict__ Wcat) {
  int i = blockIdx.x * 256 + threadIdx.x;
  const int dd = DD * DD;
  if (i >= 3 * dd) return;
  float v;
  if (i < dd)           v = Wq[i] * 0.03608439182435161f;   // 1/sqrt(768)
  else if (i < 2 * dd)  v = Wk[i - dd];
  else                  v = Wv[i - 2 * dd];
  Wcat[i] = f2b(v);
}

// ------------- mask scan: kidx[b][c] = original index of c-th unmasked key (0 beyond); ncnt[b] -------------
__global__ __launch_bounds__(256) void mask_scan(const int* __restrict__ mask,
                                                 int* __restrict__ kidx,
                                                 int* __restrict__ ncnt) {
  int b = blockIdx.x;
  const int* mr = mask + b * NN;
  int t = threadIdx.x;
#pragma unroll
  for (int j = 0; j < 8; ++j) kidx[b * NN + t * 8 + j] = 0;
  int v[8]; int s = 0;
#pragma unroll
  for (int j = 0; j < 8; ++j) { v[j] = (mr[t * 8 + j] == 0) ? 1 : 0; s += v[j]; }
  int lane = t & 63, w = t >> 6;
  int x = s;
  for (int o = 1; o < 64; o <<= 1) { int y = __shfl_up(x, o); if (lane >= o) x += y; }
  __shared__ int wsum[4];
  if (lane == 63) wsum[w] = x;
  __syncthreads();
  int base = 0;
#pragma unroll
  for (int i = 0; i < 4; ++i) if (i < w) base += wsum[i];
  int run = base + x - s;                 // exclusive prefix at this thread's first element
#pragma unroll
  for (int j = 0; j < 8; ++j) { if (v[j]) kidx[b * NN + run] = t * 8 + j; run += v[j]; }
  if (t == 255) ncnt[b] = base + x;
}

// ------------- X row compaction: Xc[off[b]+c][:] = Xb[b][kidx[c]][:] (c<nc), 0 for [nc,r256) -------------
__global__ __launch_bounds__(256) void xc_gather(const unsigned short* __restrict__ Xb,
                                                 const int* __restrict__ kidx,
                                                 const int* __restrict__ ncnt,
                                                 unsigned short* __restrict__ Xc) {
  const int b = blockIdx.y;
  const int nc = ncnt[b];
  const int r256 = (nc + 255) & ~255;
  const int row0 = blockIdx.x * 32;
  if (row0 >= r256) return;
  int off = 0;
#pragma unroll
  for (int i = 0; i < 8; ++i) if (i < b) off += (ncnt[i] + 255) & ~255;
  const int t = threadIdx.x;
  for (int r = 0; r < 32; ++r) {
    const int rl = row0 + r;
    unsigned short* dst = Xc + (size_t)(off + rl) * DD;
    if (t < 96) {
      if (rl < nc) {
        const unsigned short* src = Xb + ((size_t)b * NN + kidx[b * NN + rl]) * DD;
        *(ushort8v*)&dst[t * 8] = *(const ushort8v*)&src[t * 8];
      } else {
        *(ushort8v*)&dst[t * 8] = ushort8v{0, 0, 0, 0, 0, 0, 0, 0};
      }
    }
  }
}

// ---------------- async global->LDS (16B per lane, wave-uniform LDS base) ----------------
__device__ __forceinline__ void gload_lds16(const void* g, void* l) {
  __builtin_amdgcn_global_load_lds(
      (const __attribute__((address_space(1))) void*)g,
      (__attribute__((address_space(3))) void*)(unsigned)(uintptr_t)l,
      16, 0, 0);
}

// LDS geometry (elements): buffer b at b*32768.
//   slot A-ks at  buf + ks*8192          (256 rows x 32 cols, 64B rows)
//   slot B-ks at  buf + 16384 + ks*8192
#define RDA(i0, ks, B)                                                                   \
  _Pragma("unroll")                                                                      \
  for (int i_ = 0; i_ < 4; ++i_)                                                         \
    aq[i_] = *(const bf16v8*)&smem[(B) + (ks) * 8192 + arow0 + ((i0) + i_) * 512 + kg8];
#define RDB(ks, B)                                                                       \
  _Pragma("unroll")                                                                      \
  for (int j_ = 0; j_ < NJ; ++j_)                                                        \
    bq[j_] = *(const bf16v8*)&smem[(B) + 16384 + (ks) * 8192 + brow0 + j_ * 512 + kg8];
#define MFQ(i0)                                                                          \
  _Pragma("unroll")                                                                      \
  for (int i_ = 0; i_ < 4; ++i_) {                                                       \
    _Pragma("unroll")                                                                    \
    for (int j_ = 0; j_ < NJ; ++j_)                                                      \
      acc[(i0) + i_][j_] = __builtin_amdgcn_mfma_f32_16x16x32_bf16(                      \
          aq[i_], bq[j_], acc[(i0) + i_][j_], 0, 0, 0);                                  \
  }
#define BARF asm volatile("s_barrier" ::: "memory")
#define VMC6 asm volatile("s_waitcnt vmcnt(6)" ::: "memory")
#define VMC0 asm volatile("s_waitcnt vmcnt(0)" ::: "memory")
#define P1   __builtin_amdgcn_s_setprio(1)
#define P0   __builtin_amdgcn_s_setprio(0)

// r6 per-tile schedule:
#define TILEK(KT, CURB, NXTB)                                                            \
  do {                                                                                   \
    RDA(0, 0, CURB); RDB(0, CURB);                                                       \
    if ((KT) + 1 < NT) stgA((KT) + 1, 1, (NXTB));                                        \
    BARF; P1; MFQ(0); P0; BARF;                                                          \
    RDA(4, 0, CURB);                                                                     \
    if ((KT) + 1 < NT) stgB((KT) + 1, 1, (NXTB));                                        \
    BARF; P1; MFQ(4); P0;                                                                \
    VMC6; BARF;                                                                          \
    RDA(0, 1, CURB); RDB(1, CURB);                                                       \
    if ((KT) + 2 < NT) stgA((KT) + 2, 0, (CURB));                                        \
    BARF; P1; MFQ(0); P0; BARF;                                                          \
    RDA(4, 1, CURB);                                                                     \
    if ((KT) + 2 < NT) stgB((KT) + 2, 0, (CURB));                                        \
    BARF; P1; MFQ(4); P0;                                                                \
    if ((KT) < NT - 2) { VMC6; } else { VMC0; }                                          \
    BARF;                                                                                \
  } while (0)

// ---- 256xBN pipelined bf16 GEMM (r6 structure), C = A * B^T ----
// MODE 2: f32 store (ld=DD) with runtime NT = 2*ceil(ncnt/128) per batch
// MODE 3: bf16 store (ld=DD), static K
template <int MODE, int NJ>
__global__ __launch_bounds__(512, 2) void gemm256(
    const unsigned short* __restrict__ A, const unsigned short* __restrict__ Bm,
    unsigned short* __restrict__ Cq, float* __restrict__ Cf,
    int K, int lda, int ldb,
    long aStride, long bStride, long cStride,
    const int* __restrict__ ncnt) {
  extern __shared__ unsigned short smem[];      // 65536 elems = 131072 B
  const int BN = NJ * 64;

  const int t = threadIdx.x;
  int bx = blockIdx.x, by = blockIdx.y, bz = blockIdx.z;
  {  // bijective XCD swizzle (all grids are %8==0)
    const int gx = gridDim.x, gy = gridDim.y;
    const int nwg = gx * gy * (int)gridDim.z;
    int id = bx + gx * (by + gy * bz);
    int sw = (id & 7) * (nwg >> 3) + (id >> 3);
    bx = sw % gx; int r2 = sw / gx;
    by = r2 % gy; bz = r2 / gy;
  }
  const int n0 = bx * BN, m0 = by * 256;
  const int NT = (MODE == 2) ? (((ncnt[bz] + 127) >> 7) << 1) : (K >> 6);

  const unsigned short* Ab = A + (size_t)bz * aStride;
  const unsigned short* Bb = Bm + (size_t)bz * bStride;

  const int lane = t & 63;
  const int w = t >> 6;
  const int wm = w >> 2, wn = w & 3;
  const int frow = lane & 15;
  const int kg8 = (lane >> 4) * 8;
  const int arow0 = (wm * 128 + frow) * 32;
  const int brow0 = (wn * (NJ * 16) + frow) * 32;

  const int srow = t >> 2;
  const int scol8 = (t & 3) * 8;
  const unsigned short* Asrc = Ab + (size_t)(m0 + srow) * lda + scol8;
  const unsigned short* Bsrc = Bb + (size_t)(n0 + srow) * ldb + scol8;
  const int sdst = w * 512;

  auto stgA = [&](int kt, int ks, int bufb) {
    const unsigned short* s = Asrc + kt * 64 + ks * 32;
    gload_lds16(s, &smem[bufb + ks * 8192 + sdst]);
    gload_lds16(s + (size_t)128 * lda, &smem[bufb + ks * 8192 + 4096 + sdst]);
  };
  auto stgB = [&](int kt, int ks, int bufb) {
    const unsigned short* s = Bsrc + kt * 64 + ks * 32;
    gload_lds16(s, &smem[bufb + 16384 + ks * 8192 + sdst]);
    gload_lds16(s + (size_t)128 * ldb, &smem[bufb + 16384 + ks * 8192 + 4096 + sdst]);
  };

  f32x4 acc[8][NJ] = {};
  bf16v8 aq[4], bq[NJ];

  stgA(0, 0, 0);     stgB(0, 0, 0);
  stgA(0, 1, 0);     stgB(0, 1, 0);
  stgA(1, 0, 32768); stgB(1, 0, 32768);
  asm volatile("s_waitcnt vmcnt(8)" ::: "memory");
  BARF;

  for (int ktp = 0; ktp < NT; ktp += 2) {
    TILEK(ktp, 0, 32768);
    TILEK(ktp + 1, 32768, 0);
  }

  // Epilogue. C/D layout: col = lane&15, row = (lane>>4)*4 + reg  [HW-verified]
  const int r0 = (lane >> 4) * 4;
  const int c0 = lane & 15;
  const int mrowB = m0 + wm * 128 + r0;
  const int ncolB = n0 + wn * (NJ * 16) + c0;

  if (MODE == 3) {
#pragma unroll
    for (int i = 0; i < 8; ++i)
#pragma unroll
      for (int j = 0; j < NJ; ++j)
#pragma unroll
        for (int r = 0; r < 4; ++r)
          Cq[(size_t)(mrowB + i * 16 + r) * DD + (ncolB + j * 16)] = f2b(acc[i][j][r]);
  } else {
    float* dst = Cf + (size_t)bz * cStride;
#pragma unroll
    for (int i = 0; i < 8; ++i)
#pragma unroll
      for (int j = 0; j < NJ; ++j)
#pragma unroll
        for (int r = 0; r < 4; ++r)
          dst[(size_t)(mrowB + i * 16 + r) * DD + (ncolB + j * 16)] = acc[i][j][r];
  }
}

// ---- K/V projection on COMPACTED tokens: [Kc|Vtc] = Xc * Wkv^T (persistent items) ----
// Xc: globally packed rows (batch regions r256-aligned). items = GT x 8 n-tiles (NJ=3).
// Outputs emerge compacted: Kc[b][c][:] dense rows; Vtc[b][e][c] dense cols (vectorized).
template <int NJ, int NTT>
__global__ __launch_bounds__(512, 2) void gemmKV(
    const unsigned short* __restrict__ Xc, const unsigned short* __restrict__ Wcat,
    unsigned short* __restrict__ Kc, unsigned short* __restrict__ Vtc,
    const int* __restrict__ ncnt) {
  extern __shared__ unsigned short smem[];      // 131072 B
  constexpr int NT = NTT;

  int offv[9]; offv[0] = 0;
#pragma unroll
  for (int i = 0; i < 8; ++i) offv[i + 1] = offv[i] + ((ncnt[i] + 255) & ~255);
  const int GT = offv[8] >> 8;
  const int id = (int)blockIdx.x;
  if (id >= GT * 8) return;
  const int gt = id >> 3, ni = id & 7;
  int b = 0;
#pragma unroll
  for (int i = 1; i < 8; ++i) if (offv[i] <= gt * 256) b = i;
  const int off_b = offv[b];

  const int t = threadIdx.x;
  const int lane = t & 63;
  const int w = t >> 6;
  const int wm = w >> 2, wn = w & 3;
  const int frow = lane & 15;
  const int kg8 = (lane >> 4) * 8;
  const int arow0 = (wm * 128 + frow) * 32;
  const int brow0 = (wn * (NJ * 16) + frow) * 32;
  const int srow = t >> 2;
  const int scol8 = (t & 3) * 8;
  const int sdst = w * 512;

  const unsigned short* Asrc = Xc + (size_t)(gt * 256 + srow) * DD + scol8;
  const unsigned short* Bsrc = Wcat + (size_t)(768 + ni * (NJ * 64) + srow) * DD + scol8;

  auto stgA = [&](int kt, int ks, int bufb) {
    const unsigned short* s = Asrc + kt * 64 + ks * 32;
    gload_lds16(s, &smem[bufb + ks * 8192 + sdst]);
    gload_lds16(s + (size_t)128 * DD, &smem[bufb + ks * 8192 + 4096 + sdst]);
  };
  auto stgB = [&](int kt, int ks, int bufb) {
    const unsigned short* s = Bsrc + kt * 64 + ks * 32;
    gload_lds16(s, &smem[bufb + 16384 + ks * 8192 + sdst]);
    gload_lds16(s + (size_t)128 * DD, &smem[bufb + 16384 + ks * 8192 + 4096 + sdst]);
  };

  f32x4 acc[8][NJ] = {};
  bf16v8 aq[4], bq[NJ];

  stgA(0, 0, 0);     stgB(0, 0, 0);
  stgA(0, 1, 0);     stgB(0, 1, 0);
  stgA(1, 0, 32768); stgB(1, 0, 32768);
  asm volatile("s_waitcnt vmcnt(8)" ::: "memory");
  BARF;

  for (int ktp = 0; ktp < NT; ktp += 2) {
    TILEK(ktp, 0, 32768);
    TILEK(ktp + 1, 32768, 0);
  }

  // Epilogue: c_local = gt*256 - off_b + (row within tile). ncolL in [0,1536).
  const int r0 = (lane >> 4) * 4;
  const int c0 = lane & 15;
  const int rowL = wm * 128 + r0;
  const int ncolL = ni * (NJ * 64) + wn * (NJ * 16) + c0;
  const int cbase = gt * 256 - off_b + rowL;

  if (ni < 4) {   // K region: dense compacted rows, ld=768
    unsigned short* dst = Kc + (size_t)b * NN * DD;
#pragma unroll
    for (int i = 0; i < 8; ++i)
#pragma unroll
      for (int j = 0; j < NJ; ++j)
#pragma unroll
        for (int r = 0; r < 4; ++r)
          dst[(size_t)(cbase + i * 16 + r) * DD + (ncolL + j * 16)] = f2b(acc[i][j][r]);
  } else {        // V region: transposed, dense compacted cols (vectorized over r)
#pragma unroll
    for (int i = 0; i < 8; ++i) {
#pragma unroll
      for (int j = 0; j < NJ; ++j) {
        const int e = ncolL + j * 16 - 768;
        ushort4v pk;
#pragma unroll
        for (int r = 0; r < 4; ++r) pk[r] = f2b(acc[i][j][r]);
        *(ushort4v*)&Vtc[((size_t)b * DD + e) * NN + cbase + i * 16] = pk;
      }
    }
  }
}

// ---- Persistent scores GEMM: S[b][m][c] = Q[b][m] . Kc[b][c] (dense compacted keys) ----
// 256 blocks; items enumerated densely (per batch: nbv n-tiles x 8 m-tiles, n-major).
template <int NJ, int NTT>
__global__ __launch_bounds__(512, 2) void gemm1P(
    const unsigned short* __restrict__ Qa, const unsigned short* __restrict__ Kn,
    unsigned short* __restrict__ So, const int* __restrict__ ncnt, int lda, int ldb) {
  extern __shared__ unsigned short smem[];      // 131072 B
  constexpr int NT = NTT;

  const int t = threadIdx.x;
  const int lane = t & 63;
  const int w = t >> 6;
  const int wm = w >> 2, wn = w & 3;
  const int frow = lane & 15;
  const int kg8 = (lane >> 4) * 8;
  const int arow0 = (wm * 128 + frow) * 32;
  const int brow0 = (wn * (NJ * 16) + frow) * 32;
  const int srow = t >> 2;
  const int scol8 = (t & 3) * 8;
  const int sdst = w * 512;
  const int r0 = (lane >> 4) * 4;
  const int c0 = lane & 15;

  int nbv[8];
#pragma unroll
  for (int b_ = 0; b_ < 8; ++b_) nbv[b_] = (ncnt[b_] + 255) >> 8;   // n-tiles per batch

  f32x4 acc[8][NJ];
  bf16v8 aq[4], bq[NJ];

#pragma unroll 1
  for (int it = 0; it < 2; ++it) {
    int rem = (int)blockIdx.x + it * 256;
    int b = 0;
#pragma unroll 1
    for (; b < 8; ++b) { int c = nbv[b] * 8; if (rem < c) break; rem -= c; }
    if (b >= 8) break;
    const int ni = rem >> 3, mi = rem & 7;   // n-major: 8 consecutive items share B panel
    const int m0 = mi * 256, n0 = ni * 256;

    const unsigned short* Asrc = Qa + ((size_t)b * NN + m0 + srow) * lda + scol8;
    const unsigned short* Bsrc = Kn + ((size_t)b * NN + n0 + srow) * ldb + scol8;

    auto stgA = [&](int kt, int ks, int bufb) {
      const unsigned short* s = Asrc + kt * 64 + ks * 32;
      gload_lds16(s, &smem[bufb + ks * 8192 + sdst]);
      gload_lds16(s + (size_t)128 * lda, &smem[bufb + ks * 8192 + 4096 + sdst]);
    };
    auto stgB = [&](int kt, int ks, int bufb) {
      const unsigned short* s = Bsrc + kt * 64 + ks * 32;
      gload_lds16(s, &smem[bufb + 16384 + ks * 8192 + sdst]);
      gload_lds16(s + (size_t)128 * ldb, &smem[bufb + 16384 + ks * 8192 + 4096 + sdst]);
    };

#pragma unroll
    for (int i = 0; i < 8; ++i)
#pragma unroll
      for (int j = 0; j < NJ; ++j) acc[i][j] = f32x4{0.f, 0.f, 0.f, 0.f};

    stgA(0, 0, 0);     stgB(0, 0, 0);
    stgA(0, 1, 0);     stgB(0, 1, 0);
    stgA(1, 0, 32768); stgB(1, 0, 32768);
    asm volatile("s_waitcnt vmcnt(8)" ::: "memory");
    BARF;

    for (int ktp = 0; ktp < NT; ktp += 2) {
      TILEK(ktp, 0, 32768);
      TILEK(ktp + 1, 32768, 0);
    }

    unsigned short* dst = So + (size_t)b * NN * NN;
    const int mrowB = m0 + wm * 128 + r0;
    const int ncolB = n0 + wn * (NJ * 16) + c0;
#pragma unroll
    for (int i = 0; i < 8; ++i)
#pragma unroll
      for (int j = 0; j < NJ; ++j)
#pragma unroll
        for (int r = 0; r < 4; ++r)
          dst[(size_t)(mrowB + i * 16 + r) * NN + (ncolB + j * 16)] = f2b(acc[i][j][r]);
  }
}

// ---------------- compacted softmax: cols [0,nc) valid, zero-fill [nc,r128), skip rest ----------------
__global__ __launch_bounds__(256) void softmax_c(unsigned short* __restrict__ S,
                                                 const int* __restrict__ ncnt) {
  int row = blockIdx.x;            // 0..16383
  int bb = row >> 11;
  const int nc = ncnt[bb];
  const int p128 = (nc + 127) & ~127;
  unsigned short* sr = S + (size_t)row * NN;
  int t = threadIdx.x;
  const int cbase = t * 8;

  float v[8];
  const bool anyload = cbase < nc;
  ushort8v pk;
  if (anyload) pk = *(const ushort8v*)&sr[cbase];
  float mx = -1e30f;
#pragma unroll
  for (int j = 0; j < 8; ++j) {
    v[j] = anyload ? b2f(pk[j]) : 0.f;
    if (cbase + j < nc) mx = fmaxf(mx, v[j]);
  }
  for (int o = 32; o > 0; o >>= 1) mx = fmaxf(mx, __shfl_xor(mx, o));
  __shared__ float redm[4], reds[4];
  int w = t >> 6, lane = t & 63;
  if (lane == 0) redm[w] = mx;
  __syncthreads();
  mx = fmaxf(fmaxf(redm[0], redm[1]), fmaxf(redm[2], redm[3]));

  float e[8];
  float sum = 0.f;
#pragma unroll
  for (int j = 0; j < 8; ++j) {
    e[j] = (cbase + j < nc) ? __expf(v[j] - mx) : 0.f;
    sum += e[j];
  }
  for (int o = 32; o > 0; o >>= 1) sum += __shfl_xor(sum, o);
  if (lane == 0) reds[w] = sum;
  __syncthreads();
  sum = reds[0] + reds[1] + reds[2] + reds[3];
  float inv = 1.0f / sum;

  if (cbase < p128) {
    ushort8v op;
#pragma unroll
    for (int j = 0; j < 8; ++j) op[j] = f2b(e[j] * inv);
    *(ushort8v*)&sr[cbase] = op;
  }
}

extern "C" void kernel_launch(void* const* d_in, const int* in_sizes, int n_in,
                              void* d_out, int out_size, void* d_ws, size_t ws_size,
                              hipStream_t stream) {
  const float* features = (const float*)d_in[0];
  const int* mask       = (const int*)d_in[1];
  const float* Wq       = (const float*)d_in[2];
  const float* Wk       = (const float*)d_in[3];
  const float* Wv       = (const float*)d_in[4];
  const float* gamma    = (const float*)d_in[5];
  const float* beta     = (const float*)d_in[6];
  float* out = (float*)d_out;

  char* ws = (char*)d_ws;
  size_t off = 0;
  auto alloc = [&](size_t bytes) {
    char* p = ws + off;
    off += (bytes + 255) & ~(size_t)255;
    return p;
  };
  // Wcat padded by 64 rows (192-wide B staging over-reads at the last n-tile)
  unsigned short* Wcat = (unsigned short*)alloc((size_t)(2304 + 64) * DD * 2);
  unsigned short* Qb   = (unsigned short*)alloc((size_t)BB * NN * DD * 2);
  unsigned short* Kc   = (unsigned short*)alloc((size_t)BB * NN * DD * 2);   // compacted K rows
  unsigned short* Vtc  = (unsigned short*)alloc(((size_t)BB * DD + 64) * NN * 2);  // compacted Vt cols
  int* kidx = (int*)alloc((size_t)BB * NN * 4);
  int* ncnt = (int*)alloc(64 * 4);
  // S (67 MB): Xb aliases its first 25 MB; Xc aliases its upper half (dead before gemm1P writes S).
  char* last = alloc((size_t)BB * NN * NN * 2);
  unsigned short* Sb = (unsigned short*)last;
  unsigned short* Xb = (unsigned short*)last;
  unsigned short* Xc = (unsigned short*)(last + (size_t)34 * 1024 * 1024);

  (void)hipFuncSetAttribute(reinterpret_cast<const void*>(&gemm256<3, 3>),
                            hipFuncAttributeMaxDynamicSharedMemorySize, 131072);
  (void)hipFuncSetAttribute(reinterpret_cast<const void*>(&gemmKV<3, 12>),
                            hipFuncAttributeMaxDynamicSharedMemorySize, 131072);
  (void)hipFuncSetAttribute(reinterpret_cast<const void*>(&gemm1P<4, 12>),
                            hipFuncAttributeMaxDynamicSharedMemorySize, 131072);
  (void)hipFuncSetAttribute(reinterpret_cast<const void*>(&gemm256<2, 3>),
                            hipFuncAttributeMaxDynamicSharedMemorySize, 131072);

  ln_kernel<<<BB * NN, 256, 0, stream>>>(features, gamma, beta, Xb);
  wconvert<<<(3 * DD * DD + 255) / 256, 256, 0, stream>>>(Wq, Wk, Wv, Wcat);
  mask_scan<<<BB, 256, 0, stream>>>(mask, kidx, ncnt);
  xc_gather<<<dim3(64, BB), 256, 0, stream>>>(Xb, kidx, ncnt, Xc);

  // Q projection: [16384,768] x [768,768]^T ; 4x64 = 256 blocks = 1.0/CU exact
  gemm256<3, 3><<<dim3(4, 64, 1), 512, 131072, stream>>>(
      Xb, Wcat, Qb, nullptr, DD, DD, DD, 0, 0, 0, ncnt);

  // K/V projection on compacted tokens: ~half the work, outputs pre-compacted
  gemmKV<3, 12><<<512, 512, 131072, stream>>>(Xc, Wcat, Kc, Vtc, ncnt);

  // Scores (dense compacted keys, persistent balanced): S[b][m][c] bf16
  gemm1P<4, 12><<<256, 512, 131072, stream>>>(Qb, Kc, Sb, ncnt, DD, DD);

  softmax_c<<<BB * NN, 256, 0, stream>>>(Sb, ncnt);

  // Context (compacted K-dim): per batch P[2048,r128] x Vtc[768,r128]^T -> f32 out
  gemm256<2, 3><<<dim3(DD / 192, NN / 256, BB), 512, 131072, stream>>>(
      Sb, Vtc, nullptr, out, NN, NN, NN,
      (long)NN * NN, (long)DD * NN, (long)NN * DD, ncnt);
}

// Round 15
// 217.430 us; speedup vs baseline: 1.2759x; 1.0280x over previous
//
#include <hip/hip_runtime.h>
#include <hip/hip_bf16.h>
#include <cstdint>

typedef __attribute__((ext_vector_type(8))) __bf16 bf16v8;
typedef __attribute__((ext_vector_type(4))) float f32x4;
typedef __attribute__((ext_vector_type(4))) unsigned short ushort4v;
typedef __attribute__((ext_vector_type(8))) unsigned short ushort8v;

#define BB 8
#define NN 2048
#define DD 768

__device__ __forceinline__ float b2f(unsigned short u) {
  union { unsigned int i; float f; } c; c.i = ((unsigned int)u) << 16; return c.f;
}
__device__ __forceinline__ unsigned short f2b(float f) {
  union { float f; unsigned int i; } c; c.f = f;
  unsigned int u = c.i;
  return (unsigned short)((u + 0x7fffu + ((u >> 16) & 1u)) >> 16);
}

// ---------------- LayerNorm: f32 [16384][768] -> bf16 ----------------
__global__ __launch_bounds__(256) void ln_kernel(const float* __restrict__ x,
                                                 const float* __restrict__ gamma,
                                                 const float* __restrict__ beta,
                                                 unsigned short* __restrict__ xb) {
  int row = blockIdx.x;
  const float* xr = x + (size_t)row * DD;
  int t = threadIdx.x;
  float a0 = xr[t], a1 = xr[t + 256], a2 = xr[t + 512];
  float s = a0 + a1 + a2;
  float q = a0 * a0 + a1 * a1 + a2 * a2;
  for (int o = 32; o > 0; o >>= 1) { s += __shfl_xor(s, o); q += __shfl_xor(q, o); }
  __shared__ float red[2][4];
  int w = t >> 6, lane = t & 63;
  if (lane == 0) { red[0][w] = s; red[1][w] = q; }
  __syncthreads();
  s = red[0][0] + red[0][1] + red[0][2] + red[0][3];
  q = red[1][0] + red[1][1] + red[1][2] + red[1][3];
  float mean = s * (1.0f / DD);
  float var = q * (1.0f / DD) - mean * mean;
  float inv = rsqrtf(var + 1e-5f);
  unsigned short* o0 = xb + (size_t)row * DD;
  o0[t]       = f2b((a0 - mean) * inv * gamma[t]       + beta[t]);
  o0[t + 256] = f2b((a1 - mean) * inv * gamma[t + 256] + beta[t + 256]);
  o0[t + 512] = f2b((a2 - mean) * inv * gamma[t + 512] + beta[t + 512]);
}

// ------------- Weight concat/convert: Wcat[2304][768] bf16, scale folded into Wq -------------
__global__ __launch_bounds__(256) void wconvert(const float* __restrict__ Wq,
                                                const float* __restrict__ Wk,
                                                const float* __restrict__ Wv,
                                                unsigned short* __restrict__ Wcat) {
  int i = blockIdx.x * 256 + threadIdx.x;
  const int dd = DD * DD;
  if (i >= 3 * dd) return;
  float v;
  if (i < dd)           v = Wq[i] * 0.03608439182435161f;   // 1/sqrt(768)
  else if (i < 2 * dd)  v = Wk[i - dd];
  else                  v = Wv[i - 2 * dd];
  Wcat[i] = f2b(v);
}

// ------------- mask scan: kidx[b][c] = original index of c-th unmasked key (0 beyond); ncnt[b] -------------
__global__ __launch_bounds__(256) void mask_scan(const int* __restrict__ mask,
                                                 int* __restrict__ kidx,
                                                 int* __restrict__ ncnt) {
  int b = blockIdx.x;
  const int* mr = mask + b * NN;
  int t = threadIdx.x;
#pragma unroll
  for (int j = 0; j < 8; ++j) kidx[b * NN + t * 8 + j] = 0;
  int v[8]; int s = 0;
#pragma unroll
  for (int j = 0; j < 8; ++j) { v[j] = (mr[t * 8 + j] == 0) ? 1 : 0; s += v[j]; }
  int lane = t & 63, w = t >> 6;
  int x = s;
  for (int o = 1; o < 64; o <<= 1) { int y = __shfl_up(x, o); if (lane >= o) x += y; }
  __shared__ int wsum[4];
  if (lane == 63) wsum[w] = x;
  __syncthreads();
  int base = 0;
#pragma unroll
  for (int i = 0; i < 4; ++i) if (i < w) base += wsum[i];
  int run = base + x - s;                 // exclusive prefix at this thread's first element
#pragma unroll
  for (int j = 0; j < 8; ++j) { if (v[j]) kidx[b * NN + run] = t * 8 + j; run += v[j]; }
  if (t == 255) ncnt[b] = base + x;
}

// ------------- X row compaction: Xc[off[b]+c][:] = Xb[b][kidx[c]][:] (c<nc), 0 for [nc,r256) -------------
// full-occupancy: flat (row,chunk) units, 16 rows x 96 chunks per block
__global__ __launch_bounds__(256) void xc_gather(const unsigned short* __restrict__ Xb,
                                                 const int* __restrict__ kidx,
                                                 const int* __restrict__ ncnt,
                                                 unsigned short* __restrict__ Xc) {
  const int b = blockIdx.y;
  const int nc = ncnt[b];
  const int r256 = (nc + 255) & ~255;
  const int row0 = blockIdx.x * 16;
  if (row0 >= r256) return;
  int off = 0;
#pragma unroll
  for (int i = 0; i < 8; ++i) if (i < b) off += (ncnt[i] + 255) & ~255;
  for (int u = threadIdx.x; u < 16 * 96; u += 256) {
    const int r = row0 + u / 96;
    const int ch = (u % 96) * 8;
    if (r >= r256) continue;
    ushort8v val = {0, 0, 0, 0, 0, 0, 0, 0};
    if (r < nc)
      val = *(const ushort8v*)&Xb[((size_t)b * NN + kidx[b * NN + r]) * DD + ch];
    *(ushort8v*)&Xc[(size_t)(off + r) * DD + ch] = val;
  }
}

// ---------------- async global->LDS (16B per lane, wave-uniform LDS base) ----------------
__device__ __forceinline__ void gload_lds16(const void* g, void* l) {
  __builtin_amdgcn_global_load_lds(
      (const __attribute__((address_space(1))) void*)g,
      (__attribute__((address_space(3))) void*)(unsigned)(uintptr_t)l,
      16, 0, 0);
}

// LDS geometry (elements): buffer b at b*32768.
//   slot A-ks at  buf + ks*8192          (256 rows x 32 cols, 64B rows)
//   slot B-ks at  buf + 16384 + ks*8192
#define RDA(i0, ks, B)                                                                   \
  _Pragma("unroll")                                                                      \
  for (int i_ = 0; i_ < 4; ++i_)                                                         \
    aq[i_] = *(const bf16v8*)&smem[(B) + (ks) * 8192 + arow0 + ((i0) + i_) * 512 + kg8];
#define RDB(ks, B)                                                                       \
  _Pragma("unroll")                                                                      \
  for (int j_ = 0; j_ < NJ; ++j_)                                                        \
    bq[j_] = *(const bf16v8*)&smem[(B) + 16384 + (ks) * 8192 + brow0 + j_ * 512 + kg8];
#define MFQ(i0)                                                                          \
  _Pragma("unroll")                                                                      \
  for (int i_ = 0; i_ < 4; ++i_) {                                                       \
    _Pragma("unroll")                                                                    \
    for (int j_ = 0; j_ < NJ; ++j_)                                                      \
      acc[(i0) + i_][j_] = __builtin_amdgcn_mfma_f32_16x16x32_bf16(                      \
          aq[i_], bq[j_], acc[(i0) + i_][j_], 0, 0, 0);                                  \
  }
#define BARF asm volatile("s_barrier" ::: "memory")
#define VMC6 asm volatile("s_waitcnt vmcnt(6)" ::: "memory")
#define VMC3 asm volatile("s_waitcnt vmcnt(3)" ::: "memory")
#define VMC0 asm volatile("s_waitcnt vmcnt(0)" ::: "memory")
#define P1   __builtin_amdgcn_s_setprio(1)
#define P0   __builtin_amdgcn_s_setprio(0)

// r6 per-tile schedule (256-row tiles):
#define TILEK(KT, CURB, NXTB)                                                            \
  do {                                                                                   \
    RDA(0, 0, CURB); RDB(0, CURB);                                                       \
    if ((KT) + 1 < NT) stgA((KT) + 1, 1, (NXTB));                                        \
    BARF; P1; MFQ(0); P0; BARF;                                                          \
    RDA(4, 0, CURB);                                                                     \
    if ((KT) + 1 < NT) stgB((KT) + 1, 1, (NXTB));                                        \
    BARF; P1; MFQ(4); P0;                                                                \
    VMC6; BARF;                                                                          \
    RDA(0, 1, CURB); RDB(1, CURB);                                                       \
    if ((KT) + 2 < NT) stgA((KT) + 2, 0, (CURB));                                        \
    BARF; P1; MFQ(0); P0; BARF;                                                          \
    RDA(4, 1, CURB);                                                                     \
    if ((KT) + 2 < NT) stgB((KT) + 2, 0, (CURB));                                        \
    BARF; P1; MFQ(4); P0;                                                                \
    if ((KT) < NT - 2) { VMC6; } else { VMC0; }                                          \
    BARF;                                                                                \
  } while (0)

// ---- 256xBN pipelined bf16 GEMM (r6 structure), C = A * B^T ----
// MODE 2: f32 store (ld=DD) with runtime NT = 2*ceil(ncnt/128) per batch
// MODE 3: bf16 store (ld=DD), static K
template <int MODE, int NJ>
__global__ __launch_bounds__(512, 2) void gemm256(
    const unsigned short* __restrict__ A, const unsigned short* __restrict__ Bm,
    unsigned short* __restrict__ Cq, float* __restrict__ Cf,
    int K, int lda, int ldb,
    long aStride, long bStride, long cStride,
    const int* __restrict__ ncnt) {
  extern __shared__ unsigned short smem[];      // 65536 elems = 131072 B
  const int BN = NJ * 64;

  const int t = threadIdx.x;
  int bx = blockIdx.x, by = blockIdx.y, bz = blockIdx.z;
  {  // bijective XCD swizzle (all grids are %8==0)
    const int gx = gridDim.x, gy = gridDim.y;
    const int nwg = gx * gy * (int)gridDim.z;
    int id = bx + gx * (by + gy * bz);
    int sw = (id & 7) * (nwg >> 3) + (id >> 3);
    bx = sw % gx; int r2 = sw / gx;
    by = r2 % gy; bz = r2 / gy;
  }
  const int n0 = bx * BN, m0 = by * 256;
  const int NT = (MODE == 2) ? (((ncnt[bz] + 127) >> 7) << 1) : (K >> 6);

  const unsigned short* Ab = A + (size_t)bz * aStride;
  const unsigned short* Bb = Bm + (size_t)bz * bStride;

  const int lane = t & 63;
  const int w = t >> 6;
  const int wm = w >> 2, wn = w & 3;
  const int frow = lane & 15;
  const int kg8 = (lane >> 4) * 8;
  const int arow0 = (wm * 128 + frow) * 32;
  const int brow0 = (wn * (NJ * 16) + frow) * 32;

  const int srow = t >> 2;
  const int scol8 = (t & 3) * 8;
  const unsigned short* Asrc = Ab + (size_t)(m0 + srow) * lda + scol8;
  const unsigned short* Bsrc = Bb + (size_t)(n0 + srow) * ldb + scol8;
  const int sdst = w * 512;

  auto stgA = [&](int kt, int ks, int bufb) {
    const unsigned short* s = Asrc + kt * 64 + ks * 32;
    gload_lds16(s, &smem[bufb + ks * 8192 + sdst]);
    gload_lds16(s + (size_t)128 * lda, &smem[bufb + ks * 8192 + 4096 + sdst]);
  };
  auto stgB = [&](int kt, int ks, int bufb) {
    const unsigned short* s = Bsrc + kt * 64 + ks * 32;
    gload_lds16(s, &smem[bufb + 16384 + ks * 8192 + sdst]);
    gload_lds16(s + (size_t)128 * ldb, &smem[bufb + 16384 + ks * 8192 + 4096 + sdst]);
  };

  f32x4 acc[8][NJ] = {};
  bf16v8 aq[4], bq[NJ];

  stgA(0, 0, 0);     stgB(0, 0, 0);
  stgA(0, 1, 0);     stgB(0, 1, 0);
  stgA(1, 0, 32768); stgB(1, 0, 32768);
  asm volatile("s_waitcnt vmcnt(8)" ::: "memory");
  BARF;

  for (int ktp = 0; ktp < NT; ktp += 2) {
    TILEK(ktp, 0, 32768);
    TILEK(ktp + 1, 32768, 0);
  }

  // Epilogue. C/D layout: col = lane&15, row = (lane>>4)*4 + reg  [HW-verified]
  const int r0 = (lane >> 4) * 4;
  const int c0 = lane & 15;
  const int mrowB = m0 + wm * 128 + r0;
  const int ncolB = n0 + wn * (NJ * 16) + c0;

  if (MODE == 3) {
#pragma unroll
    for (int i = 0; i < 8; ++i)
#pragma unroll
      for (int j = 0; j < NJ; ++j)
#pragma unroll
        for (int r = 0; r < 4; ++r)
          Cq[(size_t)(mrowB + i * 16 + r) * DD + (ncolB + j * 16)] = f2b(acc[i][j][r]);
  } else {
    float* dst = Cf + (size_t)bz * cStride;
#pragma unroll
    for (int i = 0; i < 8; ++i)
#pragma unroll
      for (int j = 0; j < NJ; ++j)
#pragma unroll
        for (int r = 0; r < 4; ++r)
          dst[(size_t)(mrowB + i * 16 + r) * DD + (ncolB + j * 16)] = acc[i][j][r];
  }
}

// ---- K/V projection on COMPACTED tokens: [Kc|Vtc] = Xc * Wkv^T (persistent items) ----
template <int NJ, int NTT>
__global__ __launch_bounds__(512, 2) void gemmKV(
    const unsigned short* __restrict__ Xc, const unsigned short* __restrict__ Wcat,
    unsigned short* __restrict__ Kc, unsigned short* __restrict__ Vtc,
    const int* __restrict__ ncnt) {
  extern __shared__ unsigned short smem[];      // 131072 B
  constexpr int NT = NTT;

  int offv[9]; offv[0] = 0;
#pragma unroll
  for (int i = 0; i < 8; ++i) offv[i + 1] = offv[i] + ((ncnt[i] + 255) & ~255);
  const int GT = offv[8] >> 8;
  const int id = (int)blockIdx.x;
  if (id >= GT * 8) return;
  const int gt = id >> 3, ni = id & 7;
  int b = 0;
#pragma unroll
  for (int i = 1; i < 8; ++i) if (offv[i] <= gt * 256) b = i;
  const int off_b = offv[b];

  const int t = threadIdx.x;
  const int lane = t & 63;
  const int w = t >> 6;
  const int wm = w >> 2, wn = w & 3;
  const int frow = lane & 15;
  const int kg8 = (lane >> 4) * 8;
  const int arow0 = (wm * 128 + frow) * 32;
  const int brow0 = (wn * (NJ * 16) + frow) * 32;
  const int srow = t >> 2;
  const int scol8 = (t & 3) * 8;
  const int sdst = w * 512;

  const unsigned short* Asrc = Xc + (size_t)(gt * 256 + srow) * DD + scol8;
  const unsigned short* Bsrc = Wcat + (size_t)(768 + ni * (NJ * 64) + srow) * DD + scol8;

  auto stgA = [&](int kt, int ks, int bufb) {
    const unsigned short* s = Asrc + kt * 64 + ks * 32;
    gload_lds16(s, &smem[bufb + ks * 8192 + sdst]);
    gload_lds16(s + (size_t)128 * DD, &smem[bufb + ks * 8192 + 4096 + sdst]);
  };
  auto stgB = [&](int kt, int ks, int bufb) {
    const unsigned short* s = Bsrc + kt * 64 + ks * 32;
    gload_lds16(s, &smem[bufb + 16384 + ks * 8192 + sdst]);
    gload_lds16(s + (size_t)128 * DD, &smem[bufb + 16384 + ks * 8192 + 4096 + sdst]);
  };

  f32x4 acc[8][NJ] = {};
  bf16v8 aq[4], bq[NJ];

  stgA(0, 0, 0);     stgB(0, 0, 0);
  stgA(0, 1, 0);     stgB(0, 1, 0);
  stgA(1, 0, 32768); stgB(1, 0, 32768);
  asm volatile("s_waitcnt vmcnt(8)" ::: "memory");
  BARF;

  for (int ktp = 0; ktp < NT; ktp += 2) {
    TILEK(ktp, 0, 32768);
    TILEK(ktp + 1, 32768, 0);
  }

  const int r0 = (lane >> 4) * 4;
  const int c0 = lane & 15;
  const int rowL = wm * 128 + r0;
  const int ncolL = ni * (NJ * 64) + wn * (NJ * 16) + c0;
  const int cbase = gt * 256 - off_b + rowL;

  if (ni < 4) {   // K region: dense compacted rows, ld=768
    unsigned short* dst = Kc + (size_t)b * NN * DD;
#pragma unroll
    for (int i = 0; i < 8; ++i)
#pragma unroll
      for (int j = 0; j < NJ; ++j)
#pragma unroll
        for (int r = 0; r < 4; ++r)
          dst[(size_t)(cbase + i * 16 + r) * DD + (ncolL + j * 16)] = f2b(acc[i][j][r]);
  } else {        // V region: transposed, dense compacted cols (vectorized over r)
#pragma unroll
    for (int i = 0; i < 8; ++i) {
#pragma unroll
      for (int j = 0; j < NJ; ++j) {
        const int e = ncolL + j * 16 - 768;
        ushort4v pk;
#pragma unroll
        for (int r = 0; r < 4; ++r) pk[r] = f2b(acc[i][j][r]);
        *(ushort4v*)&Vtc[((size_t)b * DD + e) * NN + cbase + i * 16] = pk;
      }
    }
  }
}

// ---- Persistent scores GEMM, 128x256 items: S[b][m][c] = Q[b][m] . Kc[b][c] ----
// items = sum_b ceil(nc/256) x 16 m-tiles (n-major). 2-phase/K-tile schedule (half-mirror
// of the r6 ledger): 3 gloads/phase, steady vmcnt(3) keeps ks0(t+1) in flight; tail vmcnt(0).
// LDS 96KB: buf at beta*24576; A-ks at +ks*4096 (128x32); B-ks at +8192+ks*8192 (256x32).
__global__ __launch_bounds__(512, 2) void gemm1P(
    const unsigned short* __restrict__ Qa, const unsigned short* __restrict__ Kn,
    unsigned short* __restrict__ So, const int* __restrict__ ncnt) {
  extern __shared__ unsigned short smem[];      // 49152 elems = 98304 B
  constexpr int NT = 12;

  const int t = threadIdx.x;
  const int lane = t & 63;
  const int w = t >> 6;
  const int wm = w >> 2, wn = w & 3;
  const int frow = lane & 15;
  const int kg8 = (lane >> 4) * 8;
  const int arow0 = (wm * 64 + frow) * 32;     // wave rows: wm*64 + i*16 + frow
  const int brow0 = (wn * 64 + frow) * 32;     // wave cols: wn*64 + j*16 + frow
  const int srow = t >> 2;
  const int scol8 = (t & 3) * 8;
  const int sdst = w * 512;
  const int r0 = (lane >> 4) * 4;
  const int c0 = lane & 15;

  int nbv[8];
#pragma unroll
  for (int b_ = 0; b_ < 8; ++b_) nbv[b_] = (ncnt[b_] + 255) >> 8;

  f32x4 acc[4][4];
  bf16v8 aq[4], bq[4];

#pragma unroll 1
  for (int it = 0; it < 4; ++it) {
    int rem = (int)blockIdx.x + it * 256;
    int b = 0;
#pragma unroll 1
    for (; b < 8; ++b) { int c = nbv[b] * 16; if (rem < c) break; rem -= c; }
    if (b >= 8) break;
    const int ni = rem >> 4, mi = rem & 15;    // n-major: 16 consecutive items share B panel
    const int m0 = mi * 128, n0 = ni * 256;

    const unsigned short* Asrc = Qa + ((size_t)b * NN + m0 + srow) * DD + scol8;
    const unsigned short* Bsrc = Kn + ((size_t)b * NN + n0 + srow) * DD + scol8;

    // A halftile (128x32) = 1 gload; B (256x32) = 2 gloads
    auto stgA = [&](int kt, int ks, int bufb) {
      gload_lds16(Asrc + kt * 64 + ks * 32, &smem[bufb + ks * 4096 + sdst]);
    };
    auto stgB = [&](int kt, int ks, int bufb) {
      const unsigned short* s = Bsrc + kt * 64 + ks * 32;
      gload_lds16(s, &smem[bufb + 8192 + ks * 8192 + sdst]);
      gload_lds16(s + (size_t)128 * DD, &smem[bufb + 8192 + ks * 8192 + 4096 + sdst]);
    };

#pragma unroll
    for (int i = 0; i < 4; ++i)
#pragma unroll
      for (int j = 0; j < 4; ++j) acc[i][j] = f32x4{0.f, 0.f, 0.f, 0.f};

    // prologue: ks0(0), ks1(0), ks0(1); vmcnt(3) retires tile0 (first 6 loads)
    stgA(0, 0, 0);     stgB(0, 0, 0);
    stgA(0, 1, 0);     stgB(0, 1, 0);
    stgA(1, 0, 24576); stgB(1, 0, 24576);
    VMC3;
    BARF;

#pragma unroll 1
    for (int kt = 0; kt < NT; ++kt) {
      const int cur = (kt & 1) ? 24576 : 0;
      const int nxt = cur ^ 24576;
      // ---- phase 1: ks0 reads+MFMA; stage ks1(t+1) -> nxt
#pragma unroll
      for (int i_ = 0; i_ < 4; ++i_)
        aq[i_] = *(const bf16v8*)&smem[cur + arow0 + i_ * 512 + kg8];
#pragma unroll
      for (int j_ = 0; j_ < 4; ++j_)
        bq[j_] = *(const bf16v8*)&smem[cur + 8192 + brow0 + j_ * 512 + kg8];
      if (kt + 1 < NT) { stgA(kt + 1, 1, nxt); stgB(kt + 1, 1, nxt); }
      BARF; P1;
#pragma unroll
      for (int i_ = 0; i_ < 4; ++i_)
#pragma unroll
        for (int j_ = 0; j_ < 4; ++j_)
          acc[i_][j_] = __builtin_amdgcn_mfma_f32_16x16x32_bf16(aq[i_], bq[j_], acc[i_][j_], 0, 0, 0);
      P0; BARF;
      // ---- phase 2: ks1 reads+MFMA; stage ks0(t+2) -> cur; counted vmcnt
#pragma unroll
      for (int i_ = 0; i_ < 4; ++i_)
        aq[i_] = *(const bf16v8*)&smem[cur + 4096 + arow0 + i_ * 512 + kg8];
#pragma unroll
      for (int j_ = 0; j_ < 4; ++j_)
        bq[j_] = *(const bf16v8*)&smem[cur + 16384 + brow0 + j_ * 512 + kg8];
      if (kt + 2 < NT) { stgA(kt + 2, 0, cur); stgB(kt + 2, 0, cur); }
      BARF; P1;
#pragma unroll
      for (int i_ = 0; i_ < 4; ++i_)
#pragma unroll
        for (int j_ = 0; j_ < 4; ++j_)
          acc[i_][j_] = __builtin_amdgcn_mfma_f32_16x16x32_bf16(aq[i_], bq[j_], acc[i_][j_], 0, 0, 0);
      P0;
      if (kt < NT - 2) { VMC3; } else { VMC0; }
      BARF;
    }

    unsigned short* dst = So + (size_t)b * NN * NN;
    const int mrowB = m0 + wm * 64 + r0;
    const int ncolB = n0 + wn * 64 + c0;
#pragma unroll
    for (int i = 0; i < 4; ++i)
#pragma unroll
      for (int j = 0; j < 4; ++j)
#pragma unroll
        for (int r = 0; r < 4; ++r)
          dst[(size_t)(mrowB + i * 16 + r) * NN + (ncolB + j * 16)] = f2b(acc[i][j][r]);
  }
}

// ---------------- compacted softmax: cols [0,nc) valid, zero-fill [nc,r128), skip rest ----------------
__global__ __launch_bounds__(256) void softmax_c(unsigned short* __restrict__ S,
                                                 const int* __restrict__ ncnt) {
  int row = blockIdx.x;            // 0..16383
  int bb = row >> 11;
  const int nc = ncnt[bb];
  const int p128 = (nc + 127) & ~127;
  unsigned short* sr = S + (size_t)row * NN;
  int t = threadIdx.x;
  const int cbase = t * 8;

  float v[8];
  const bool anyload = cbase < nc;
  ushort8v pk;
  if (anyload) pk = *(const ushort8v*)&sr[cbase];
  float mx = -1e30f;
#pragma unroll
  for (int j = 0; j < 8; ++j) {
    v[j] = anyload ? b2f(pk[j]) : 0.f;
    if (cbase + j < nc) mx = fmaxf(mx, v[j]);
  }
  for (int o = 32; o > 0; o >>= 1) mx = fmaxf(mx, __shfl_xor(mx, o));
  __shared__ float redm[4], reds[4];
  int w = t >> 6, lane = t & 63;
  if (lane == 0) redm[w] = mx;
  __syncthreads();
  mx = fmaxf(fmaxf(redm[0], redm[1]), fmaxf(redm[2], redm[3]));

  float e[8];
  float sum = 0.f;
#pragma unroll
  for (int j = 0; j < 8; ++j) {
    e[j] = (cbase + j < nc) ? __expf(v[j] - mx) : 0.f;
    sum += e[j];
  }
  for (int o = 32; o > 0; o >>= 1) sum += __shfl_xor(sum, o);
  if (lane == 0) reds[w] = sum;
  __syncthreads();
  sum = reds[0] + reds[1] + reds[2] + reds[3];
  float inv = 1.0f / sum;

  if (cbase < p128) {
    ushort8v op;
#pragma unroll
    for (int j = 0; j < 8; ++j) op[j] = f2b(e[j] * inv);
    *(ushort8v*)&sr[cbase] = op;
  }
}

extern "C" void kernel_launch(void* const* d_in, const int* in_sizes, int n_in,
                              void* d_out, int out_size, void* d_ws, size_t ws_size,
                              hipStream_t stream) {
  const float* features = (const float*)d_in[0];
  const int* mask       = (const int*)d_in[1];
  const float* Wq       = (const float*)d_in[2];
  const float* Wk       = (const float*)d_in[3];
  const float* Wv       = (const float*)d_in[4];
  const float* gamma    = (const float*)d_in[5];
  const float* beta     = (const float*)d_in[6];
  float* out = (float*)d_out;

  char* ws = (char*)d_ws;
  size_t off = 0;
  auto alloc = [&](size_t bytes) {
    char* p = ws + off;
    off += (bytes + 255) & ~(size_t)255;
    return p;
  };
  // Wcat padded by 64 rows (192-wide B staging over-reads at the last n-tile)
  unsigned short* Wcat = (unsigned short*)alloc((size_t)(2304 + 64) * DD * 2);
  unsigned short* Qb   = (unsigned short*)alloc((size_t)BB * NN * DD * 2);
  unsigned short* Kc   = (unsigned short*)alloc((size_t)BB * NN * DD * 2);   // compacted K rows
  unsigned short* Vtc  = (unsigned short*)alloc(((size_t)BB * DD + 64) * NN * 2);  // compacted Vt cols
  int* kidx = (int*)alloc((size_t)BB * NN * 4);
  int* ncnt = (int*)alloc(64 * 4);
  // S (67 MB): Xb aliases its first 25 MB; Xc aliases its upper half (dead before gemm1P writes S).
  char* last = alloc((size_t)BB * NN * NN * 2);
  unsigned short* Sb = (unsigned short*)last;
  unsigned short* Xb = (unsigned short*)last;
  unsigned short* Xc = (unsigned short*)(last + (size_t)34 * 1024 * 1024);

  (void)hipFuncSetAttribute(reinterpret_cast<const void*>(&gemm256<3, 3>),
                            hipFuncAttributeMaxDynamicSharedMemorySize, 131072);
  (void)hipFuncSetAttribute(reinterpret_cast<const void*>(&gemmKV<3, 12>),
                            hipFuncAttributeMaxDynamicSharedMemorySize, 131072);
  (void)hipFuncSetAttribute(reinterpret_cast<const void*>(&gemm1P),
                            hipFuncAttributeMaxDynamicSharedMemorySize, 98304);
  (void)hipFuncSetAttribute(reinterpret_cast<const void*>(&gemm256<2, 3>),
                            hipFuncAttributeMaxDynamicSharedMemorySize, 131072);

  ln_kernel<<<BB * NN, 256, 0, stream>>>(features, gamma, beta, Xb);
  wconvert<<<(3 * DD * DD + 255) / 256, 256, 0, stream>>>(Wq, Wk, Wv, Wcat);
  mask_scan<<<BB, 256, 0, stream>>>(mask, kidx, ncnt);
  xc_gather<<<dim3(128, BB), 256, 0, stream>>>(Xb, kidx, ncnt, Xc);

  // Q projection: [16384,768] x [768,768]^T ; 4x64 = 256 blocks = 1.0/CU exact
  gemm256<3, 3><<<dim3(4, 64, 1), 512, 131072, stream>>>(
      Xb, Wcat, Qb, nullptr, DD, DD, DD, 0, 0, 0, ncnt);

  // K/V projection on compacted tokens: ~half the work, outputs pre-compacted
  gemmKV<3, 12><<<512, 512, 131072, stream>>>(Xc, Wcat, Kc, Vtc, ncnt);

  // Scores (dense compacted keys, persistent 128x256 items): S[b][m][c] bf16
  gemm1P<<<256, 512, 98304, stream>>>(Qb, Kc, Sb, ncnt);

  softmax_c<<<BB * NN, 256, 0, stream>>>(Sb, ncnt);

  // Context (compacted K-dim): per batch P[2048,r128] x Vtc[768,r128]^T -> f32 out
  gemm256<2, 3><<<dim3(DD / 192, NN / 256, BB), 512, 131072, stream>>>(
      Sb, Vtc, nullptr, out, NN, NN, NN,
      (long)NN * NN, (long)DD * NN, (long)NN * DD, ncnt);
}

// Round 16
// 213.784 us; speedup vs baseline: 1.2977x; 1.0171x over previous
//
#include <hip/hip_runtime.h>
#include <hip/hip_bf16.h>
#include <cstdint>

typedef __attribute__((ext_vector_type(8))) __bf16 bf16v8;
typedef __attribute__((ext_vector_type(4))) float f32x4;
typedef __attribute__((ext_vector_type(4))) unsigned short ushort4v;
typedef __attribute__((ext_vector_type(8))) unsigned short ushort8v;

#define BB 8
#define NN 2048
#define DD 768

__device__ __forceinline__ float b2f(unsigned short u) {
  union { unsigned int i; float f; } c; c.i = ((unsigned int)u) << 16; return c.f;
}
__device__ __forceinline__ unsigned short f2b(float f) {
  union { float f; unsigned int i; } c; c.f = f;
  unsigned int u = c.i;
  return (unsigned short)((u + 0x7fffu + ((u >> 16) & 1u)) >> 16);
}

// ---------------- prep: LayerNorm ∪ Wconvert ∪ mask_scan (block-partitioned) ----------------
__global__ __launch_bounds__(256) void prep(
    const float* __restrict__ x, const float* __restrict__ gamma, const float* __restrict__ beta,
    unsigned short* __restrict__ xb,
    const float* __restrict__ Wq, const float* __restrict__ Wk, const float* __restrict__ Wv,
    unsigned short* __restrict__ Wcat,
    const int* __restrict__ mask, int* __restrict__ kidx, int* __restrict__ ncnt) {
  __shared__ float red[2][4];
  __shared__ int wsum[4];
  const int bid = blockIdx.x;
  const int t = threadIdx.x;

  if (bid < BB * NN) {
    // ---- LayerNorm row ----
    const int row = bid;
    const float* xr = x + (size_t)row * DD;
    float a0 = xr[t], a1 = xr[t + 256], a2 = xr[t + 512];
    float s = a0 + a1 + a2;
    float q = a0 * a0 + a1 * a1 + a2 * a2;
    for (int o = 32; o > 0; o >>= 1) { s += __shfl_xor(s, o); q += __shfl_xor(q, o); }
    int w = t >> 6, lane = t & 63;
    if (lane == 0) { red[0][w] = s; red[1][w] = q; }
    __syncthreads();
    s = red[0][0] + red[0][1] + red[0][2] + red[0][3];
    q = red[1][0] + red[1][1] + red[1][2] + red[1][3];
    float mean = s * (1.0f / DD);
    float var = q * (1.0f / DD) - mean * mean;
    float inv = rsqrtf(var + 1e-5f);
    unsigned short* o0 = xb + (size_t)row * DD;
    o0[t]       = f2b((a0 - mean) * inv * gamma[t]       + beta[t]);
    o0[t + 256] = f2b((a1 - mean) * inv * gamma[t + 256] + beta[t + 256]);
    o0[t + 512] = f2b((a2 - mean) * inv * gamma[t + 512] + beta[t + 512]);
  } else if (bid < BB * NN + 6912) {
    // ---- weight concat/convert (scale folded into Wq) ----
    const int i = (bid - BB * NN) * 256 + t;
    const int dd = DD * DD;
    if (i < 3 * dd) {
      float v;
      if (i < dd)           v = Wq[i] * 0.03608439182435161f;   // 1/sqrt(768)
      else if (i < 2 * dd)  v = Wk[i - dd];
      else                  v = Wv[i - 2 * dd];
      Wcat[i] = f2b(v);
    }
  } else {
    // ---- mask prefix scan: kidx / ncnt ----
    const int b = bid - (BB * NN + 6912);
    const int* mr = mask + b * NN;
#pragma unroll
    for (int j = 0; j < 8; ++j) kidx[b * NN + t * 8 + j] = 0;
    int v[8]; int s = 0;
#pragma unroll
    for (int j = 0; j < 8; ++j) { v[j] = (mr[t * 8 + j] == 0) ? 1 : 0; s += v[j]; }
    int lane = t & 63, w = t >> 6;
    int xp = s;
    for (int o = 1; o < 64; o <<= 1) { int y = __shfl_up(xp, o); if (lane >= o) xp += y; }
    if (lane == 63) wsum[w] = xp;
    __syncthreads();
    int base = 0;
#pragma unroll
    for (int i = 0; i < 4; ++i) if (i < w) base += wsum[i];
    int run = base + xp - s;
#pragma unroll
    for (int j = 0; j < 8; ++j) { if (v[j]) kidx[b * NN + run] = t * 8 + j; run += v[j]; }
    if (t == 255) ncnt[b] = base + xp;
  }
}

// ------------- X row compaction: Xc[off[b]+c][:] = Xb[b][kidx[c]][:] (c<nc), 0 for [nc,r256) -------------
__global__ __launch_bounds__(256) void xc_gather(const unsigned short* __restrict__ Xb,
                                                 const int* __restrict__ kidx,
                                                 const int* __restrict__ ncnt,
                                                 unsigned short* __restrict__ Xc) {
  const int b = blockIdx.y;
  const int nc = ncnt[b];
  const int r256 = (nc + 255) & ~255;
  const int row0 = blockIdx.x * 16;
  if (row0 >= r256) return;
  int off = 0;
#pragma unroll
  for (int i = 0; i < 8; ++i) if (i < b) off += (ncnt[i] + 255) & ~255;
  for (int u = threadIdx.x; u < 16 * 96; u += 256) {
    const int r = row0 + u / 96;
    const int ch = (u % 96) * 8;
    if (r >= r256) continue;
    ushort8v val = {0, 0, 0, 0, 0, 0, 0, 0};
    if (r < nc)
      val = *(const ushort8v*)&Xb[((size_t)b * NN + kidx[b * NN + r]) * DD + ch];
    *(ushort8v*)&Xc[(size_t)(off + r) * DD + ch] = val;
  }
}

// ---------------- async global->LDS (16B per lane, wave-uniform LDS base) ----------------
__device__ __forceinline__ void gload_lds16(const void* g, void* l) {
  __builtin_amdgcn_global_load_lds(
      (const __attribute__((address_space(1))) void*)g,
      (__attribute__((address_space(3))) void*)(unsigned)(uintptr_t)l,
      16, 0, 0);
}

// LDS geometry (elements): buffer b at b*32768.
//   slot A-ks at  buf + ks*8192          (256 rows x 32 cols, 64B rows)
//   slot B-ks at  buf + 16384 + ks*8192
#define RDA(i0, ks, B)                                                                   \
  _Pragma("unroll")                                                                      \
  for (int i_ = 0; i_ < 4; ++i_)                                                         \
    aq[i_] = *(const bf16v8*)&smem[(B) + (ks) * 8192 + arow0 + ((i0) + i_) * 512 + kg8];
#define RDB(ks, B)                                                                       \
  _Pragma("unroll")                                                                      \
  for (int j_ = 0; j_ < NJ; ++j_)                                                        \
    bq[j_] = *(const bf16v8*)&smem[(B) + 16384 + (ks) * 8192 + brow0 + j_ * 512 + kg8];
#define MFQ(i0)                                                                          \
  _Pragma("unroll")                                                                      \
  for (int i_ = 0; i_ < 4; ++i_) {                                                       \
    _Pragma("unroll")                                                                    \
    for (int j_ = 0; j_ < NJ; ++j_)                                                      \
      acc[(i0) + i_][j_] = __builtin_amdgcn_mfma_f32_16x16x32_bf16(                      \
          aq[i_], bq[j_], acc[(i0) + i_][j_], 0, 0, 0);                                  \
  }
#define BARF asm volatile("s_barrier" ::: "memory")
#define VMC6 asm volatile("s_waitcnt vmcnt(6)" ::: "memory")
#define VMC3 asm volatile("s_waitcnt vmcnt(3)" ::: "memory")
#define VMC0 asm volatile("s_waitcnt vmcnt(0)" ::: "memory")
#define P1   __builtin_amdgcn_s_setprio(1)
#define P0   __builtin_amdgcn_s_setprio(0)

// r6 per-tile schedule (256-row tiles):
#define TILEK(KT, CURB, NXTB)                                                            \
  do {                                                                                   \
    RDA(0, 0, CURB); RDB(0, CURB);                                                       \
    if ((KT) + 1 < NT) stgA((KT) + 1, 1, (NXTB));                                        \
    BARF; P1; MFQ(0); P0; BARF;                                                          \
    RDA(4, 0, CURB);                                                                     \
    if ((KT) + 1 < NT) stgB((KT) + 1, 1, (NXTB));                                        \
    BARF; P1; MFQ(4); P0;                                                                \
    VMC6; BARF;                                                                          \
    RDA(0, 1, CURB); RDB(1, CURB);                                                       \
    if ((KT) + 2 < NT) stgA((KT) + 2, 0, (CURB));                                        \
    BARF; P1; MFQ(0); P0; BARF;                                                          \
    RDA(4, 1, CURB);                                                                     \
    if ((KT) + 2 < NT) stgB((KT) + 2, 0, (CURB));                                        \
    BARF; P1; MFQ(4); P0;                                                                \
    if ((KT) < NT - 2) { VMC6; } else { VMC0; }                                          \
    BARF;                                                                                \
  } while (0)

// ---- context GEMM (r6 structure), C = A * B^T, f32 store, runtime NT = 2*ceil(nc/128) ----
template <int NJ>
__global__ __launch_bounds__(512, 2) void gemmCtx(
    const unsigned short* __restrict__ A, const unsigned short* __restrict__ Bm,
    float* __restrict__ Cf, int lda, int ldb,
    long aStride, long bStride, long cStride,
    const int* __restrict__ ncnt) {
  extern __shared__ unsigned short smem[];      // 65536 elems = 131072 B
  const int BN = NJ * 64;

  const int t = threadIdx.x;
  int bx = blockIdx.x, by = blockIdx.y, bz = blockIdx.z;
  {  // bijective XCD swizzle (grid %8==0)
    const int gx = gridDim.x, gy = gridDim.y;
    const int nwg = gx * gy * (int)gridDim.z;
    int id = bx + gx * (by + gy * bz);
    int sw = (id & 7) * (nwg >> 3) + (id >> 3);
    bx = sw % gx; int r2 = sw / gx;
    by = r2 % gy; bz = r2 / gy;
  }
  const int n0 = bx * BN, m0 = by * 256;
  const int NT = ((ncnt[bz] + 127) >> 7) << 1;

  const unsigned short* Ab = A + (size_t)bz * aStride;
  const unsigned short* Bb = Bm + (size_t)bz * bStride;

  const int lane = t & 63;
  const int w = t >> 6;
  const int wm = w >> 2, wn = w & 3;
  const int frow = lane & 15;
  const int kg8 = (lane >> 4) * 8;
  const int arow0 = (wm * 128 + frow) * 32;
  const int brow0 = (wn * (NJ * 16) + frow) * 32;

  const int srow = t >> 2;
  const int scol8 = (t & 3) * 8;
  const unsigned short* Asrc = Ab + (size_t)(m0 + srow) * lda + scol8;
  const unsigned short* Bsrc = Bb + (size_t)(n0 + srow) * ldb + scol8;
  const int sdst = w * 512;

  auto stgA = [&](int kt, int ks, int bufb) {
    const unsigned short* s = Asrc + kt * 64 + ks * 32;
    gload_lds16(s, &smem[bufb + ks * 8192 + sdst]);
    gload_lds16(s + (size_t)128 * lda, &smem[bufb + ks * 8192 + 4096 + sdst]);
  };
  auto stgB = [&](int kt, int ks, int bufb) {
    const unsigned short* s = Bsrc + kt * 64 + ks * 32;
    gload_lds16(s, &smem[bufb + 16384 + ks * 8192 + sdst]);
    gload_lds16(s + (size_t)128 * ldb, &smem[bufb + 16384 + ks * 8192 + 4096 + sdst]);
  };

  f32x4 acc[8][NJ] = {};
  bf16v8 aq[4], bq[NJ];

  stgA(0, 0, 0);     stgB(0, 0, 0);
  stgA(0, 1, 0);     stgB(0, 1, 0);
  stgA(1, 0, 32768); stgB(1, 0, 32768);
  asm volatile("s_waitcnt vmcnt(8)" ::: "memory");
  BARF;

  for (int ktp = 0; ktp < NT; ktp += 2) {
    TILEK(ktp, 0, 32768);
    TILEK(ktp + 1, 32768, 0);
  }

  const int r0 = (lane >> 4) * 4;
  const int c0 = lane & 15;
  const int mrowB = m0 + wm * 128 + r0;
  const int ncolB = n0 + wn * (NJ * 16) + c0;
  float* dst = Cf + (size_t)bz * cStride;
#pragma unroll
  for (int i = 0; i < 8; ++i)
#pragma unroll
    for (int j = 0; j < NJ; ++j)
#pragma unroll
      for (int r = 0; r < 4; ++r)
        dst[(size_t)(mrowB + i * 16 + r) * DD + (ncolB + j * 16)] = acc[i][j][r];
}

// ---- Merged Q + K/V projection (independent halves, one dispatch) ----
// id < 256:      Q items  (64 m-tiles x 4 n-tiles): Q = Xb * Wcat[0:768]^T
// id in [256..): KV items (GT x 8 n-tiles):        [Kc|Vtc] = Xc * Wcat[768:2304]^T
// Pipeline identical for both (NJ=3, NT=12, lda=ldb=DD).
template <int NJ>
__global__ __launch_bounds__(512, 2) void gemmQKV(
    const unsigned short* __restrict__ Xb, const unsigned short* __restrict__ Xc,
    const unsigned short* __restrict__ Wcat,
    unsigned short* __restrict__ Qb, unsigned short* __restrict__ Kc,
    unsigned short* __restrict__ Vtc, const int* __restrict__ ncnt) {
  extern __shared__ unsigned short smem[];      // 131072 B
  constexpr int NT = 12;

  const int t = threadIdx.x;
  const int id = (int)blockIdx.x;

  const int lane = t & 63;
  const int w = t >> 6;
  const int wm = w >> 2, wn = w & 3;
  const int frow = lane & 15;
  const int kg8 = (lane >> 4) * 8;
  const int arow0 = (wm * 128 + frow) * 32;
  const int brow0 = (wn * (NJ * 16) + frow) * 32;
  const int srow = t >> 2;
  const int scol8 = (t & 3) * 8;
  const int sdst = w * 512;

  const bool isQ = id < 256;
  const unsigned short* Asrc;
  const unsigned short* Bsrc;
  int m0 = 0, ncolQ = 0, b = 0, cbase0 = 0, ni = 0;
  if (isQ) {
    m0 = (id >> 2) * 256;
    ncolQ = (id & 3) * 192;
    Asrc = Xb + (size_t)(m0 + srow) * DD + scol8;
    Bsrc = Wcat + (size_t)(ncolQ + srow) * DD + scol8;
  } else {
    int offv[9]; offv[0] = 0;
#pragma unroll
    for (int i = 0; i < 8; ++i) offv[i + 1] = offv[i] + ((ncnt[i] + 255) & ~255);
    const int GT = offv[8] >> 8;
    const int kid = id - 256;
    if (kid >= GT * 8) return;
    const int gt = kid >> 3; ni = kid & 7;
#pragma unroll
    for (int i = 1; i < 8; ++i) if (offv[i] <= gt * 256) b = i;
    cbase0 = gt * 256 - offv[b];
    Asrc = Xc + (size_t)(gt * 256 + srow) * DD + scol8;
    Bsrc = Wcat + (size_t)(768 + ni * (NJ * 64) + srow) * DD + scol8;
  }

  auto stgA = [&](int kt, int ks, int bufb) {
    const unsigned short* s = Asrc + kt * 64 + ks * 32;
    gload_lds16(s, &smem[bufb + ks * 8192 + sdst]);
    gload_lds16(s + (size_t)128 * DD, &smem[bufb + ks * 8192 + 4096 + sdst]);
  };
  auto stgB = [&](int kt, int ks, int bufb) {
    const unsigned short* s = Bsrc + kt * 64 + ks * 32;
    gload_lds16(s, &smem[bufb + 16384 + ks * 8192 + sdst]);
    gload_lds16(s + (size_t)128 * DD, &smem[bufb + 16384 + ks * 8192 + 4096 + sdst]);
  };

  f32x4 acc[8][NJ] = {};
  bf16v8 aq[4], bq[NJ];

  stgA(0, 0, 0);     stgB(0, 0, 0);
  stgA(0, 1, 0);     stgB(0, 1, 0);
  stgA(1, 0, 32768); stgB(1, 0, 32768);
  asm volatile("s_waitcnt vmcnt(8)" ::: "memory");
  BARF;

  for (int ktp = 0; ktp < NT; ktp += 2) {
    TILEK(ktp, 0, 32768);
    TILEK(ktp + 1, 32768, 0);
  }

  const int r0 = (lane >> 4) * 4;
  const int c0 = lane & 15;
  if (isQ) {
    const int mrowB = m0 + wm * 128 + r0;
    const int ncolB = ncolQ + wn * (NJ * 16) + c0;
#pragma unroll
    for (int i = 0; i < 8; ++i)
#pragma unroll
      for (int j = 0; j < NJ; ++j)
#pragma unroll
        for (int r = 0; r < 4; ++r)
          Qb[(size_t)(mrowB + i * 16 + r) * DD + (ncolB + j * 16)] = f2b(acc[i][j][r]);
  } else {
    const int rowL = wm * 128 + r0;
    const int ncolL = ni * (NJ * 64) + wn * (NJ * 16) + c0;
    const int cbase = cbase0 + rowL;
    if (ni < 4) {   // K region: dense compacted rows, ld=768
      unsigned short* dst = Kc + (size_t)b * NN * DD;
#pragma unroll
      for (int i = 0; i < 8; ++i)
#pragma unroll
        for (int j = 0; j < NJ; ++j)
#pragma unroll
          for (int r = 0; r < 4; ++r)
            dst[(size_t)(cbase + i * 16 + r) * DD + (ncolL + j * 16)] = f2b(acc[i][j][r]);
    } else {        // V region: transposed, dense compacted cols (vectorized over r)
#pragma unroll
      for (int i = 0; i < 8; ++i) {
#pragma unroll
        for (int j = 0; j < NJ; ++j) {
          const int e = ncolL + j * 16 - 768;
          ushort4v pk;
#pragma unroll
          for (int r = 0; r < 4; ++r) pk[r] = f2b(acc[i][j][r]);
          *(ushort4v*)&Vtc[((size_t)b * DD + e) * NN + cbase + i * 16] = pk;
        }
      }
    }
  }
}

// ---- Persistent scores GEMM, 128x256 items: S[b][m][c] = Q[b][m] . Kc[b][c] ----
__global__ __launch_bounds__(512, 2) void gemm1P(
    const unsigned short* __restrict__ Qa, const unsigned short* __restrict__ Kn,
    unsigned short* __restrict__ So, const int* __restrict__ ncnt) {
  extern __shared__ unsigned short smem[];      // 49152 elems = 98304 B
  constexpr int NT = 12;

  const int t = threadIdx.x;
  const int lane = t & 63;
  const int w = t >> 6;
  const int wm = w >> 2, wn = w & 3;
  const int frow = lane & 15;
  const int kg8 = (lane >> 4) * 8;
  const int arow0 = (wm * 64 + frow) * 32;
  const int brow0 = (wn * 64 + frow) * 32;
  const int srow = t >> 2;
  const int scol8 = (t & 3) * 8;
  const int sdst = w * 512;
  const int r0 = (lane >> 4) * 4;
  const int c0 = lane & 15;

  int nbv[8];
#pragma unroll
  for (int b_ = 0; b_ < 8; ++b_) nbv[b_] = (ncnt[b_] + 255) >> 8;

  f32x4 acc[4][4];
  bf16v8 aq[4], bq[4];

#pragma unroll 1
  for (int it = 0; it < 4; ++it) {
    int rem = (int)blockIdx.x + it * 256;
    int b = 0;
#pragma unroll 1
    for (; b < 8; ++b) { int c = nbv[b] * 16; if (rem < c) break; rem -= c; }
    if (b >= 8) break;
    const int ni = rem >> 4, mi = rem & 15;
    const int m0 = mi * 128, n0 = ni * 256;

    const unsigned short* Asrc = Qa + ((size_t)b * NN + m0 + srow) * DD + scol8;
    const unsigned short* Bsrc = Kn + ((size_t)b * NN + n0 + srow) * DD + scol8;

    auto stgA = [&](int kt, int ks, int bufb) {
      gload_lds16(Asrc + kt * 64 + ks * 32, &smem[bufb + ks * 4096 + sdst]);
    };
    auto stgB = [&](int kt, int ks, int bufb) {
      const unsigned short* s = Bsrc + kt * 64 + ks * 32;
      gload_lds16(s, &smem[bufb + 8192 + ks * 8192 + sdst]);
      gload_lds16(s + (size_t)128 * DD, &smem[bufb + 8192 + ks * 8192 + 4096 + sdst]);
    };

#pragma unroll
    for (int i = 0; i < 4; ++i)
#pragma unroll
      for (int j = 0; j < 4; ++j) acc[i][j] = f32x4{0.f, 0.f, 0.f, 0.f};

    stgA(0, 0, 0);     stgB(0, 0, 0);
    stgA(0, 1, 0);     stgB(0, 1, 0);
    stgA(1, 0, 24576); stgB(1, 0, 24576);
    VMC3;
    BARF;

#pragma unroll 1
    for (int kt = 0; kt < NT; ++kt) {
      const int cur = (kt & 1) ? 24576 : 0;
      const int nxt = cur ^ 24576;
#pragma unroll
      for (int i_ = 0; i_ < 4; ++i_)
        aq[i_] = *(const bf16v8*)&smem[cur + arow0 + i_ * 512 + kg8];
#pragma unroll
      for (int j_ = 0; j_ < 4; ++j_)
        bq[j_] = *(const bf16v8*)&smem[cur + 8192 + brow0 + j_ * 512 + kg8];
      if (kt + 1 < NT) { stgA(kt + 1, 1, nxt); stgB(kt + 1, 1, nxt); }
      BARF; P1;
#pragma unroll
      for (int i_ = 0; i_ < 4; ++i_)
#pragma unroll
        for (int j_ = 0; j_ < 4; ++j_)
          acc[i_][j_] = __builtin_amdgcn_mfma_f32_16x16x32_bf16(aq[i_], bq[j_], acc[i_][j_], 0, 0, 0);
      P0; BARF;
#pragma unroll
      for (int i_ = 0; i_ < 4; ++i_)
        aq[i_] = *(const bf16v8*)&smem[cur + 4096 + arow0 + i_ * 512 + kg8];
#pragma unroll
      for (int j_ = 0; j_ < 4; ++j_)
        bq[j_] = *(const bf16v8*)&smem[cur + 16384 + brow0 + j_ * 512 + kg8];
      if (kt + 2 < NT) { stgA(kt + 2, 0, cur); stgB(kt + 2, 0, cur); }
      BARF; P1;
#pragma unroll
      for (int i_ = 0; i_ < 4; ++i_)
#pragma unroll
        for (int j_ = 0; j_ < 4; ++j_)
          acc[i_][j_] = __builtin_amdgcn_mfma_f32_16x16x32_bf16(aq[i_], bq[j_], acc[i_][j_], 0, 0, 0);
      P0;
      if (kt < NT - 2) { VMC3; } else { VMC0; }
      BARF;
    }

    unsigned short* dst = So + (size_t)b * NN * NN;
    const int mrowB = m0 + wm * 64 + r0;
    const int ncolB = n0 + wn * 64 + c0;
#pragma unroll
    for (int i = 0; i < 4; ++i)
#pragma unroll
      for (int j = 0; j < 4; ++j)
#pragma unroll
        for (int r = 0; r < 4; ++r)
          dst[(size_t)(mrowB + i * 16 + r) * NN + (ncolB + j * 16)] = f2b(acc[i][j][r]);
  }
}

// ---------------- compacted softmax: cols [0,nc) valid, zero-fill [nc,r128), skip rest ----------------
__global__ __launch_bounds__(256) void softmax_c(unsigned short* __restrict__ S,
                                                 const int* __restrict__ ncnt) {
  int row = blockIdx.x;            // 0..16383
  int bb = row >> 11;
  const int nc = ncnt[bb];
  const int p128 = (nc + 127) & ~127;
  unsigned short* sr = S + (size_t)row * NN;
  int t = threadIdx.x;
  const int cbase = t * 8;

  float v[8];
  const bool anyload = cbase < nc;
  ushort8v pk;
  if (anyload) pk = *(const ushort8v*)&sr[cbase];
  float mx = -1e30f;
#pragma unroll
  for (int j = 0; j < 8; ++j) {
    v[j] = anyload ? b2f(pk[j]) : 0.f;
    if (cbase + j < nc) mx = fmaxf(mx, v[j]);
  }
  for (int o = 32; o > 0; o >>= 1) mx = fmaxf(mx, __shfl_xor(mx, o));
  __shared__ float redm[4], reds[4];
  int w = t >> 6, lane = t & 63;
  if (lane == 0) redm[w] = mx;
  __syncthreads();
  mx = fmaxf(fmaxf(redm[0], redm[1]), fmaxf(redm[2], redm[3]));

  float e[8];
  float sum = 0.f;
#pragma unroll
  for (int j = 0; j < 8; ++j) {
    e[j] = (cbase + j < nc) ? __expf(v[j] - mx) : 0.f;
    sum += e[j];
  }
  for (int o = 32; o > 0; o >>= 1) sum += __shfl_xor(sum, o);
  if (lane == 0) reds[w] = sum;
  __syncthreads();
  sum = reds[0] + reds[1] + reds[2] + reds[3];
  float inv = 1.0f / sum;

  if (cbase < p128) {
    ushort8v op;
#pragma unroll
    for (int j = 0; j < 8; ++j) op[j] = f2b(e[j] * inv);
    *(ushort8v*)&sr[cbase] = op;
  }
}

extern "C" void kernel_launch(void* const* d_in, const int* in_sizes, int n_in,
                              void* d_out, int out_size, void* d_ws, size_t ws_size,
                              hipStream_t stream) {
  const float* features = (const float*)d_in[0];
  const int* mask       = (const int*)d_in[1];
  const float* Wq       = (const float*)d_in[2];
  const float* Wk       = (const float*)d_in[3];
  const float* Wv       = (const float*)d_in[4];
  const float* gamma    = (const float*)d_in[5];
  const float* beta     = (const float*)d_in[6];
  float* out = (float*)d_out;

  char* ws = (char*)d_ws;
  size_t off = 0;
  auto alloc = [&](size_t bytes) {
    char* p = ws + off;
    off += (bytes + 255) & ~(size_t)255;
    return p;
  };
  // Wcat padded by 64 rows (192-wide B staging over-reads at the last n-tile)
  unsigned short* Wcat = (unsigned short*)alloc((size_t)(2304 + 64) * DD * 2);
  unsigned short* Qb   = (unsigned short*)alloc((size_t)BB * NN * DD * 2);
  unsigned short* Kc   = (unsigned short*)alloc((size_t)BB * NN * DD * 2);   // compacted K rows
  unsigned short* Vtc  = (unsigned short*)alloc(((size_t)BB * DD + 64) * NN * 2);  // compacted Vt cols
  int* kidx = (int*)alloc((size_t)BB * NN * 4);
  int* ncnt = (int*)alloc(64 * 4);
  // S (67 MB): Xb aliases its first 25 MB; Xc aliases its upper half (dead before gemm1P writes S).
  char* last = alloc((size_t)BB * NN * NN * 2);
  unsigned short* Sb = (unsigned short*)last;
  unsigned short* Xb = (unsigned short*)last;
  unsigned short* Xc = (unsigned short*)(last + (size_t)34 * 1024 * 1024);

  (void)hipFuncSetAttribute(reinterpret_cast<const void*>(&gemmQKV<3>),
                            hipFuncAttributeMaxDynamicSharedMemorySize, 131072);
  (void)hipFuncSetAttribute(reinterpret_cast<const void*>(&gemm1P),
                            hipFuncAttributeMaxDynamicSharedMemorySize, 98304);
  (void)hipFuncSetAttribute(reinterpret_cast<const void*>(&gemmCtx<3>),
                            hipFuncAttributeMaxDynamicSharedMemorySize, 131072);

  // 1) prep: LN ∪ Wconvert ∪ mask_scan
  prep<<<BB * NN + 6912 + BB, 256, 0, stream>>>(
      features, gamma, beta, Xb, Wq, Wk, Wv, Wcat, mask, kidx, ncnt);

  // 2) X row compaction
  xc_gather<<<dim3(128, BB), 256, 0, stream>>>(Xb, kidx, ncnt, Xc);

  // 3) merged Q + K/V projection (Q: 256 items; KV: up to 512 items, early-exit)
  gemmQKV<3><<<768, 512, 131072, stream>>>(Xb, Xc, Wcat, Qb, Kc, Vtc, ncnt);

  // 4) scores (dense compacted keys, persistent 128x256 items)
  gemm1P<<<256, 512, 98304, stream>>>(Qb, Kc, Sb, ncnt);

  // 5) compacted softmax
  softmax_c<<<BB * NN, 256, 0, stream>>>(Sb, ncnt);

  // 6) context: per batch P[2048,r128] x Vtc[768,r128]^T -> f32 out
  gemmCtx<3><<<dim3(DD / 192, NN / 256, BB), 512, 131072, stream>>>(
      Sb, Vtc, out, NN, NN,
      (long)NN * NN, (long)DD * NN, (long)NN * DD, ncnt);
}

// Round 17
// 199.534 us; speedup vs baseline: 1.3904x; 1.0714x over previous
//
#include <hip/hip_runtime.h>
#include <hip/hip_bf16.h>
#include <cstdint>

typedef __attribute__((ext_vector_type(8))) __bf16 bf16v8;
typedef __attribute__((ext_vector_type(4))) float f32x4;
typedef __attribute__((ext_vector_type(4))) unsigned short ushort4v;
typedef __attribute__((ext_vector_type(8))) unsigned short ushort8v;

#define BB 8
#define NN 2048
#define DD 768

__device__ __forceinline__ float b2f(unsigned short u) {
  union { unsigned int i; float f; } c; c.i = ((unsigned int)u) << 16; return c.f;
}
__device__ __forceinline__ unsigned short f2b(float f) {
  union { float f; unsigned int i; } c; c.f = f;
  unsigned int u = c.i;
  return (unsigned short)((u + 0x7fffu + ((u >> 16) & 1u)) >> 16);
}

// ---------------- prep: LayerNorm ∪ Wconvert ∪ mask_scan (block-partitioned) ----------------
__global__ __launch_bounds__(256) void prep(
    const float* __restrict__ x, const float* __restrict__ gamma, const float* __restrict__ beta,
    unsigned short* __restrict__ xb,
    const float* __restrict__ Wq, const float* __restrict__ Wk, const float* __restrict__ Wv,
    unsigned short* __restrict__ Wcat,
    const int* __restrict__ mask, int* __restrict__ kidx, int* __restrict__ ncnt) {
  __shared__ float red[2][4];
  __shared__ int wsum[4];
  const int bid = blockIdx.x;
  const int t = threadIdx.x;

  if (bid < BB * NN) {
    // ---- LayerNorm row ----
    const int row = bid;
    const float* xr = x + (size_t)row * DD;
    float a0 = xr[t], a1 = xr[t + 256], a2 = xr[t + 512];
    float s = a0 + a1 + a2;
    float q = a0 * a0 + a1 * a1 + a2 * a2;
    for (int o = 32; o > 0; o >>= 1) { s += __shfl_xor(s, o); q += __shfl_xor(q, o); }
    int w = t >> 6, lane = t & 63;
    if (lane == 0) { red[0][w] = s; red[1][w] = q; }
    __syncthreads();
    s = red[0][0] + red[0][1] + red[0][2] + red[0][3];
    q = red[1][0] + red[1][1] + red[1][2] + red[1][3];
    float mean = s * (1.0f / DD);
    float var = q * (1.0f / DD) - mean * mean;
    float inv = rsqrtf(var + 1e-5f);
    unsigned short* o0 = xb + (size_t)row * DD;
    o0[t]       = f2b((a0 - mean) * inv * gamma[t]       + beta[t]);
    o0[t + 256] = f2b((a1 - mean) * inv * gamma[t + 256] + beta[t + 256]);
    o0[t + 512] = f2b((a2 - mean) * inv * gamma[t + 512] + beta[t + 512]);
  } else if (bid < BB * NN + 6912) {
    // ---- weight concat/convert (scale folded into Wq) ----
    const int i = (bid - BB * NN) * 256 + t;
    const int dd = DD * DD;
    if (i < 3 * dd) {
      float v;
      if (i < dd)           v = Wq[i] * 0.03608439182435161f;   // 1/sqrt(768)
      else if (i < 2 * dd)  v = Wk[i - dd];
      else                  v = Wv[i - 2 * dd];
      Wcat[i] = f2b(v);
    }
  } else {
    // ---- mask prefix scan: kidx / ncnt ----
    const int b = bid - (BB * NN + 6912);
    const int* mr = mask + b * NN;
#pragma unroll
    for (int j = 0; j < 8; ++j) kidx[b * NN + t * 8 + j] = 0;
    int v[8]; int s = 0;
#pragma unroll
    for (int j = 0; j < 8; ++j) { v[j] = (mr[t * 8 + j] == 0) ? 1 : 0; s += v[j]; }
    int lane = t & 63, w = t >> 6;
    int xp = s;
    for (int o = 1; o < 64; o <<= 1) { int y = __shfl_up(xp, o); if (lane >= o) xp += y; }
    if (lane == 63) wsum[w] = xp;
    __syncthreads();
    int base = 0;
#pragma unroll
    for (int i = 0; i < 4; ++i) if (i < w) base += wsum[i];
    int run = base + xp - s;
#pragma unroll
    for (int j = 0; j < 8; ++j) { if (v[j]) kidx[b * NN + run] = t * 8 + j; run += v[j]; }
    if (t == 255) ncnt[b] = base + xp;
  }
}

// ------------- X row compaction: Xc[off[b]+c][:] = Xb[b][kidx[c]][:] (c<nc), 0 for [nc,r256) -------------
__global__ __launch_bounds__(256) void xc_gather(const unsigned short* __restrict__ Xb,
                                                 const int* __restrict__ kidx,
                                                 const int* __restrict__ ncnt,
                                                 unsigned short* __restrict__ Xc) {
  const int b = blockIdx.y;
  const int nc = ncnt[b];
  const int r256 = (nc + 255) & ~255;
  const int row0 = blockIdx.x * 16;
  if (row0 >= r256) return;
  int off = 0;
#pragma unroll
  for (int i = 0; i < 8; ++i) if (i < b) off += (ncnt[i] + 255) & ~255;
  for (int u = threadIdx.x; u < 16 * 96; u += 256) {
    const int r = row0 + u / 96;
    const int ch = (u % 96) * 8;
    if (r >= r256) continue;
    ushort8v val = {0, 0, 0, 0, 0, 0, 0, 0};
    if (r < nc)
      val = *(const ushort8v*)&Xb[((size_t)b * NN + kidx[b * NN + r]) * DD + ch];
    *(ushort8v*)&Xc[(size_t)(off + r) * DD + ch] = val;
  }
}

// ---------------- async global->LDS (16B per lane, wave-uniform LDS base) ----------------
__device__ __forceinline__ void gload_lds16(const void* g, void* l) {
  __builtin_amdgcn_global_load_lds(
      (const __attribute__((address_space(1))) void*)g,
      (__attribute__((address_space(3))) void*)(unsigned)(uintptr_t)l,
      16, 0, 0);
}

// LDS geometry (elements): buffer b at b*32768.
//   slot A-ks at  buf + ks*8192          (256 rows x 32 cols, 64B rows)
//   slot B-ks at  buf + 16384 + ks*8192
#define RDA(i0, ks, B)                                                                   \
  _Pragma("unroll")                                                                      \
  for (int i_ = 0; i_ < 4; ++i_)                                                         \
    aq[i_] = *(const bf16v8*)&smem[(B) + (ks) * 8192 + arow0 + ((i0) + i_) * 512 + kg8];
#define RDB(ks, B)                                                                       \
  _Pragma("unroll")                                                                      \
  for (int j_ = 0; j_ < NJ; ++j_)                                                        \
    bq[j_] = *(const bf16v8*)&smem[(B) + 16384 + (ks) * 8192 + brow0 + j_ * 512 + kg8];
#define MFQ(i0)                                                                          \
  _Pragma("unroll")                                                                      \
  for (int i_ = 0; i_ < 4; ++i_) {                                                       \
    _Pragma("unroll")                                                                    \
    for (int j_ = 0; j_ < NJ; ++j_)                                                      \
      acc[(i0) + i_][j_] = __builtin_amdgcn_mfma_f32_16x16x32_bf16(                      \
          aq[i_], bq[j_], acc[(i0) + i_][j_], 0, 0, 0);                                  \
  }
#define BARF asm volatile("s_barrier" ::: "memory")
#define VMC6 asm volatile("s_waitcnt vmcnt(6)" ::: "memory")
#define VMC3 asm volatile("s_waitcnt vmcnt(3)" ::: "memory")
#define VMC0 asm volatile("s_waitcnt vmcnt(0)" ::: "memory")
#define P1   __builtin_amdgcn_s_setprio(1)
#define P0   __builtin_amdgcn_s_setprio(0)

// r6 per-tile schedule (256-row tiles):
#define TILEK(KT, CURB, NXTB)                                                            \
  do {                                                                                   \
    RDA(0, 0, CURB); RDB(0, CURB);                                                       \
    if ((KT) + 1 < NT) stgA((KT) + 1, 1, (NXTB));                                        \
    BARF; P1; MFQ(0); P0; BARF;                                                          \
    RDA(4, 0, CURB);                                                                     \
    if ((KT) + 1 < NT) stgB((KT) + 1, 1, (NXTB));                                        \
    BARF; P1; MFQ(4); P0;                                                                \
    VMC6; BARF;                                                                          \
    RDA(0, 1, CURB); RDB(1, CURB);                                                       \
    if ((KT) + 2 < NT) stgA((KT) + 2, 0, (CURB));                                        \
    BARF; P1; MFQ(0); P0; BARF;                                                          \
    RDA(4, 1, CURB);                                                                     \
    if ((KT) + 2 < NT) stgB((KT) + 2, 0, (CURB));                                        \
    BARF; P1; MFQ(4); P0;                                                                \
    if ((KT) < NT - 2) { VMC6; } else { VMC0; }                                          \
    BARF;                                                                                \
  } while (0)

// ---- context GEMM (r6 structure), C = A * B^T, f32 store, runtime NT = 2*ceil(nc/128) ----
template <int NJ>
__global__ __launch_bounds__(512, 2) void gemmCtx(
    const unsigned short* __restrict__ A, const unsigned short* __restrict__ Bm,
    float* __restrict__ Cf, int lda, int ldb,
    long aStride, long bStride, long cStride,
    const int* __restrict__ ncnt) {
  extern __shared__ unsigned short smem[];      // 65536 elems = 131072 B
  const int BN = NJ * 64;

  const int t = threadIdx.x;
  int bx = blockIdx.x, by = blockIdx.y, bz = blockIdx.z;
  {  // bijective XCD swizzle (grid %8==0)
    const int gx = gridDim.x, gy = gridDim.y;
    const int nwg = gx * gy * (int)gridDim.z;
    int id = bx + gx * (by + gy * bz);
    int sw = (id & 7) * (nwg >> 3) + (id >> 3);
    bx = sw % gx; int r2 = sw / gx;
    by = r2 % gy; bz = r2 / gy;
  }
  const int n0 = bx * BN, m0 = by * 256;
  const int NT = ((ncnt[bz] + 127) >> 7) << 1;

  const unsigned short* Ab = A + (size_t)bz * aStride;
  const unsigned short* Bb = Bm + (size_t)bz * bStride;

  const int lane = t & 63;
  const int w = t >> 6;
  const int wm = w >> 2, wn = w & 3;
  const int frow = lane & 15;
  const int kg8 = (lane >> 4) * 8;
  const int arow0 = (wm * 128 + frow) * 32;
  const int brow0 = (wn * (NJ * 16) + frow) * 32;

  const int srow = t >> 2;
  const int scol8 = (t & 3) * 8;
  const unsigned short* Asrc = Ab + (size_t)(m0 + srow) * lda + scol8;
  const unsigned short* Bsrc = Bb + (size_t)(n0 + srow) * ldb + scol8;
  const int sdst = w * 512;

  auto stgA = [&](int kt, int ks, int bufb) {
    const unsigned short* s = Asrc + kt * 64 + ks * 32;
    gload_lds16(s, &smem[bufb + ks * 8192 + sdst]);
    gload_lds16(s + (size_t)128 * lda, &smem[bufb + ks * 8192 + 4096 + sdst]);
  };
  auto stgB = [&](int kt, int ks, int bufb) {
    const unsigned short* s = Bsrc + kt * 64 + ks * 32;
    gload_lds16(s, &smem[bufb + 16384 + ks * 8192 + sdst]);
    gload_lds16(s + (size_t)128 * ldb, &smem[bufb + 16384 + ks * 8192 + 4096 + sdst]);
  };

  f32x4 acc[8][NJ] = {};
  bf16v8 aq[4], bq[NJ];

  stgA(0, 0, 0);     stgB(0, 0, 0);
  stgA(0, 1, 0);     stgB(0, 1, 0);
  stgA(1, 0, 32768); stgB(1, 0, 32768);
  asm volatile("s_waitcnt vmcnt(8)" ::: "memory");
  BARF;

  for (int ktp = 0; ktp < NT; ktp += 2) {
    TILEK(ktp, 0, 32768);
    TILEK(ktp + 1, 32768, 0);
  }

  const int r0 = (lane >> 4) * 4;
  const int c0 = lane & 15;
  const int mrowB = m0 + wm * 128 + r0;
  const int ncolB = n0 + wn * (NJ * 16) + c0;
  float* dst = Cf + (size_t)bz * cStride;
#pragma unroll
  for (int i = 0; i < 8; ++i)
#pragma unroll
    for (int j = 0; j < NJ; ++j)
#pragma unroll
      for (int r = 0; r < 4; ++r)
        dst[(size_t)(mrowB + i * 16 + r) * DD + (ncolB + j * 16)] = acc[i][j][r];
}

// ---- Merged Q + K/V projection, NJ=4 (256-wide tiles) -> 2-round makespan ----
// lid < 192:        Q items (64 m x 3 n):  Q = Xb * Wcat[0:768]^T
// lid in [192..):   KV items (GT x 6 n):   [Kc|Vtc] = Xc * Wcat[768:2304]^T
// lid remap clusters A-panel-sharing neighbors (3 Q / 6 KV consecutive) on one XCD.
template <int NJ>
__global__ __launch_bounds__(512, 2) void gemmQKV(
    const unsigned short* __restrict__ Xb, const unsigned short* __restrict__ Xc,
    const unsigned short* __restrict__ Wcat,
    unsigned short* __restrict__ Qb, unsigned short* __restrict__ Kc,
    unsigned short* __restrict__ Vtc, const int* __restrict__ ncnt) {
  extern __shared__ unsigned short smem[];      // 131072 B
  constexpr int NT = 12;

  const int t = threadIdx.x;
  const int bid = (int)blockIdx.x;
  const int lid = (bid & 7) * 64 + (bid >> 3);   // XCD chunking (512 grid)

  const int lane = t & 63;
  const int w = t >> 6;
  const int wm = w >> 2, wn = w & 3;
  const int frow = lane & 15;
  const int kg8 = (lane >> 4) * 8;
  const int arow0 = (wm * 128 + frow) * 32;
  const int brow0 = (wn * (NJ * 16) + frow) * 32;
  const int srow = t >> 2;
  const int scol8 = (t & 3) * 8;
  const int sdst = w * 512;

  const bool isQ = lid < 192;
  const unsigned short* Asrc;
  const unsigned short* Bsrc;
  int m0 = 0, ncolQ = 0, b = 0, cbase0 = 0, ni = 0;
  if (isQ) {
    m0 = (lid / 3) * 256;
    ncolQ = (lid % 3) * 256;
    Asrc = Xb + (size_t)(m0 + srow) * DD + scol8;
    Bsrc = Wcat + (size_t)(ncolQ + srow) * DD + scol8;
  } else {
    int offv[9]; offv[0] = 0;
#pragma unroll
    for (int i = 0; i < 8; ++i) offv[i + 1] = offv[i] + ((ncnt[i] + 255) & ~255);
    const int GT = offv[8] >> 8;
    const int kid = lid - 192;
    if (kid >= GT * 6) return;
    const int gt = kid / 6; ni = kid % 6;
#pragma unroll
    for (int i = 1; i < 8; ++i) if (offv[i] <= gt * 256) b = i;
    cbase0 = gt * 256 - offv[b];
    Asrc = Xc + (size_t)(gt * 256 + srow) * DD + scol8;
    Bsrc = Wcat + (size_t)(768 + ni * 256 + srow) * DD + scol8;
  }

  auto stgA = [&](int kt, int ks, int bufb) {
    const unsigned short* s = Asrc + kt * 64 + ks * 32;
    gload_lds16(s, &smem[bufb + ks * 8192 + sdst]);
    gload_lds16(s + (size_t)128 * DD, &smem[bufb + ks * 8192 + 4096 + sdst]);
  };
  auto stgB = [&](int kt, int ks, int bufb) {
    const unsigned short* s = Bsrc + kt * 64 + ks * 32;
    gload_lds16(s, &smem[bufb + 16384 + ks * 8192 + sdst]);
    gload_lds16(s + (size_t)128 * DD, &smem[bufb + 16384 + ks * 8192 + 4096 + sdst]);
  };

  f32x4 acc[8][NJ] = {};
  bf16v8 aq[4], bq[NJ];

  stgA(0, 0, 0);     stgB(0, 0, 0);
  stgA(0, 1, 0);     stgB(0, 1, 0);
  stgA(1, 0, 32768); stgB(1, 0, 32768);
  asm volatile("s_waitcnt vmcnt(8)" ::: "memory");
  BARF;

  for (int ktp = 0; ktp < NT; ktp += 2) {
    TILEK(ktp, 0, 32768);
    TILEK(ktp + 1, 32768, 0);
  }

  const int r0 = (lane >> 4) * 4;
  const int c0 = lane & 15;
  if (isQ) {
    const int mrowB = m0 + wm * 128 + r0;
    const int ncolB = ncolQ + wn * (NJ * 16) + c0;
#pragma unroll
    for (int i = 0; i < 8; ++i)
#pragma unroll
      for (int j = 0; j < NJ; ++j)
#pragma unroll
        for (int r = 0; r < 4; ++r)
          Qb[(size_t)(mrowB + i * 16 + r) * DD + (ncolB + j * 16)] = f2b(acc[i][j][r]);
  } else {
    const int rowL = wm * 128 + r0;
    const int ncolL = ni * 256 + wn * (NJ * 16) + c0;
    const int cbase = cbase0 + rowL;
    if (ni < 3) {   // K region: dense compacted rows, ld=768
      unsigned short* dst = Kc + (size_t)b * NN * DD;
#pragma unroll
      for (int i = 0; i < 8; ++i)
#pragma unroll
        for (int j = 0; j < NJ; ++j)
#pragma unroll
          for (int r = 0; r < 4; ++r)
            dst[(size_t)(cbase + i * 16 + r) * DD + (ncolL + j * 16)] = f2b(acc[i][j][r]);
    } else {        // V region (ncolL >= 768): transposed, dense compacted cols (vectorized)
#pragma unroll
      for (int i = 0; i < 8; ++i) {
#pragma unroll
        for (int j = 0; j < NJ; ++j) {
          const int e = ncolL + j * 16 - 768;
          ushort4v pk;
#pragma unroll
          for (int r = 0; r < 4; ++r) pk[r] = f2b(acc[i][j][r]);
          *(ushort4v*)&Vtc[((size_t)b * DD + e) * NN + cbase + i * 16] = pk;
        }
      }
    }
  }
}

// ---- Persistent scores GEMM, 128x256 items: S[b][m][c] = Q[b][m] . Kc[b][c] ----
__global__ __launch_bounds__(512, 2) void gemm1P(
    const unsigned short* __restrict__ Qa, const unsigned short* __restrict__ Kn,
    unsigned short* __restrict__ So, const int* __restrict__ ncnt) {
  extern __shared__ unsigned short smem[];      // 49152 elems = 98304 B
  constexpr int NT = 12;

  const int t = threadIdx.x;
  const int lane = t & 63;
  const int w = t >> 6;
  const int wm = w >> 2, wn = w & 3;
  const int frow = lane & 15;
  const int kg8 = (lane >> 4) * 8;
  const int arow0 = (wm * 64 + frow) * 32;
  const int brow0 = (wn * 64 + frow) * 32;
  const int srow = t >> 2;
  const int scol8 = (t & 3) * 8;
  const int sdst = w * 512;
  const int r0 = (lane >> 4) * 4;
  const int c0 = lane & 15;

  int nbv[8];
#pragma unroll
  for (int b_ = 0; b_ < 8; ++b_) nbv[b_] = (ncnt[b_] + 255) >> 8;

  f32x4 acc[4][4];
  bf16v8 aq[4], bq[4];

#pragma unroll 1
  for (int it = 0; it < 4; ++it) {
    int rem = (int)blockIdx.x + it * 256;
    int b = 0;
#pragma unroll 1
    for (; b < 8; ++b) { int c = nbv[b] * 16; if (rem < c) break; rem -= c; }
    if (b >= 8) break;
    const int ni = rem >> 4, mi = rem & 15;
    const int m0 = mi * 128, n0 = ni * 256;

    const unsigned short* Asrc = Qa + ((size_t)b * NN + m0 + srow) * DD + scol8;
    const unsigned short* Bsrc = Kn + ((size_t)b * NN + n0 + srow) * DD + scol8;

    auto stgA = [&](int kt, int ks, int bufb) {
      gload_lds16(Asrc + kt * 64 + ks * 32, &smem[bufb + ks * 4096 + sdst]);
    };
    auto stgB = [&](int kt, int ks, int bufb) {
      const unsigned short* s = Bsrc + kt * 64 + ks * 32;
      gload_lds16(s, &smem[bufb + 8192 + ks * 8192 + sdst]);
      gload_lds16(s + (size_t)128 * DD, &smem[bufb + 8192 + ks * 8192 + 4096 + sdst]);
    };

#pragma unroll
    for (int i = 0; i < 4; ++i)
#pragma unroll
      for (int j = 0; j < 4; ++j) acc[i][j] = f32x4{0.f, 0.f, 0.f, 0.f};

    stgA(0, 0, 0);     stgB(0, 0, 0);
    stgA(0, 1, 0);     stgB(0, 1, 0);
    stgA(1, 0, 24576); stgB(1, 0, 24576);
    VMC3;
    BARF;

#pragma unroll 1
    for (int kt = 0; kt < NT; ++kt) {
      const int cur = (kt & 1) ? 24576 : 0;
      const int nxt = cur ^ 24576;
#pragma unroll
      for (int i_ = 0; i_ < 4; ++i_)
        aq[i_] = *(const bf16v8*)&smem[cur + arow0 + i_ * 512 + kg8];
#pragma unroll
      for (int j_ = 0; j_ < 4; ++j_)
        bq[j_] = *(const bf16v8*)&smem[cur + 8192 + brow0 + j_ * 512 + kg8];
      if (kt + 1 < NT) { stgA(kt + 1, 1, nxt); stgB(kt + 1, 1, nxt); }
      BARF; P1;
#pragma unroll
      for (int i_ = 0; i_ < 4; ++i_)
#pragma unroll
        for (int j_ = 0; j_ < 4; ++j_)
          acc[i_][j_] = __builtin_amdgcn_mfma_f32_16x16x32_bf16(aq[i_], bq[j_], acc[i_][j_], 0, 0, 0);
      P0; BARF;
#pragma unroll
      for (int i_ = 0; i_ < 4; ++i_)
        aq[i_] = *(const bf16v8*)&smem[cur + 4096 + arow0 + i_ * 512 + kg8];
#pragma unroll
      for (int j_ = 0; j_ < 4; ++j_)
        bq[j_] = *(const bf16v8*)&smem[cur + 16384 + brow0 + j_ * 512 + kg8];
      if (kt + 2 < NT) { stgA(kt + 2, 0, cur); stgB(kt + 2, 0, cur); }
      BARF; P1;
#pragma unroll
      for (int i_ = 0; i_ < 4; ++i_)
#pragma unroll
        for (int j_ = 0; j_ < 4; ++j_)
          acc[i_][j_] = __builtin_amdgcn_mfma_f32_16x16x32_bf16(aq[i_], bq[j_], acc[i_][j_], 0, 0, 0);
      P0;
      if (kt < NT - 2) { VMC3; } else { VMC0; }
      BARF;
    }

    unsigned short* dst = So + (size_t)b * NN * NN;
    const int mrowB = m0 + wm * 64 + r0;
    const int ncolB = n0 + wn * 64 + c0;
#pragma unroll
    for (int i = 0; i < 4; ++i)
#pragma unroll
      for (int j = 0; j < 4; ++j)
#pragma unroll
        for (int r = 0; r < 4; ++r)
          dst[(size_t)(mrowB + i * 16 + r) * NN + (ncolB + j * 16)] = f2b(acc[i][j][r]);
  }
}

// ---------------- compacted softmax: cols [0,nc) valid, zero-fill [nc,r128), skip rest ----------------
__global__ __launch_bounds__(256) void softmax_c(unsigned short* __restrict__ S,
                                                 const int* __restrict__ ncnt) {
  int row = blockIdx.x;            // 0..16383
  int bb = row >> 11;
  const int nc = ncnt[bb];
  const int p128 = (nc + 127) & ~127;
  unsigned short* sr = S + (size_t)row * NN;
  int t = threadIdx.x;
  const int cbase = t * 8;

  float v[8];
  const bool anyload = cbase < nc;
  ushort8v pk;
  if (anyload) pk = *(const ushort8v*)&sr[cbase];
  float mx = -1e30f;
#pragma unroll
  for (int j = 0; j < 8; ++j) {
    v[j] = anyload ? b2f(pk[j]) : 0.f;
    if (cbase + j < nc) mx = fmaxf(mx, v[j]);
  }
  for (int o = 32; o > 0; o >>= 1) mx = fmaxf(mx, __shfl_xor(mx, o));
  __shared__ float redm[4], reds[4];
  int w = t >> 6, lane = t & 63;
  if (lane == 0) redm[w] = mx;
  __syncthreads();
  mx = fmaxf(fmaxf(redm[0], redm[1]), fmaxf(redm[2], redm[3]));

  float e[8];
  float sum = 0.f;
#pragma unroll
  for (int j = 0; j < 8; ++j) {
    e[j] = (cbase + j < nc) ? __expf(v[j] - mx) : 0.f;
    sum += e[j];
  }
  for (int o = 32; o > 0; o >>= 1) sum += __shfl_xor(sum, o);
  if (lane == 0) reds[w] = sum;
  __syncthreads();
  sum = reds[0] + reds[1] + reds[2] + reds[3];
  float inv = 1.0f / sum;

  if (cbase < p128) {
    ushort8v op;
#pragma unroll
    for (int j = 0; j < 8; ++j) op[j] = f2b(e[j] * inv);
    *(ushort8v*)&sr[cbase] = op;
  }
}

extern "C" void kernel_launch(void* const* d_in, const int* in_sizes, int n_in,
                              void* d_out, int out_size, void* d_ws, size_t ws_size,
                              hipStream_t stream) {
  const float* features = (const float*)d_in[0];
  const int* mask       = (const int*)d_in[1];
  const float* Wq       = (const float*)d_in[2];
  const float* Wk       = (const float*)d_in[3];
  const float* Wv       = (const float*)d_in[4];
  const float* gamma    = (const float*)d_in[5];
  const float* beta     = (const float*)d_in[6];
  float* out = (float*)d_out;

  char* ws = (char*)d_ws;
  size_t off = 0;
  auto alloc = [&](size_t bytes) {
    char* p = ws + off;
    off += (bytes + 255) & ~(size_t)255;
    return p;
  };
  unsigned short* Wcat = (unsigned short*)alloc((size_t)(2304 + 64) * DD * 2);
  unsigned short* Qb   = (unsigned short*)alloc((size_t)BB * NN * DD * 2);
  unsigned short* Kc   = (unsigned short*)alloc((size_t)BB * NN * DD * 2);   // compacted K rows
  unsigned short* Vtc  = (unsigned short*)alloc(((size_t)BB * DD + 64) * NN * 2);  // compacted Vt cols
  int* kidx = (int*)alloc((size_t)BB * NN * 4);
  int* ncnt = (int*)alloc(64 * 4);
  // S (67 MB): Xb aliases its first 25 MB; Xc aliases its upper half (dead before gemm1P writes S).
  char* last = alloc((size_t)BB * NN * NN * 2);
  unsigned short* Sb = (unsigned short*)last;
  unsigned short* Xb = (unsigned short*)last;
  unsigned short* Xc = (unsigned short*)(last + (size_t)34 * 1024 * 1024);

  (void)hipFuncSetAttribute(reinterpret_cast<const void*>(&gemmQKV<4>),
                            hipFuncAttributeMaxDynamicSharedMemorySize, 131072);
  (void)hipFuncSetAttribute(reinterpret_cast<const void*>(&gemm1P),
                            hipFuncAttributeMaxDynamicSharedMemorySize, 98304);
  (void)hipFuncSetAttribute(reinterpret_cast<const void*>(&gemmCtx<3>),
                            hipFuncAttributeMaxDynamicSharedMemorySize, 131072);

  // 1) prep: LN ∪ Wconvert ∪ mask_scan
  prep<<<BB * NN + 6912 + BB, 256, 0, stream>>>(
      features, gamma, beta, Xb, Wq, Wk, Wv, Wcat, mask, kidx, ncnt);

  // 2) X row compaction
  xc_gather<<<dim3(128, BB), 256, 0, stream>>>(Xb, kidx, ncnt, Xc);

  // 3) merged Q + K/V projection, NJ=4: ~408 items on 512 blocks -> 2-round makespan
  gemmQKV<4><<<512, 512, 131072, stream>>>(Xb, Xc, Wcat, Qb, Kc, Vtc, ncnt);

  // 4) scores (dense compacted keys, persistent 128x256 items)
  gemm1P<<<256, 512, 98304, stream>>>(Qb, Kc, Sb, ncnt);

  // 5) compacted softmax
  softmax_c<<<BB * NN, 256, 0, stream>>>(Sb, ncnt);

  // 6) context: per batch P[2048,r128] x Vtc[768,r128]^T -> f32 out
  gemmCtx<3><<<dim3(DD / 192, NN / 256, BB), 512, 131072, stream>>>(
      Sb, Vtc, out, NN, NN,
      (long)NN * NN, (long)DD * NN, (long)NN * DD, ncnt);
}